// Round 4
// baseline (1665.624 us; speedup 1.0000x reference)
//
#include <hip/hip_runtime.h>
#include <hip/hip_bf16.h>

#define NN 100000
#define DD 128
#define VV 3
#define EE 500000

typedef unsigned short u16;
typedef unsigned int u32;

__device__ __forceinline__ float bf2f(u16 u) {
    return __uint_as_float(((u32)u) << 16);
}
__device__ __forceinline__ u16 f2bf(float f) {
    u32 x = __float_as_uint(f);
    u32 r = (x + 0x7fffu + ((x >> 16) & 1u)) >> 16;
    return (u16)r;
}

// packed bf16 atomic add of (f0,f1) at 4B-aligned bf16 pair (fallback path only)
__device__ __forceinline__ void atomAddBf16x2(u16* addr, float f0, float f1) {
#if __has_builtin(__builtin_amdgcn_global_atomic_fadd_v2bf16)
    typedef short v2s __attribute__((ext_vector_type(2)));
    typedef v2s __attribute__((address_space(1)))* v2s_gp;
    v2s v;
    v.x = (short)f2bf(f0);
    v.y = (short)f2bf(f1);
    __builtin_amdgcn_global_atomic_fadd_v2bf16((v2s_gp)(void*)addr, v);
#else
    u32* p = (u32*)addr;
    u32 old = *(volatile u32*)p;
    while (true) {
        float lo = bf2f((u16)(old & 0xffffu)) + f0;
        float hi = bf2f((u16)(old >> 16)) + f1;
        u32 nv = (u32)f2bf(lo) | ((u32)f2bf(hi) << 16);
        u32 prev = atomicCAS(p, old, nv);
        if (prev == old) break;
        old = prev;
    }
#endif
}

// ---- generic GEMM accumulate: acc[4][4] += X[32 rows][K] * W[64 krows][BN] ----
template<int XSTR, int WSTR>
__device__ __forceinline__ void gemm16(float acc[4][4], const float* Xs,
                                       const float* Ws, int n0, int o0, int kbase) {
    #pragma unroll 4
    for (int kk = 0; kk < 64; kk += 4) {
        float4 w0 = *reinterpret_cast<const float4*>(Ws + (kk + 0) * WSTR + o0);
        float4 w1 = *reinterpret_cast<const float4*>(Ws + (kk + 1) * WSTR + o0);
        float4 w2 = *reinterpret_cast<const float4*>(Ws + (kk + 2) * WSTR + o0);
        float4 w3 = *reinterpret_cast<const float4*>(Ws + (kk + 3) * WSTR + o0);
        #pragma unroll
        for (int i = 0; i < 4; ++i) {
            float4 x = *reinterpret_cast<const float4*>(Xs + (n0 + i) * XSTR + kbase + kk);
            acc[i][0] = fmaf(x.x, w0.x, fmaf(x.y, w1.x, fmaf(x.z, w2.x, fmaf(x.w, w3.x, acc[i][0]))));
            acc[i][1] = fmaf(x.x, w0.y, fmaf(x.y, w1.y, fmaf(x.z, w2.y, fmaf(x.w, w3.y, acc[i][1]))));
            acc[i][2] = fmaf(x.x, w0.z, fmaf(x.y, w1.z, fmaf(x.z, w2.z, fmaf(x.w, w3.z, acc[i][2]))));
            acc[i][3] = fmaf(x.x, w0.w, fmaf(x.y, w1.w, fmaf(x.z, w2.w, fmaf(x.w, w3.w, acc[i][3]))));
        }
    }
}

// stage 64x128 fp32 weights (global, row stride 128) into LDS, row stride WSTR
template<int WSTR, int NT>
__device__ __forceinline__ void stage_w_f32(float* Ws, const float* __restrict__ src, int tid) {
    #pragma unroll
    for (int rep = 0; rep < 2048 / NT; ++rep) {
        int flat = rep * NT + tid;          // 0..2047 float4 chunks
        int kk = flat >> 5;
        int c4 = flat & 31;
        float4 q = *reinterpret_cast<const float4*>(src + kk * 128 + c4 * 4);
        *reinterpret_cast<float4*>(Ws + kk * WSTR + c4 * 4) = q;
    }
}

// stage 32x128 fp32 rows (row stride 128) into LDS [32][XSTR]
template<int XSTR, int NT>
__device__ __forceinline__ void stage_x_f32(float* Xs, const float* __restrict__ src, int tid) {
    #pragma unroll
    for (int rep = 0; rep < 1024 / NT; ++rep) {
        int flat = rep * NT + tid;          // 0..1023 float4 chunks
        int n = flat >> 5;
        int c4 = flat & 31;
        float4 q = *reinterpret_cast<const float4*>(src + (size_t)n * 128 + c4 * 4);
        *reinterpret_cast<float4*>(Xs + n * XSTR + c4 * 4) = q;
    }
}

// stage 32x128 bf16 rows (row stride 128) into LDS fp32 [32][XSTR]
template<int XSTR, int NT>
__device__ __forceinline__ void stage_x_bf16(float* Xs, const u16* __restrict__ src, int tid) {
    #pragma unroll
    for (int rep = 0; rep < 512 / NT; ++rep) {
        int flat = rep * NT + tid;          // 0..511 : uint4 chunks of 8 bf16
        int n = flat >> 4;
        int c8 = flat & 15;
        uint4 q = *reinterpret_cast<const uint4*>(src + (size_t)n * 128 + c8 * 8);
        float* d = Xs + n * XSTR + c8 * 8;
        d[0] = bf2f((u16)(q.x & 0xffffu)); d[1] = bf2f((u16)(q.x >> 16));
        d[2] = bf2f((u16)(q.y & 0xffffu)); d[3] = bf2f((u16)(q.y >> 16));
        d[4] = bf2f((u16)(q.z & 0xffffu)); d[5] = bf2f((u16)(q.z >> 16));
        d[6] = bf2f((u16)(q.w & 0xffffu)); d[7] = bf2f((u16)(q.w >> 16));
    }
}

// ---------------- prep: Wsf = selfW @ fusW_top ; c1 = selfb @ fusW_top + fusb ----
__global__ void prep_kernel(const float* __restrict__ selfW, const float* __restrict__ selfb,
                            const float* __restrict__ fusW, const float* __restrict__ fusb,
                            float* __restrict__ Wsf, float* __restrict__ c1) {
    int o = threadIdx.x;
    int k = blockIdx.x;
    if (k < 128) {
        float acc = 0.f;
        for (int m = 0; m < 128; ++m)
            acc += selfW[k * 128 + m] * fusW[m * 128 + o];
        Wsf[k * 128 + o] = acc;
    } else {
        float acc = 0.f;
        for (int m = 0; m < 128; ++m)
            acc += selfb[m] * fusW[m * 128 + o];
        c1[o] = acc + fusb[o];
    }
}

// ================= CSR build + gather path =================
// C[v*NN+dst]: counts -> exclusive offsets -> (after fill) inclusive ends

__global__ __launch_bounds__(256) void count_kernel(
        const int* __restrict__ edst, int* __restrict__ C) {
    int t = blockIdx.x * 256 + threadIdx.x;
    if (t >= VV * EE) return;
    int v = t / EE;
    atomicAdd(&C[v * NN + edst[t]], 1);
}

// single-block exclusive prefix sum over C[0..3N)
__global__ __launch_bounds__(1024) void scan_kernel(int* __restrict__ C) {
    const int TOT = VV * NN;                // 300000
    const int CH = (TOT + 1023) / 1024;     // 293
    int t = threadIdx.x;
    int lo = t * CH, hi = lo + CH;
    if (hi > TOT) hi = TOT;
    int s = 0;
    for (int i = lo; i < hi; ++i) s += C[i];
    __shared__ int sums[1024];
    sums[t] = s;
    __syncthreads();
    // Hillis-Steele inclusive scan
    for (int off = 1; off < 1024; off <<= 1) {
        int vv = (t >= off) ? sums[t - off] : 0;
        __syncthreads();
        sums[t] += vv;
        __syncthreads();
    }
    int run = sums[t] - s;                  // exclusive base for this chunk
    for (int i = lo; i < hi; ++i) {
        int c = C[i];
        C[i] = run;
        run += c;
    }
}

__global__ __launch_bounds__(256) void fill_kernel(
        const int* __restrict__ edst, int* __restrict__ C, int* __restrict__ bucket) {
    int t = blockIdx.x * 256 + threadIdx.x;
    if (t >= VV * EE) return;
    int v = t / EE;
    int pos = atomicAdd(&C[v * NN + edst[t]], 1);
    bucket[pos] = t;
}

// one wave per (v,dst) row: agg[row] = sum_e w_e * feat[src_e], wsum[row] = sum_e w_e
__global__ __launch_bounds__(256) void gather_kernel(
        const int* __restrict__ esrc, const float* __restrict__ ew,
        const float* __restrict__ feat, const int* __restrict__ C,
        const int* __restrict__ bucket,
        u16* __restrict__ aggB, float* __restrict__ wsum) {
    int wid = (blockIdx.x * 256 + threadIdx.x) >> 6;   // row id in [0, 3N)
    int lane = threadIdx.x & 63;
    int end = C[wid];                    // post-fill: inclusive end
    int start = (wid == 0) ? 0 : C[wid - 1];
    float a0 = 0.f, a1 = 0.f, wacc = 0.f;
    for (int e = start; e < end; ++e) {
        int eid = bucket[e];
        int src = esrc[eid];
        float w = ew[eid];
        float2 f = *reinterpret_cast<const float2*>(feat + (size_t)src * DD + lane * 2);
        a0 = fmaf(w, f.x, a0);
        a1 = fmaf(w, f.y, a1);
        wacc += w;
    }
    u32 packed = (u32)f2bf(a0) | ((u32)f2bf(a1) << 16);
    *reinterpret_cast<u32*>(aggB + (size_t)wid * DD + lane * 2) = packed;
    if (lane == 0) wsum[wid] = wacc;
}

// ================= fallback: atomic scatter (R3 path) =================
__global__ __launch_bounds__(256) void scatter_kernel(
        const int* __restrict__ esrc, const int* __restrict__ edst,
        const float* __restrict__ ew, const float* __restrict__ feat,
        u16* __restrict__ aggB, float* __restrict__ wsum) {
    long long t = (long long)blockIdx.x * 256 + threadIdx.x;
    int lane = (int)(t & 31);
    int eg = (int)(t >> 5);
    int v = eg / EE;
    int src = 0, dst = 0; float w = 0.f;
    if (lane == 0) {
        src = esrc[eg]; dst = edst[eg]; w = ew[eg];
    }
    src = __shfl(src, 0, 32);
    dst = __shfl(dst, 0, 32);
    w   = __shfl(w, 0, 32);
    const float* fr = feat + (size_t)src * DD + lane * 4;
    float4 q = *reinterpret_cast<const float4*>(fr);
    u16* outp = aggB + ((size_t)v * NN + dst) * DD + lane * 4;
    atomAddBf16x2(outp,     w * q.x, w * q.y);
    atomAddBf16x2(outp + 2, w * q.z, w * q.w);
    if (lane == 0) atomicAdd(wsum + v * NN + dst, w);
}

// ---------------- label-aware attention -> node_att (fp32 ws), class_probs (fp32 out) ----
__global__ __launch_bounds__(256) void label_kernel(
        const float* __restrict__ feat, const float* __restrict__ clsW, const float* __restrict__ clsb,
        const float* __restrict__ attW1, const float* __restrict__ attb1,
        const float* __restrict__ attW2, const float* __restrict__ attb2,
        const float* __restrict__ att_bias,
        float* __restrict__ node_att, float* __restrict__ probs_out) {
    __shared__ float Xs[32][132];
    __shared__ float Ws[64][132];
    int tid = threadIdx.x;
    int row0 = blockIdx.x * 32;
    stage_x_f32<132, 256>(&Xs[0][0], feat + (size_t)row0 * DD, tid);
    int to = tid & 31, tn = tid >> 5;
    int o0 = to * 4, n0 = tn * 4;
    float acc[4][4] = {};
    for (int half = 0; half < 2; ++half) {
        __syncthreads();
        #pragma unroll
        for (int rep = 0; rep < 8; ++rep) {
            int flat = rep * 256 + tid;     // 0..2047 float4 chunks
            int kk = flat >> 5, o4 = flat & 31;
            int o = o4 * 4;
            int c = o >> 6, h = o & 63;
            int k = half * 64 + kk;
            float4 q = *reinterpret_cast<const float4*>(attW1 + (size_t)(c * 128 + k) * 64 + h);
            *reinterpret_cast<float4*>(&Ws[kk][o]) = q;
        }
        __syncthreads();
        gemm16<132, 132>(acc, &Xs[0][0], &Ws[0][0], n0, o0, half * 64);
    }
    int c = o0 >> 6, h0 = o0 & 63;
    float b1j[4], w2j[4];
    #pragma unroll
    for (int j = 0; j < 4; ++j) {
        b1j[j] = attb1[c * 64 + h0 + j];
        w2j[j] = attW2[c * 64 + h0 + j];
    }
    float part[4];
    #pragma unroll
    for (int i = 0; i < 4; ++i) {
        float s = 0.f;
        #pragma unroll
        for (int j = 0; j < 4; ++j) {
            float hv = acc[i][j] + b1j[j];
            hv = hv > 0.f ? hv : 0.f;
            s += hv * w2j[j];
        }
        part[i] = s;
    }
    __syncthreads();
    float* red = &Ws[0][0];          // [32][33]
    float* Ssc = red + 32 * 33;      // [32][2]
    float* Lsc = Ssc + 64;           // [32][2]
    #pragma unroll
    for (int i = 0; i < 4; ++i) red[(n0 + i) * 33 + to] = part[i];
    __syncthreads();
    if (tid < 64) {
        int n = tid >> 1, cc = tid & 1;
        float l = 0.f;
        for (int k = 0; k < 128; k += 4) {
            float4 x = *reinterpret_cast<const float4*>(&Xs[n][k]);
            l += x.x * clsW[(k + 0) * 2 + cc];
            l += x.y * clsW[(k + 1) * 2 + cc];
            l += x.z * clsW[(k + 2) * 2 + cc];
            l += x.w * clsW[(k + 3) * 2 + cc];
        }
        Lsc[n * 2 + cc] = l + clsb[cc];
        float s = 0.f;
        for (int u = 0; u < 16; ++u) s += red[n * 33 + cc * 16 + u];
        s += attb2[cc];
        Ssc[n * 2 + cc] = 1.f / (1.f + expf(-s));
    }
    __syncthreads();
    if (tid < 32) {
        int n = tid;
        float l0 = Lsc[n * 2], l1 = Lsc[n * 2 + 1];
        float m = fmaxf(l0, l1);
        float e0 = expf(l0 - m), e1 = expf(l1 - m);
        float inv = 1.f / (e0 + e1);
        float p0 = e0 * inv, p1 = e1 * inv;
        float na = p0 * Ssc[n * 2] + p1 * Ssc[n * 2 + 1] + att_bias[0];
        int row = row0 + n;
        node_att[row] = na;
        probs_out[row * 2]     = p0;
        probs_out[row * 2 + 1] = p1;
    }
}

// ---------------- per-view: agg = aggB@relW + wsum*relb ; view_out = sigmoid(agg@gateW+gb)*agg ----
__global__ __launch_bounds__(256) void relgate_kernel(
        const float* __restrict__ relW, const float* __restrict__ relb,
        const float* __restrict__ gateW, const float* __restrict__ gateb,
        u16* __restrict__ aggB, const float* __restrict__ wsum) {
    __shared__ float Xs[32][128];
    __shared__ float Ws[64][132];
    int tid = threadIdx.x;
    int v = blockIdx.y;
    int row0 = blockIdx.x * 32;
    u16* base = aggB + ((size_t)v * NN + row0) * DD;
    stage_x_bf16<128, 256>(&Xs[0][0], base, tid);
    int to = tid & 31, tn = tid >> 5;
    int o0 = to * 4, n0 = tn * 4;
    float acc[4][4] = {};
    const float* W1 = relW + (size_t)v * DD * DD;
    for (int half = 0; half < 2; ++half) {
        __syncthreads();
        stage_w_f32<132, 256>(&Ws[0][0], W1 + half * 64 * DD, tid);
        __syncthreads();
        gemm16<128, 132>(acc, &Xs[0][0], &Ws[0][0], n0, o0, half * 64);
    }
    float wsn[4], rb[4];
    #pragma unroll
    for (int i = 0; i < 4; ++i) wsn[i] = wsum[v * NN + row0 + n0 + i];
    #pragma unroll
    for (int j = 0; j < 4; ++j) rb[j] = relb[v * DD + o0 + j];
    #pragma unroll
    for (int i = 0; i < 4; ++i)
        #pragma unroll
        for (int j = 0; j < 4; ++j) acc[i][j] += wsn[i] * rb[j];
    __syncthreads();
    #pragma unroll
    for (int i = 0; i < 4; ++i)
        *reinterpret_cast<float4*>(&Xs[n0 + i][o0]) = make_float4(acc[i][0], acc[i][1], acc[i][2], acc[i][3]);
    float acc2[4][4] = {};
    const float* W2 = gateW + (size_t)v * DD * DD;
    for (int half = 0; half < 2; ++half) {
        __syncthreads();
        stage_w_f32<132, 256>(&Ws[0][0], W2 + half * 64 * DD, tid);
        __syncthreads();
        gemm16<128, 132>(acc2, &Xs[0][0], &Ws[0][0], n0, o0, half * 64);
    }
    float gb[4];
    #pragma unroll
    for (int j = 0; j < 4; ++j) gb[j] = gateb[v * DD + o0 + j];
    #pragma unroll
    for (int i = 0; i < 4; ++i) {
        float g0 = 1.f / (1.f + expf(-(acc2[i][0] + gb[0])));
        float g1 = 1.f / (1.f + expf(-(acc2[i][1] + gb[1])));
        float g2 = 1.f / (1.f + expf(-(acc2[i][2] + gb[2])));
        float g3 = 1.f / (1.f + expf(-(acc2[i][3] + gb[3])));
        ushort4 r;
        r.x = f2bf(g0 * acc[i][0]); r.y = f2bf(g1 * acc[i][1]);
        r.z = f2bf(g2 * acc[i][2]); r.w = f2bf(g3 * acc[i][3]);
        *reinterpret_cast<ushort4*>(base + (size_t)(n0 + i) * DD + o0) = r;
    }
}

// ---------------- view attention scores: vscores[v][n] ----
__global__ __launch_bounds__(128) void vatt_kernel(
        const u16* __restrict__ aggB, const float* __restrict__ view_pref,
        const float* __restrict__ vattW1, const float* __restrict__ vattb1,
        const float* __restrict__ vattW2, const float* __restrict__ vattb2,
        float* __restrict__ vscores) {
    __shared__ float Xs[32][132];
    __shared__ float Ws[128][68];
    int tid = threadIdx.x;
    int v = blockIdx.y;
    int row0 = blockIdx.x * 32;
    const u16* base = aggB + ((size_t)v * NN + row0) * DD;
    #pragma unroll
    for (int rep = 0; rep < 4; ++rep) {
        int flat = rep * 128 + tid;        // 0..511 uint4 chunks of 8 bf16
        int n = flat >> 4, c8 = flat & 15;
        uint4 q = *reinterpret_cast<const uint4*>(base + (size_t)n * DD + c8 * 8);
        float4 pa = *reinterpret_cast<const float4*>(view_pref + v * DD + c8 * 8);
        float4 pb = *reinterpret_cast<const float4*>(view_pref + v * DD + c8 * 8 + 4);
        float* d = &Xs[n][c8 * 8];
        d[0] = bf2f((u16)(q.x & 0xffffu)) * pa.x; d[1] = bf2f((u16)(q.x >> 16)) * pa.y;
        d[2] = bf2f((u16)(q.y & 0xffffu)) * pa.z; d[3] = bf2f((u16)(q.y >> 16)) * pa.w;
        d[4] = bf2f((u16)(q.z & 0xffffu)) * pb.x; d[5] = bf2f((u16)(q.z >> 16)) * pb.y;
        d[6] = bf2f((u16)(q.w & 0xffffu)) * pb.z; d[7] = bf2f((u16)(q.w >> 16)) * pb.w;
    }
    #pragma unroll
    for (int rep = 0; rep < 16; ++rep) {
        int flat = rep * 128 + tid;     // 0..2047 float4 chunks
        int k = flat >> 4, c4 = flat & 15;
        float4 q = *reinterpret_cast<const float4*>(vattW1 + k * 64 + c4 * 4);
        *reinterpret_cast<float4*>(&Ws[k][c4 * 4]) = q;
    }
    __syncthreads();
    int to = tid & 15, tn = tid >> 4;    // o0 in [0,64), n0 in [0,32)
    int o0 = to * 4, n0 = tn * 4;
    float acc[4][4] = {};
    gemm16<132, 68>(acc, &Xs[0][0], &Ws[0][0], n0, o0, 0);
    gemm16<132, 68>(acc, &Xs[0][0], &Ws[64][0], n0, o0, 64);
    float b1[4], w2[4];
    #pragma unroll
    for (int j = 0; j < 4; ++j) {
        b1[j] = vattb1[o0 + j];
        w2[j] = vattW2[o0 + j];
    }
    float part[4];
    #pragma unroll
    for (int i = 0; i < 4; ++i) {
        float s = 0.f;
        #pragma unroll
        for (int j = 0; j < 4; ++j) {
            float hv = acc[i][j] + b1[j];
            hv = hv > 0.f ? hv : 0.f;
            s += hv * w2[j];
        }
        part[i] = s;
    }
    __syncthreads();
    float* red = &Ws[0][0];   // [32][17]
    #pragma unroll
    for (int i = 0; i < 4; ++i) red[(n0 + i) * 17 + to] = part[i];
    __syncthreads();
    if (tid < 32) {
        float s = 0.f;
        for (int u = 0; u < 16; ++u) s += red[tid * 17 + u];
        vscores[(size_t)v * NN + row0 + tid] = s + vattb2[0];
    }
}

// ---------------- combine: weighted = node_att * sum_v softmax_v(vsc) * view_out (into aggB[0]) ----
__global__ __launch_bounds__(256) void combine_kernel(
        u16* __restrict__ aggB, const float* __restrict__ vscores,
        const float* __restrict__ node_att) {
    int t = blockIdx.x * 256 + threadIdx.x;   // < 3.2M
    int n = t >> 5, c4 = t & 31;
    float s0 = vscores[n], s1 = vscores[NN + n], s2 = vscores[2 * NN + n];
    float m = fmaxf(s0, fmaxf(s1, s2));
    float e0 = expf(s0 - m), e1 = expf(s1 - m), e2 = expf(s2 - m);
    float inv = 1.f / (e0 + e1 + e2);
    float w0 = e0 * inv, w1 = e1 * inv, w2 = e2 * inv;
    float na = node_att[n];
    size_t off = (size_t)n * DD + c4 * 4;
    ushort4 q0 = *reinterpret_cast<const ushort4*>(aggB + off);
    ushort4 q1 = *reinterpret_cast<const ushort4*>(aggB + (size_t)NN * DD + off);
    ushort4 q2 = *reinterpret_cast<const ushort4*>(aggB + 2 * (size_t)NN * DD + off);
    ushort4 r;
    r.x = f2bf((bf2f(q0.x) * w0 + bf2f(q1.x) * w1 + bf2f(q2.x) * w2) * na);
    r.y = f2bf((bf2f(q0.y) * w0 + bf2f(q1.y) * w1 + bf2f(q2.y) * w2) * na);
    r.z = f2bf((bf2f(q0.z) * w0 + bf2f(q1.z) * w1 + bf2f(q2.z) * w2) * na);
    r.w = f2bf((bf2f(q0.w) * w0 + bf2f(q1.w) * w1 + bf2f(q2.w) * w2) * na);
    *reinterpret_cast<ushort4*>(aggB + off) = r;
}

// ---------------- final: fused = relu(feat@Wsf + weighted@fusW_bot + c1); out = LN(fused + feat@featW + featb) ----
__global__ __launch_bounds__(256) void final_kernel(
        const float* __restrict__ feat, const u16* __restrict__ weightedB,
        const float* __restrict__ Wsf, const float* __restrict__ c1,
        const float* __restrict__ fusW, const float* __restrict__ featW,
        const float* __restrict__ featb, const float* __restrict__ ln_g,
        const float* __restrict__ ln_b, float* __restrict__ outp) {
    __shared__ float Xs[32][128];
    __shared__ float Ws[64][128];
    int tid = threadIdx.x;
    int row0 = blockIdx.x * 32;
    stage_x_f32<128, 256>(&Xs[0][0], feat + (size_t)row0 * DD, tid);
    int to = tid & 31, tn = tid >> 5;
    int o0 = to * 4, n0 = tn * 4;
    float acc1[4][4] = {}, acc2[4][4] = {};
    for (int half = 0; half < 2; ++half) {
        __syncthreads();
        stage_w_f32<128, 256>(&Ws[0][0], Wsf + half * 64 * 128, tid);
        __syncthreads();
        gemm16<128, 128>(acc1, &Xs[0][0], &Ws[0][0], n0, o0, half * 64);
    }
    for (int half = 0; half < 2; ++half) {
        __syncthreads();
        stage_w_f32<128, 256>(&Ws[0][0], featW + half * 64 * 128, tid);
        __syncthreads();
        gemm16<128, 128>(acc2, &Xs[0][0], &Ws[0][0], n0, o0, half * 64);
    }
    __syncthreads();   // all reads of Xs(feat) done; reuse for weighted
    stage_x_bf16<128, 256>(&Xs[0][0], weightedB + (size_t)row0 * DD, tid);
    for (int half = 0; half < 2; ++half) {
        __syncthreads();
        stage_w_f32<128, 256>(&Ws[0][0], fusW + (size_t)(128 + half * 64) * 128, tid);
        __syncthreads();
        gemm16<128, 128>(acc1, &Xs[0][0], &Ws[0][0], n0, o0, half * 64);
    }
    float c1j[4], fbj[4], gj[4], bj[4];
    #pragma unroll
    for (int j = 0; j < 4; ++j) {
        c1j[j] = c1[o0 + j];
        fbj[j] = featb[o0 + j];
        gj[j]  = ln_g[o0 + j];
        bj[j]  = ln_b[o0 + j];
    }
    float val[4][4];
    #pragma unroll
    for (int i = 0; i < 4; ++i)
        #pragma unroll
        for (int j = 0; j < 4; ++j) {
            float f = acc1[i][j] + c1j[j];
            f = f > 0.f ? f : 0.f;
            val[i][j] = f + acc2[i][j] + fbj[j];
        }
    __syncthreads();
    float* red_s = &Ws[0][0];            // [32][33]
    float* red_q = red_s + 32 * 33;      // [32][33]
    float* mus   = red_q + 32 * 33;      // [32]
    float* rss   = mus + 32;             // [32]
    #pragma unroll
    for (int i = 0; i < 4; ++i) {
        float s = 0.f, q = 0.f;
        #pragma unroll
        for (int j = 0; j < 4; ++j) { s += val[i][j]; q += val[i][j] * val[i][j]; }
        red_s[(n0 + i) * 33 + to] = s;
        red_q[(n0 + i) * 33 + to] = q;
    }
    __syncthreads();
    if (tid < 32) {
        float s = 0.f, q = 0.f;
        for (int u = 0; u < 32; ++u) { s += red_s[tid * 33 + u]; q += red_q[tid * 33 + u]; }
        float mu = s / 128.f;
        float var = q / 128.f - mu * mu;
        mus[tid] = mu;
        rss[tid] = rsqrtf(var + 1e-5f);
    }
    __syncthreads();
    #pragma unroll
    for (int i = 0; i < 4; ++i) {
        float mu = mus[n0 + i], rs = rss[n0 + i];
        float4 o;
        o.x = (val[i][0] - mu) * rs * gj[0] + bj[0];
        o.y = (val[i][1] - mu) * rs * gj[1] + bj[1];
        o.z = (val[i][2] - mu) * rs * gj[2] + bj[2];
        o.w = (val[i][3] - mu) * rs * gj[3] + bj[3];
        *reinterpret_cast<float4*>(outp + (size_t)(row0 + n0 + i) * DD + o0) = o;
    }
}

extern "C" void kernel_launch(void* const* d_in, const int* in_sizes, int n_in,
                              void* d_out, int out_size, void* d_ws, size_t ws_size,
                              hipStream_t stream) {
    (void)in_sizes; (void)n_in; (void)out_size;
    const float* feat      = (const float*)d_in[0];
    const int*   esrc      = (const int*)d_in[1];
    const int*   edst      = (const int*)d_in[2];
    const float* ew        = (const float*)d_in[3];
    const float* clsW      = (const float*)d_in[4];
    const float* clsb      = (const float*)d_in[5];
    const float* attW1     = (const float*)d_in[6];
    const float* attb1     = (const float*)d_in[7];
    const float* attW2     = (const float*)d_in[8];
    const float* attb2     = (const float*)d_in[9];
    const float* att_bias  = (const float*)d_in[10];
    const float* relW      = (const float*)d_in[11];
    const float* relb      = (const float*)d_in[12];
    const float* gateW     = (const float*)d_in[13];
    const float* gateb     = (const float*)d_in[14];
    const float* view_pref = (const float*)d_in[15];
    const float* vattW1    = (const float*)d_in[16];
    const float* vattb1    = (const float*)d_in[17];
    const float* vattW2    = (const float*)d_in[18];
    const float* vattb2    = (const float*)d_in[19];
    const float* selfW     = (const float*)d_in[20];
    const float* selfb     = (const float*)d_in[21];
    const float* featW     = (const float*)d_in[22];
    const float* featb     = (const float*)d_in[23];
    const float* fusW      = (const float*)d_in[24];
    const float* fusb      = (const float*)d_in[25];
    const float* ln_g      = (const float*)d_in[26];
    const float* ln_b      = (const float*)d_in[27];

    // workspace layout:
    u16*   aggB = (u16*)d_ws;                                   // [3][N][128] bf16  (76.8MB)
    float* wsum = (float*)(aggB + (size_t)VV * NN * DD);        // [3][N] fp32
    float* natt = wsum + (size_t)VV * NN;                       // [N]
    float* vsc  = natt + NN;                                    // [3][N]
    float* Wsf  = vsc + (size_t)VV * NN;                        // [128][128] fp32
    float* c1   = Wsf + DD * DD;                                // [128]
    int*   C    = (int*)(c1 + DD);                              // [3N] csr offsets
    int*   bucket = C + (size_t)VV * NN;                        // [3E] edge ids (6MB)
    size_t needed = (size_t)(bucket + (size_t)VV * EE - (int*)d_ws) * sizeof(int) / 1; // bytes via ptr diff
    needed = (size_t)((char*)(bucket + (size_t)VV * EE) - (char*)d_ws);

    float* outp  = (float*)d_out;
    float* probs = outp + (size_t)NN * DD;

    prep_kernel<<<129, 128, 0, stream>>>(selfW, selfb, fusW, fusb, Wsf, c1);
    label_kernel<<<3125, 256, 0, stream>>>(feat, clsW, clsb, attW1, attb1, attW2, attb2,
                                           att_bias, natt, probs);
    if (ws_size >= needed) {
        // CSR build + gather (no data atomics)
        hipMemsetAsync(C, 0, (size_t)VV * NN * sizeof(int), stream);
        count_kernel<<<(VV * EE + 255) / 256, 256, 0, stream>>>(edst, C);
        scan_kernel<<<1, 1024, 0, stream>>>(C);
        fill_kernel<<<(VV * EE + 255) / 256, 256, 0, stream>>>(edst, C, bucket);
        gather_kernel<<<(VV * NN) / 4, 256, 0, stream>>>(esrc, ew, feat, C, bucket,
                                                         aggB, wsum);
    } else {
        // fallback: atomic scatter (R3 path)
        hipMemsetAsync(d_ws, 0,
                       (size_t)VV * NN * DD * sizeof(u16) + (size_t)VV * NN * sizeof(float),
                       stream);
        scatter_kernel<<<187500, 256, 0, stream>>>(esrc, edst, ew, feat, aggB, wsum);
    }
    relgate_kernel<<<dim3(3125, 3), 256, 0, stream>>>(relW, relb, gateW, gateb, aggB, wsum);
    vatt_kernel<<<dim3(3125, 3), 128, 0, stream>>>(aggB, view_pref, vattW1, vattb1,
                                                   vattW2, vattb2, vsc);
    combine_kernel<<<12500, 256, 0, stream>>>(aggB, vsc, natt);
    final_kernel<<<3125, 256, 0, stream>>>(feat, aggB, Wsf, c1, fusW, featW, featb,
                                           ln_g, ln_b, outp);
}

// Round 5
// 1120.933 us; speedup vs baseline: 1.4859x; 1.4859x over previous
//
#include <hip/hip_runtime.h>
#include <hip/hip_bf16.h>

#define NN 100000
#define DD 128
#define VV 3
#define EE 500000
#define TOT (VV * NN)                 // 300000 rows
#define NB ((TOT + 255) / 256)        // 1172 scan blocks

typedef unsigned short u16;
typedef unsigned int u32;

__device__ __forceinline__ float bf2f(u16 u) {
    return __uint_as_float(((u32)u) << 16);
}
__device__ __forceinline__ u16 f2bf(float f) {
    u32 x = __float_as_uint(f);
    u32 r = (x + 0x7fffu + ((x >> 16) & 1u)) >> 16;
    return (u16)r;
}

// packed bf16 atomic add (fallback path only)
__device__ __forceinline__ void atomAddBf16x2(u16* addr, float f0, float f1) {
#if __has_builtin(__builtin_amdgcn_global_atomic_fadd_v2bf16)
    typedef short v2s __attribute__((ext_vector_type(2)));
    typedef v2s __attribute__((address_space(1)))* v2s_gp;
    v2s v;
    v.x = (short)f2bf(f0);
    v.y = (short)f2bf(f1);
    __builtin_amdgcn_global_atomic_fadd_v2bf16((v2s_gp)(void*)addr, v);
#else
    u32* p = (u32*)addr;
    u32 old = *(volatile u32*)p;
    while (true) {
        float lo = bf2f((u16)(old & 0xffffu)) + f0;
        float hi = bf2f((u16)(old >> 16)) + f1;
        u32 nv = (u32)f2bf(lo) | ((u32)f2bf(hi) << 16);
        u32 prev = atomicCAS(p, old, nv);
        if (prev == old) break;
        old = prev;
    }
#endif
}

// ---- generic GEMM accumulate: acc[4][4] += X[32 rows][K] * W[64 krows][BN] ----
template<int XSTR, int WSTR>
__device__ __forceinline__ void gemm16(float acc[4][4], const float* Xs,
                                       const float* Ws, int n0, int o0, int kbase) {
    #pragma unroll 4
    for (int kk = 0; kk < 64; kk += 4) {
        float4 w0 = *reinterpret_cast<const float4*>(Ws + (kk + 0) * WSTR + o0);
        float4 w1 = *reinterpret_cast<const float4*>(Ws + (kk + 1) * WSTR + o0);
        float4 w2 = *reinterpret_cast<const float4*>(Ws + (kk + 2) * WSTR + o0);
        float4 w3 = *reinterpret_cast<const float4*>(Ws + (kk + 3) * WSTR + o0);
        #pragma unroll
        for (int i = 0; i < 4; ++i) {
            float4 x = *reinterpret_cast<const float4*>(Xs + (n0 + i) * XSTR + kbase + kk);
            acc[i][0] = fmaf(x.x, w0.x, fmaf(x.y, w1.x, fmaf(x.z, w2.x, fmaf(x.w, w3.x, acc[i][0]))));
            acc[i][1] = fmaf(x.x, w0.y, fmaf(x.y, w1.y, fmaf(x.z, w2.y, fmaf(x.w, w3.y, acc[i][1]))));
            acc[i][2] = fmaf(x.x, w0.z, fmaf(x.y, w1.z, fmaf(x.z, w2.z, fmaf(x.w, w3.z, acc[i][2]))));
            acc[i][3] = fmaf(x.x, w0.w, fmaf(x.y, w1.w, fmaf(x.z, w2.w, fmaf(x.w, w3.w, acc[i][3]))));
        }
    }
}

template<int WSTR, int NT>
__device__ __forceinline__ void stage_w_f32(float* Ws, const float* __restrict__ src, int tid) {
    #pragma unroll
    for (int rep = 0; rep < 2048 / NT; ++rep) {
        int flat = rep * NT + tid;
        int kk = flat >> 5;
        int c4 = flat & 31;
        float4 q = *reinterpret_cast<const float4*>(src + kk * 128 + c4 * 4);
        *reinterpret_cast<float4*>(Ws + kk * WSTR + c4 * 4) = q;
    }
}

template<int XSTR, int NT>
__device__ __forceinline__ void stage_x_f32(float* Xs, const float* __restrict__ src, int tid) {
    #pragma unroll
    for (int rep = 0; rep < 1024 / NT; ++rep) {
        int flat = rep * NT + tid;
        int n = flat >> 5;
        int c4 = flat & 31;
        float4 q = *reinterpret_cast<const float4*>(src + (size_t)n * 128 + c4 * 4);
        *reinterpret_cast<float4*>(Xs + n * XSTR + c4 * 4) = q;
    }
}

template<int XSTR, int NT>
__device__ __forceinline__ void stage_x_bf16(float* Xs, const u16* __restrict__ src, int tid) {
    #pragma unroll
    for (int rep = 0; rep < 512 / NT; ++rep) {
        int flat = rep * NT + tid;
        int n = flat >> 4;
        int c8 = flat & 15;
        uint4 q = *reinterpret_cast<const uint4*>(src + (size_t)n * 128 + c8 * 8);
        float* d = Xs + n * XSTR + c8 * 8;
        d[0] = bf2f((u16)(q.x & 0xffffu)); d[1] = bf2f((u16)(q.x >> 16));
        d[2] = bf2f((u16)(q.y & 0xffffu)); d[3] = bf2f((u16)(q.y >> 16));
        d[4] = bf2f((u16)(q.z & 0xffffu)); d[5] = bf2f((u16)(q.z >> 16));
        d[6] = bf2f((u16)(q.w & 0xffffu)); d[7] = bf2f((u16)(q.w >> 16));
    }
}

// ---------------- prep: Wsf = selfW @ fusW_top ; c1 = selfb @ fusW_top + fusb ----
__global__ void prep_kernel(const float* __restrict__ selfW, const float* __restrict__ selfb,
                            const float* __restrict__ fusW, const float* __restrict__ fusb,
                            float* __restrict__ Wsf, float* __restrict__ c1) {
    int o = threadIdx.x;
    int k = blockIdx.x;
    if (k < 128) {
        float acc = 0.f;
        for (int m = 0; m < 128; ++m)
            acc += selfW[k * 128 + m] * fusW[m * 128 + o];
        Wsf[k * 128 + o] = acc;
    } else {
        float acc = 0.f;
        for (int m = 0; m < 128; ++m)
            acc += selfb[m] * fusW[m * 128 + o];
        c1[o] = acc + fusb[o];
    }
}

// ================= CSR build (hierarchical scan) + gather =================

__global__ __launch_bounds__(256) void count_kernel(
        const int* __restrict__ edst, int* __restrict__ C) {
    int t = blockIdx.x * 256 + threadIdx.x;
    if (t >= VV * EE) return;
    int v = t / EE;
    atomicAdd(&C[v * NN + edst[t]], 1);
}

// pass B: per-block sums of C (256 elems per block) -> bs[NB]
__global__ __launch_bounds__(256) void scanA_kernel(
        const int* __restrict__ C, int* __restrict__ bs) {
    int b = blockIdx.x, t = threadIdx.x;
    int i = b * 256 + t;
    int v = (i < TOT) ? C[i] : 0;
    __shared__ int s[256];
    s[t] = v;
    __syncthreads();
    #pragma unroll
    for (int off = 128; off > 0; off >>= 1) {
        if (t < off) s[t] += s[t + off];
        __syncthreads();
    }
    if (t == 0) bs[b] = s[0];
}

// pass C: single-block exclusive scan of bs[NB] (NB=1172 <= 2048)
__global__ __launch_bounds__(1024) void scanB_kernel(int* __restrict__ bs) {
    __shared__ int s[2048];
    int t = threadIdx.x;
    int v0 = (t < NB) ? bs[t] : 0;
    int v1 = (t + 1024 < NB) ? bs[t + 1024] : 0;
    s[t] = v0; s[t + 1024] = v1;
    __syncthreads();
    #pragma unroll
    for (int off = 1; off < 2048; off <<= 1) {
        int x0 = (t >= off) ? s[t - off] : 0;
        int x1 = (t + 1024 >= off) ? s[t + 1024 - off] : 0;
        __syncthreads();
        s[t] += x0; s[t + 1024] += x1;
        __syncthreads();
    }
    if (t < NB) bs[t] = s[t] - v0;                    // exclusive
    if (t + 1024 < NB) bs[t + 1024] = s[t + 1024] - v1;
}

// pass D: per-block exclusive scan + base -> C[i] = global exclusive offset
__global__ __launch_bounds__(256) void scanC_kernel(
        int* __restrict__ C, const int* __restrict__ bs) {
    int b = blockIdx.x, t = threadIdx.x;
    int i = b * 256 + t;
    int v = (i < TOT) ? C[i] : 0;
    __shared__ int s[256];
    s[t] = v;
    __syncthreads();
    #pragma unroll
    for (int off = 1; off < 256; off <<= 1) {
        int x = (t >= off) ? s[t - off] : 0;
        __syncthreads();
        s[t] += x;
        __syncthreads();
    }
    if (i < TOT) C[i] = s[t] - v + bs[b];
}

// fill: materialize (src, w) per bucket slot; C becomes inclusive row ends
__global__ __launch_bounds__(256) void fill_kernel(
        const int* __restrict__ esrc, const int* __restrict__ edst,
        const float* __restrict__ ew, int* __restrict__ C,
        int* __restrict__ bsrc, float* __restrict__ bw) {
    int t = blockIdx.x * 256 + threadIdx.x;
    if (t >= VV * EE) return;
    int v = t / EE;
    int pos = atomicAdd(&C[v * NN + edst[t]], 1);
    bsrc[pos] = esrc[t];
    bw[pos] = ew[t];
}

// one wave per (v,dst) row: agg[row] = sum_e w_e * feat[src_e], wsum[row] = sum_e w_e
__global__ __launch_bounds__(256) void gather_kernel(
        const float* __restrict__ feat, const int* __restrict__ C,
        const int* __restrict__ bsrc, const float* __restrict__ bw,
        u16* __restrict__ aggB, float* __restrict__ wsum) {
    int wid = (blockIdx.x * 256 + threadIdx.x) >> 6;   // row id in [0, 3N)
    int lane = threadIdx.x & 63;
    int end = C[wid];
    int start = (wid == 0) ? 0 : C[wid - 1];
    float a0 = 0.f, a1 = 0.f, wacc = 0.f;
    for (int e = start; e < end; ++e) {
        int src = bsrc[e];
        float w = bw[e];
        float2 f = *reinterpret_cast<const float2*>(feat + (size_t)src * DD + lane * 2);
        a0 = fmaf(w, f.x, a0);
        a1 = fmaf(w, f.y, a1);
        wacc += w;
    }
    u32 packed = (u32)f2bf(a0) | ((u32)f2bf(a1) << 16);
    *reinterpret_cast<u32*>(aggB + (size_t)wid * DD + lane * 2) = packed;
    if (lane == 0) wsum[wid] = wacc;
}

// ================= fallback: atomic scatter (R3 path) =================
__global__ __launch_bounds__(256) void scatter_kernel(
        const int* __restrict__ esrc, const int* __restrict__ edst,
        const float* __restrict__ ew, const float* __restrict__ feat,
        u16* __restrict__ aggB, float* __restrict__ wsum) {
    long long t = (long long)blockIdx.x * 256 + threadIdx.x;
    int lane = (int)(t & 31);
    int eg = (int)(t >> 5);
    int v = eg / EE;
    int src = 0, dst = 0; float w = 0.f;
    if (lane == 0) {
        src = esrc[eg]; dst = edst[eg]; w = ew[eg];
    }
    src = __shfl(src, 0, 32);
    dst = __shfl(dst, 0, 32);
    w   = __shfl(w, 0, 32);
    const float* fr = feat + (size_t)src * DD + lane * 4;
    float4 q = *reinterpret_cast<const float4*>(fr);
    u16* outp = aggB + ((size_t)v * NN + dst) * DD + lane * 4;
    atomAddBf16x2(outp,     w * q.x, w * q.y);
    atomAddBf16x2(outp + 2, w * q.z, w * q.w);
    if (lane == 0) atomicAdd(wsum + v * NN + dst, w);
}

// ---------------- label-aware attention ----
__global__ __launch_bounds__(256) void label_kernel(
        const float* __restrict__ feat, const float* __restrict__ clsW, const float* __restrict__ clsb,
        const float* __restrict__ attW1, const float* __restrict__ attb1,
        const float* __restrict__ attW2, const float* __restrict__ attb2,
        const float* __restrict__ att_bias,
        float* __restrict__ node_att, float* __restrict__ probs_out) {
    __shared__ float Xs[32][132];
    __shared__ float Ws[64][132];
    int tid = threadIdx.x;
    int row0 = blockIdx.x * 32;
    stage_x_f32<132, 256>(&Xs[0][0], feat + (size_t)row0 * DD, tid);
    int to = tid & 31, tn = tid >> 5;
    int o0 = to * 4, n0 = tn * 4;
    float acc[4][4] = {};
    for (int half = 0; half < 2; ++half) {
        __syncthreads();
        #pragma unroll
        for (int rep = 0; rep < 8; ++rep) {
            int flat = rep * 256 + tid;
            int kk = flat >> 5, o4 = flat & 31;
            int o = o4 * 4;
            int c = o >> 6, h = o & 63;
            int k = half * 64 + kk;
            float4 q = *reinterpret_cast<const float4*>(attW1 + (size_t)(c * 128 + k) * 64 + h);
            *reinterpret_cast<float4*>(&Ws[kk][o]) = q;
        }
        __syncthreads();
        gemm16<132, 132>(acc, &Xs[0][0], &Ws[0][0], n0, o0, half * 64);
    }
    int c = o0 >> 6, h0 = o0 & 63;
    float b1j[4], w2j[4];
    #pragma unroll
    for (int j = 0; j < 4; ++j) {
        b1j[j] = attb1[c * 64 + h0 + j];
        w2j[j] = attW2[c * 64 + h0 + j];
    }
    float part[4];
    #pragma unroll
    for (int i = 0; i < 4; ++i) {
        float s = 0.f;
        #pragma unroll
        for (int j = 0; j < 4; ++j) {
            float hv = acc[i][j] + b1j[j];
            hv = hv > 0.f ? hv : 0.f;
            s += hv * w2j[j];
        }
        part[i] = s;
    }
    __syncthreads();
    float* red = &Ws[0][0];          // [32][33]
    float* Ssc = red + 32 * 33;      // [32][2]
    float* Lsc = Ssc + 64;           // [32][2]
    #pragma unroll
    for (int i = 0; i < 4; ++i) red[(n0 + i) * 33 + to] = part[i];
    __syncthreads();
    if (tid < 64) {
        int n = tid >> 1, cc = tid & 1;
        float l = 0.f;
        for (int k = 0; k < 128; k += 4) {
            float4 x = *reinterpret_cast<const float4*>(&Xs[n][k]);
            l += x.x * clsW[(k + 0) * 2 + cc];
            l += x.y * clsW[(k + 1) * 2 + cc];
            l += x.z * clsW[(k + 2) * 2 + cc];
            l += x.w * clsW[(k + 3) * 2 + cc];
        }
        Lsc[n * 2 + cc] = l + clsb[cc];
        float s = 0.f;
        for (int u = 0; u < 16; ++u) s += red[n * 33 + cc * 16 + u];
        s += attb2[cc];
        Ssc[n * 2 + cc] = 1.f / (1.f + expf(-s));
    }
    __syncthreads();
    if (tid < 32) {
        int n = tid;
        float l0 = Lsc[n * 2], l1 = Lsc[n * 2 + 1];
        float m = fmaxf(l0, l1);
        float e0 = expf(l0 - m), e1 = expf(l1 - m);
        float inv = 1.f / (e0 + e1);
        float p0 = e0 * inv, p1 = e1 * inv;
        float na = p0 * Ssc[n * 2] + p1 * Ssc[n * 2 + 1] + att_bias[0];
        int row = row0 + n;
        node_att[row] = na;
        probs_out[row * 2]     = p0;
        probs_out[row * 2 + 1] = p1;
    }
}

// ---------------- per-view: agg = aggB@relW + wsum*relb ; view_out = sigmoid(agg@gateW+gb)*agg ----
__global__ __launch_bounds__(256) void relgate_kernel(
        const float* __restrict__ relW, const float* __restrict__ relb,
        const float* __restrict__ gateW, const float* __restrict__ gateb,
        u16* __restrict__ aggB, const float* __restrict__ wsum) {
    __shared__ float Xs[32][128];
    __shared__ float Ws[64][132];
    int tid = threadIdx.x;
    int v = blockIdx.y;
    int row0 = blockIdx.x * 32;
    u16* base = aggB + ((size_t)v * NN + row0) * DD;
    stage_x_bf16<128, 256>(&Xs[0][0], base, tid);
    int to = tid & 31, tn = tid >> 5;
    int o0 = to * 4, n0 = tn * 4;
    float acc[4][4] = {};
    const float* W1 = relW + (size_t)v * DD * DD;
    for (int half = 0; half < 2; ++half) {
        __syncthreads();
        stage_w_f32<132, 256>(&Ws[0][0], W1 + half * 64 * DD, tid);
        __syncthreads();
        gemm16<128, 132>(acc, &Xs[0][0], &Ws[0][0], n0, o0, half * 64);
    }
    float wsn[4], rb[4];
    #pragma unroll
    for (int i = 0; i < 4; ++i) wsn[i] = wsum[v * NN + row0 + n0 + i];
    #pragma unroll
    for (int j = 0; j < 4; ++j) rb[j] = relb[v * DD + o0 + j];
    #pragma unroll
    for (int i = 0; i < 4; ++i)
        #pragma unroll
        for (int j = 0; j < 4; ++j) acc[i][j] += wsn[i] * rb[j];
    __syncthreads();
    #pragma unroll
    for (int i = 0; i < 4; ++i)
        *reinterpret_cast<float4*>(&Xs[n0 + i][o0]) = make_float4(acc[i][0], acc[i][1], acc[i][2], acc[i][3]);
    float acc2[4][4] = {};
    const float* W2 = gateW + (size_t)v * DD * DD;
    for (int half = 0; half < 2; ++half) {
        __syncthreads();
        stage_w_f32<132, 256>(&Ws[0][0], W2 + half * 64 * DD, tid);
        __syncthreads();
        gemm16<128, 132>(acc2, &Xs[0][0], &Ws[0][0], n0, o0, half * 64);
    }
    float gb[4];
    #pragma unroll
    for (int j = 0; j < 4; ++j) gb[j] = gateb[v * DD + o0 + j];
    #pragma unroll
    for (int i = 0; i < 4; ++i) {
        float g0 = 1.f / (1.f + expf(-(acc2[i][0] + gb[0])));
        float g1 = 1.f / (1.f + expf(-(acc2[i][1] + gb[1])));
        float g2 = 1.f / (1.f + expf(-(acc2[i][2] + gb[2])));
        float g3 = 1.f / (1.f + expf(-(acc2[i][3] + gb[3])));
        ushort4 r;
        r.x = f2bf(g0 * acc[i][0]); r.y = f2bf(g1 * acc[i][1]);
        r.z = f2bf(g2 * acc[i][2]); r.w = f2bf(g3 * acc[i][3]);
        *reinterpret_cast<ushort4*>(base + (size_t)(n0 + i) * DD + o0) = r;
    }
}

// ---------------- view attention scores ----
__global__ __launch_bounds__(128) void vatt_kernel(
        const u16* __restrict__ aggB, const float* __restrict__ view_pref,
        const float* __restrict__ vattW1, const float* __restrict__ vattb1,
        const float* __restrict__ vattW2, const float* __restrict__ vattb2,
        float* __restrict__ vscores) {
    __shared__ float Xs[32][132];
    __shared__ float Ws[128][68];
    int tid = threadIdx.x;
    int v = blockIdx.y;
    int row0 = blockIdx.x * 32;
    const u16* base = aggB + ((size_t)v * NN + row0) * DD;
    #pragma unroll
    for (int rep = 0; rep < 4; ++rep) {
        int flat = rep * 128 + tid;
        int n = flat >> 4, c8 = flat & 15;
        uint4 q = *reinterpret_cast<const uint4*>(base + (size_t)n * DD + c8 * 8);
        float4 pa = *reinterpret_cast<const float4*>(view_pref + v * DD + c8 * 8);
        float4 pb = *reinterpret_cast<const float4*>(view_pref + v * DD + c8 * 8 + 4);
        float* d = &Xs[n][c8 * 8];
        d[0] = bf2f((u16)(q.x & 0xffffu)) * pa.x; d[1] = bf2f((u16)(q.x >> 16)) * pa.y;
        d[2] = bf2f((u16)(q.y & 0xffffu)) * pa.z; d[3] = bf2f((u16)(q.y >> 16)) * pa.w;
        d[4] = bf2f((u16)(q.z & 0xffffu)) * pb.x; d[5] = bf2f((u16)(q.z >> 16)) * pb.y;
        d[6] = bf2f((u16)(q.w & 0xffffu)) * pb.z; d[7] = bf2f((u16)(q.w >> 16)) * pb.w;
    }
    #pragma unroll
    for (int rep = 0; rep < 16; ++rep) {
        int flat = rep * 128 + tid;
        int k = flat >> 4, c4 = flat & 15;
        float4 q = *reinterpret_cast<const float4*>(vattW1 + k * 64 + c4 * 4);
        *reinterpret_cast<float4*>(&Ws[k][c4 * 4]) = q;
    }
    __syncthreads();
    int to = tid & 15, tn = tid >> 4;
    int o0 = to * 4, n0 = tn * 4;
    float acc[4][4] = {};
    gemm16<132, 68>(acc, &Xs[0][0], &Ws[0][0], n0, o0, 0);
    gemm16<132, 68>(acc, &Xs[0][0], &Ws[64][0], n0, o0, 64);
    float b1[4], w2[4];
    #pragma unroll
    for (int j = 0; j < 4; ++j) {
        b1[j] = vattb1[o0 + j];
        w2[j] = vattW2[o0 + j];
    }
    float part[4];
    #pragma unroll
    for (int i = 0; i < 4; ++i) {
        float s = 0.f;
        #pragma unroll
        for (int j = 0; j < 4; ++j) {
            float hv = acc[i][j] + b1[j];
            hv = hv > 0.f ? hv : 0.f;
            s += hv * w2[j];
        }
        part[i] = s;
    }
    __syncthreads();
    float* red = &Ws[0][0];   // [32][17]
    #pragma unroll
    for (int i = 0; i < 4; ++i) red[(n0 + i) * 17 + to] = part[i];
    __syncthreads();
    if (tid < 32) {
        float s = 0.f;
        for (int u = 0; u < 16; ++u) s += red[tid * 17 + u];
        vscores[(size_t)v * NN + row0 + tid] = s + vattb2[0];
    }
}

// ---------------- combine ----
__global__ __launch_bounds__(256) void combine_kernel(
        u16* __restrict__ aggB, const float* __restrict__ vscores,
        const float* __restrict__ node_att) {
    int t = blockIdx.x * 256 + threadIdx.x;
    int n = t >> 5, c4 = t & 31;
    float s0 = vscores[n], s1 = vscores[NN + n], s2 = vscores[2 * NN + n];
    float m = fmaxf(s0, fmaxf(s1, s2));
    float e0 = expf(s0 - m), e1 = expf(s1 - m), e2 = expf(s2 - m);
    float inv = 1.f / (e0 + e1 + e2);
    float w0 = e0 * inv, w1 = e1 * inv, w2 = e2 * inv;
    float na = node_att[n];
    size_t off = (size_t)n * DD + c4 * 4;
    ushort4 q0 = *reinterpret_cast<const ushort4*>(aggB + off);
    ushort4 q1 = *reinterpret_cast<const ushort4*>(aggB + (size_t)NN * DD + off);
    ushort4 q2 = *reinterpret_cast<const ushort4*>(aggB + 2 * (size_t)NN * DD + off);
    ushort4 r;
    r.x = f2bf((bf2f(q0.x) * w0 + bf2f(q1.x) * w1 + bf2f(q2.x) * w2) * na);
    r.y = f2bf((bf2f(q0.y) * w0 + bf2f(q1.y) * w1 + bf2f(q2.y) * w2) * na);
    r.z = f2bf((bf2f(q0.z) * w0 + bf2f(q1.z) * w1 + bf2f(q2.z) * w2) * na);
    r.w = f2bf((bf2f(q0.w) * w0 + bf2f(q1.w) * w1 + bf2f(q2.w) * w2) * na);
    *reinterpret_cast<ushort4*>(aggB + off) = r;
}

// ---------------- final ----
__global__ __launch_bounds__(256) void final_kernel(
        const float* __restrict__ feat, const u16* __restrict__ weightedB,
        const float* __restrict__ Wsf, const float* __restrict__ c1,
        const float* __restrict__ fusW, const float* __restrict__ featW,
        const float* __restrict__ featb, const float* __restrict__ ln_g,
        const float* __restrict__ ln_b, float* __restrict__ outp) {
    __shared__ float Xs[32][128];
    __shared__ float Ws[64][128];
    int tid = threadIdx.x;
    int row0 = blockIdx.x * 32;
    stage_x_f32<128, 256>(&Xs[0][0], feat + (size_t)row0 * DD, tid);
    int to = tid & 31, tn = tid >> 5;
    int o0 = to * 4, n0 = tn * 4;
    float acc1[4][4] = {}, acc2[4][4] = {};
    for (int half = 0; half < 2; ++half) {
        __syncthreads();
        stage_w_f32<128, 256>(&Ws[0][0], Wsf + half * 64 * 128, tid);
        __syncthreads();
        gemm16<128, 128>(acc1, &Xs[0][0], &Ws[0][0], n0, o0, half * 64);
    }
    for (int half = 0; half < 2; ++half) {
        __syncthreads();
        stage_w_f32<128, 256>(&Ws[0][0], featW + half * 64 * 128, tid);
        __syncthreads();
        gemm16<128, 128>(acc2, &Xs[0][0], &Ws[0][0], n0, o0, half * 64);
    }
    __syncthreads();
    stage_x_bf16<128, 256>(&Xs[0][0], weightedB + (size_t)row0 * DD, tid);
    for (int half = 0; half < 2; ++half) {
        __syncthreads();
        stage_w_f32<128, 256>(&Ws[0][0], fusW + (size_t)(128 + half * 64) * 128, tid);
        __syncthreads();
        gemm16<128, 128>(acc1, &Xs[0][0], &Ws[0][0], n0, o0, half * 64);
    }
    float c1j[4], fbj[4], gj[4], bj[4];
    #pragma unroll
    for (int j = 0; j < 4; ++j) {
        c1j[j] = c1[o0 + j];
        fbj[j] = featb[o0 + j];
        gj[j]  = ln_g[o0 + j];
        bj[j]  = ln_b[o0 + j];
    }
    float val[4][4];
    #pragma unroll
    for (int i = 0; i < 4; ++i)
        #pragma unroll
        for (int j = 0; j < 4; ++j) {
            float f = acc1[i][j] + c1j[j];
            f = f > 0.f ? f : 0.f;
            val[i][j] = f + acc2[i][j] + fbj[j];
        }
    __syncthreads();
    float* red_s = &Ws[0][0];            // [32][33]
    float* red_q = red_s + 32 * 33;      // [32][33]
    float* mus   = red_q + 32 * 33;      // [32]
    float* rss   = mus + 32;             // [32]
    #pragma unroll
    for (int i = 0; i < 4; ++i) {
        float s = 0.f, q = 0.f;
        #pragma unroll
        for (int j = 0; j < 4; ++j) { s += val[i][j]; q += val[i][j] * val[i][j]; }
        red_s[(n0 + i) * 33 + to] = s;
        red_q[(n0 + i) * 33 + to] = q;
    }
    __syncthreads();
    if (tid < 32) {
        float s = 0.f, q = 0.f;
        for (int u = 0; u < 32; ++u) { s += red_s[tid * 33 + u]; q += red_q[tid * 33 + u]; }
        float mu = s / 128.f;
        float var = q / 128.f - mu * mu;
        mus[tid] = mu;
        rss[tid] = rsqrtf(var + 1e-5f);
    }
    __syncthreads();
    #pragma unroll
    for (int i = 0; i < 4; ++i) {
        float mu = mus[n0 + i], rs = rss[n0 + i];
        float4 o;
        o.x = (val[i][0] - mu) * rs * gj[0] + bj[0];
        o.y = (val[i][1] - mu) * rs * gj[1] + bj[1];
        o.z = (val[i][2] - mu) * rs * gj[2] + bj[2];
        o.w = (val[i][3] - mu) * rs * gj[3] + bj[3];
        *reinterpret_cast<float4*>(outp + (size_t)(row0 + n0 + i) * DD + o0) = o;
    }
}

extern "C" void kernel_launch(void* const* d_in, const int* in_sizes, int n_in,
                              void* d_out, int out_size, void* d_ws, size_t ws_size,
                              hipStream_t stream) {
    (void)in_sizes; (void)n_in; (void)out_size;
    const float* feat      = (const float*)d_in[0];
    const int*   esrc      = (const int*)d_in[1];
    const int*   edst      = (const int*)d_in[2];
    const float* ew        = (const float*)d_in[3];
    const float* clsW      = (const float*)d_in[4];
    const float* clsb      = (const float*)d_in[5];
    const float* attW1     = (const float*)d_in[6];
    const float* attb1     = (const float*)d_in[7];
    const float* attW2     = (const float*)d_in[8];
    const float* attb2     = (const float*)d_in[9];
    const float* att_bias  = (const float*)d_in[10];
    const float* relW      = (const float*)d_in[11];
    const float* relb      = (const float*)d_in[12];
    const float* gateW     = (const float*)d_in[13];
    const float* gateb     = (const float*)d_in[14];
    const float* view_pref = (const float*)d_in[15];
    const float* vattW1    = (const float*)d_in[16];
    const float* vattb1    = (const float*)d_in[17];
    const float* vattW2    = (const float*)d_in[18];
    const float* vattb2    = (const float*)d_in[19];
    const float* selfW     = (const float*)d_in[20];
    const float* selfb     = (const float*)d_in[21];
    const float* featW     = (const float*)d_in[22];
    const float* featb     = (const float*)d_in[23];
    const float* fusW      = (const float*)d_in[24];
    const float* fusb      = (const float*)d_in[25];
    const float* ln_g      = (const float*)d_in[26];
    const float* ln_b      = (const float*)d_in[27];

    // workspace layout (~93 MiB):
    u16*   aggB = (u16*)d_ws;                                   // [3][N][128] bf16  (76.8MB)
    float* wsum = (float*)(aggB + (size_t)VV * NN * DD);        // [3][N]
    float* natt = wsum + (size_t)VV * NN;                       // [N]
    float* vsc  = natt + NN;                                    // [3][N]
    float* Wsf  = vsc + (size_t)VV * NN;                        // [128][128]
    float* c1   = Wsf + DD * DD;                                // [128]
    int*   C    = (int*)(c1 + DD);                              // [3N] csr offsets
    int*   bs   = C + (size_t)TOT;                              // [NB] block sums
    int*   bsrc = bs + NB;                                      // [3E] src per slot
    float* bw   = (float*)(bsrc + (size_t)VV * EE);             // [3E] w per slot
    size_t needed = (size_t)((char*)(bw + (size_t)VV * EE) - (char*)d_ws);

    float* outp  = (float*)d_out;
    float* probs = outp + (size_t)NN * DD;

    prep_kernel<<<129, 128, 0, stream>>>(selfW, selfb, fusW, fusb, Wsf, c1);
    label_kernel<<<3125, 256, 0, stream>>>(feat, clsW, clsb, attW1, attb1, attW2, attb2,
                                           att_bias, natt, probs);
    if (ws_size >= needed) {
        hipMemsetAsync(C, 0, (size_t)TOT * sizeof(int), stream);
        count_kernel<<<(VV * EE + 255) / 256, 256, 0, stream>>>(edst, C);
        scanA_kernel<<<NB, 256, 0, stream>>>(C, bs);
        scanB_kernel<<<1, 1024, 0, stream>>>(bs);
        scanC_kernel<<<NB, 256, 0, stream>>>(C, bs);
        fill_kernel<<<(VV * EE + 255) / 256, 256, 0, stream>>>(esrc, edst, ew, C, bsrc, bw);
        gather_kernel<<<(VV * NN) / 4, 256, 0, stream>>>(feat, C, bsrc, bw, aggB, wsum);
    } else {
        hipMemsetAsync(d_ws, 0,
                       (size_t)VV * NN * DD * sizeof(u16) + (size_t)VV * NN * sizeof(float),
                       stream);
        scatter_kernel<<<187500, 256, 0, stream>>>(esrc, edst, ew, feat, aggB, wsum);
    }
    relgate_kernel<<<dim3(3125, 3), 256, 0, stream>>>(relW, relb, gateW, gateb, aggB, wsum);
    vatt_kernel<<<dim3(3125, 3), 128, 0, stream>>>(aggB, view_pref, vattW1, vattb1,
                                                   vattW2, vattb2, vsc);
    combine_kernel<<<12500, 256, 0, stream>>>(aggB, vsc, natt);
    final_kernel<<<3125, 256, 0, stream>>>(feat, aggB, Wsf, c1, fusW, featW, featb,
                                           ln_g, ln_b, outp);
}

// Round 6
// 862.350 us; speedup vs baseline: 1.9315x; 1.2999x over previous
//
#include <hip/hip_runtime.h>
#include <hip/hip_bf16.h>

#define NN 100000
#define DD 128
#define VV 3
#define EE 500000
#define TOT (VV * NN)                 // 300000 rows
#define NB ((TOT + 255) / 256)        // 1172 scan blocks
#define RGB ((NN + 127) / 128)        // 782 mfma-relgate blocks per view

typedef unsigned short u16;
typedef unsigned int u32;
typedef short s8v __attribute__((ext_vector_type(8)));   // 8 bf16 (4 VGPRs)
typedef float f4v __attribute__((ext_vector_type(4)));   // MFMA accumulator

__device__ __forceinline__ float bf2f(u16 u) {
    return __uint_as_float(((u32)u) << 16);
}
__device__ __forceinline__ u16 f2bf(float f) {
    u32 x = __float_as_uint(f);
    u32 r = (x + 0x7fffu + ((x >> 16) & 1u)) >> 16;
    return (u16)r;
}

// packed bf16 atomic add (fallback path only)
__device__ __forceinline__ void atomAddBf16x2(u16* addr, float f0, float f1) {
#if __has_builtin(__builtin_amdgcn_global_atomic_fadd_v2bf16)
    typedef short v2s __attribute__((ext_vector_type(2)));
    typedef v2s __attribute__((address_space(1)))* v2s_gp;
    v2s v;
    v.x = (short)f2bf(f0);
    v.y = (short)f2bf(f1);
    __builtin_amdgcn_global_atomic_fadd_v2bf16((v2s_gp)(void*)addr, v);
#else
    u32* p = (u32*)addr;
    u32 old = *(volatile u32*)p;
    while (true) {
        float lo = bf2f((u16)(old & 0xffffu)) + f0;
        float hi = bf2f((u16)(old >> 16)) + f1;
        u32 nv = (u32)f2bf(lo) | ((u32)f2bf(hi) << 16);
        u32 prev = atomicCAS(p, old, nv);
        if (prev == old) break;
        old = prev;
    }
#endif
}

// ---- generic VALU GEMM accumulate: acc[4][4] += X[32 rows][K] * W[64 krows][BN] ----
template<int XSTR, int WSTR>
__device__ __forceinline__ void gemm16(float acc[4][4], const float* Xs,
                                       const float* Ws, int n0, int o0, int kbase) {
    #pragma unroll 4
    for (int kk = 0; kk < 64; kk += 4) {
        float4 w0 = *reinterpret_cast<const float4*>(Ws + (kk + 0) * WSTR + o0);
        float4 w1 = *reinterpret_cast<const float4*>(Ws + (kk + 1) * WSTR + o0);
        float4 w2 = *reinterpret_cast<const float4*>(Ws + (kk + 2) * WSTR + o0);
        float4 w3 = *reinterpret_cast<const float4*>(Ws + (kk + 3) * WSTR + o0);
        #pragma unroll
        for (int i = 0; i < 4; ++i) {
            float4 x = *reinterpret_cast<const float4*>(Xs + (n0 + i) * XSTR + kbase + kk);
            acc[i][0] = fmaf(x.x, w0.x, fmaf(x.y, w1.x, fmaf(x.z, w2.x, fmaf(x.w, w3.x, acc[i][0]))));
            acc[i][1] = fmaf(x.x, w0.y, fmaf(x.y, w1.y, fmaf(x.z, w2.y, fmaf(x.w, w3.y, acc[i][1]))));
            acc[i][2] = fmaf(x.x, w0.z, fmaf(x.y, w1.z, fmaf(x.z, w2.z, fmaf(x.w, w3.z, acc[i][2]))));
            acc[i][3] = fmaf(x.x, w0.w, fmaf(x.y, w1.w, fmaf(x.z, w2.w, fmaf(x.w, w3.w, acc[i][3]))));
        }
    }
}

template<int WSTR, int NT>
__device__ __forceinline__ void stage_w_f32(float* Ws, const float* __restrict__ src, int tid) {
    #pragma unroll
    for (int rep = 0; rep < 2048 / NT; ++rep) {
        int flat = rep * NT + tid;
        int kk = flat >> 5;
        int c4 = flat & 31;
        float4 q = *reinterpret_cast<const float4*>(src + kk * 128 + c4 * 4);
        *reinterpret_cast<float4*>(Ws + kk * WSTR + c4 * 4) = q;
    }
}

template<int XSTR, int NT>
__device__ __forceinline__ void stage_x_f32(float* Xs, const float* __restrict__ src, int tid) {
    #pragma unroll
    for (int rep = 0; rep < 1024 / NT; ++rep) {
        int flat = rep * NT + tid;
        int n = flat >> 5;
        int c4 = flat & 31;
        float4 q = *reinterpret_cast<const float4*>(src + (size_t)n * 128 + c4 * 4);
        *reinterpret_cast<float4*>(Xs + n * XSTR + c4 * 4) = q;
    }
}

template<int XSTR, int NT>
__device__ __forceinline__ void stage_x_bf16(float* Xs, const u16* __restrict__ src, int tid) {
    #pragma unroll
    for (int rep = 0; rep < 512 / NT; ++rep) {
        int flat = rep * NT + tid;
        int n = flat >> 4;
        int c8 = flat & 15;
        uint4 q = *reinterpret_cast<const uint4*>(src + (size_t)n * 128 + c8 * 8);
        float* d = Xs + n * XSTR + c8 * 8;
        d[0] = bf2f((u16)(q.x & 0xffffu)); d[1] = bf2f((u16)(q.x >> 16));
        d[2] = bf2f((u16)(q.y & 0xffffu)); d[3] = bf2f((u16)(q.y >> 16));
        d[4] = bf2f((u16)(q.z & 0xffffu)); d[5] = bf2f((u16)(q.z >> 16));
        d[6] = bf2f((u16)(q.w & 0xffffu)); d[7] = bf2f((u16)(q.w >> 16));
    }
}

// ---------------- prep: Wsf = selfW @ fusW_top ; c1 = selfb @ fusW_top + fusb ----
__global__ void prep_kernel(const float* __restrict__ selfW, const float* __restrict__ selfb,
                            const float* __restrict__ fusW, const float* __restrict__ fusb,
                            float* __restrict__ Wsf, float* __restrict__ c1) {
    int o = threadIdx.x;
    int k = blockIdx.x;
    if (k < 128) {
        float acc = 0.f;
        for (int m = 0; m < 128; ++m)
            acc += selfW[k * 128 + m] * fusW[m * 128 + o];
        Wsf[k * 128 + o] = acc;
    } else {
        float acc = 0.f;
        for (int m = 0; m < 128; ++m)
            acc += selfb[m] * fusW[m * 128 + o];
        c1[o] = acc + fusb[o];
    }
}

// ---------------- wprep: transpose+convert relW/gateW -> bf16 [v][n][k] ----
__global__ __launch_bounds__(128) void wprep_kernel(
        const float* __restrict__ relW, const float* __restrict__ gateW,
        u16* __restrict__ relWb, u16* __restrict__ gateWb) {
    int k = threadIdx.x;               // 0..127
    int n = blockIdx.x & 127;
    int v = blockIdx.x >> 7;           // 0..2
    size_t o = ((size_t)v * 128 + n) * 128 + k;
    size_t i = ((size_t)v * 128 + k) * 128 + n;
    relWb[o]  = f2bf(relW[i]);
    gateWb[o] = f2bf(gateW[i]);
}

// ================= CSR build (hierarchical scan) + gather =================

__global__ __launch_bounds__(256) void count_kernel(
        const int* __restrict__ edst, int* __restrict__ C) {
    int t = blockIdx.x * 256 + threadIdx.x;
    if (t >= VV * EE) return;
    int v = t / EE;
    atomicAdd(&C[v * NN + edst[t]], 1);
}

__global__ __launch_bounds__(256) void scanA_kernel(
        const int* __restrict__ C, int* __restrict__ bs) {
    int b = blockIdx.x, t = threadIdx.x;
    int i = b * 256 + t;
    int v = (i < TOT) ? C[i] : 0;
    __shared__ int s[256];
    s[t] = v;
    __syncthreads();
    #pragma unroll
    for (int off = 128; off > 0; off >>= 1) {
        if (t < off) s[t] += s[t + off];
        __syncthreads();
    }
    if (t == 0) bs[b] = s[0];
}

__global__ __launch_bounds__(1024) void scanB_kernel(int* __restrict__ bs) {
    __shared__ int s[2048];
    int t = threadIdx.x;
    int v0 = (t < NB) ? bs[t] : 0;
    int v1 = (t + 1024 < NB) ? bs[t + 1024] : 0;
    s[t] = v0; s[t + 1024] = v1;
    __syncthreads();
    #pragma unroll
    for (int off = 1; off < 2048; off <<= 1) {
        int x0 = (t >= off) ? s[t - off] : 0;
        int x1 = (t + 1024 >= off) ? s[t + 1024 - off] : 0;
        __syncthreads();
        s[t] += x0; s[t + 1024] += x1;
        __syncthreads();
    }
    if (t < NB) bs[t] = s[t] - v0;
    if (t + 1024 < NB) bs[t + 1024] = s[t + 1024] - v1;
}

__global__ __launch_bounds__(256) void scanC_kernel(
        int* __restrict__ C, const int* __restrict__ bs) {
    int b = blockIdx.x, t = threadIdx.x;
    int i = b * 256 + t;
    int v = (i < TOT) ? C[i] : 0;
    __shared__ int s[256];
    s[t] = v;
    __syncthreads();
    #pragma unroll
    for (int off = 1; off < 256; off <<= 1) {
        int x = (t >= off) ? s[t - off] : 0;
        __syncthreads();
        s[t] += x;
        __syncthreads();
    }
    if (i < TOT) C[i] = s[t] - v + bs[b];
}

__global__ __launch_bounds__(256) void fill_kernel(
        const int* __restrict__ esrc, const int* __restrict__ edst,
        const float* __restrict__ ew, int* __restrict__ C,
        int* __restrict__ bsrc, float* __restrict__ bw) {
    int t = blockIdx.x * 256 + threadIdx.x;
    if (t >= VV * EE) return;
    int v = t / EE;
    int pos = atomicAdd(&C[v * NN + edst[t]], 1);
    bsrc[pos] = esrc[t];
    bw[pos] = ew[t];
}

__global__ __launch_bounds__(256) void gather_kernel(
        const float* __restrict__ feat, const int* __restrict__ C,
        const int* __restrict__ bsrc, const float* __restrict__ bw,
        u16* __restrict__ aggB, float* __restrict__ wsum) {
    int wid = (blockIdx.x * 256 + threadIdx.x) >> 6;
    int lane = threadIdx.x & 63;
    int end = C[wid];
    int start = (wid == 0) ? 0 : C[wid - 1];
    float a0 = 0.f, a1 = 0.f, wacc = 0.f;
    for (int e = start; e < end; ++e) {
        int src = bsrc[e];
        float w = bw[e];
        float2 f = *reinterpret_cast<const float2*>(feat + (size_t)src * DD + lane * 2);
        a0 = fmaf(w, f.x, a0);
        a1 = fmaf(w, f.y, a1);
        wacc += w;
    }
    u32 packed = (u32)f2bf(a0) | ((u32)f2bf(a1) << 16);
    *reinterpret_cast<u32*>(aggB + (size_t)wid * DD + lane * 2) = packed;
    if (lane == 0) wsum[wid] = wacc;
}

// ================= fallback: atomic scatter (R3 path) =================
__global__ __launch_bounds__(256) void scatter_kernel(
        const int* __restrict__ esrc, const int* __restrict__ edst,
        const float* __restrict__ ew, const float* __restrict__ feat,
        u16* __restrict__ aggB, float* __restrict__ wsum) {
    long long t = (long long)blockIdx.x * 256 + threadIdx.x;
    int lane = (int)(t & 31);
    int eg = (int)(t >> 5);
    int v = eg / EE;
    int src = 0, dst = 0; float w = 0.f;
    if (lane == 0) {
        src = esrc[eg]; dst = edst[eg]; w = ew[eg];
    }
    src = __shfl(src, 0, 32);
    dst = __shfl(dst, 0, 32);
    w   = __shfl(w, 0, 32);
    const float* fr = feat + (size_t)src * DD + lane * 4;
    float4 q = *reinterpret_cast<const float4*>(fr);
    u16* outp = aggB + ((size_t)v * NN + dst) * DD + lane * 4;
    atomAddBf16x2(outp,     w * q.x, w * q.y);
    atomAddBf16x2(outp + 2, w * q.z, w * q.w);
    if (lane == 0) atomicAdd(wsum + v * NN + dst, w);
}

// ---------------- label-aware attention ----
__global__ __launch_bounds__(256) void label_kernel(
        const float* __restrict__ feat, const float* __restrict__ clsW, const float* __restrict__ clsb,
        const float* __restrict__ attW1, const float* __restrict__ attb1,
        const float* __restrict__ attW2, const float* __restrict__ attb2,
        const float* __restrict__ att_bias,
        float* __restrict__ node_att, float* __restrict__ probs_out) {
    __shared__ float Xs[32][132];
    __shared__ float Ws[64][132];
    int tid = threadIdx.x;
    int row0 = blockIdx.x * 32;
    stage_x_f32<132, 256>(&Xs[0][0], feat + (size_t)row0 * DD, tid);
    int to = tid & 31, tn = tid >> 5;
    int o0 = to * 4, n0 = tn * 4;
    float acc[4][4] = {};
    for (int half = 0; half < 2; ++half) {
        __syncthreads();
        #pragma unroll
        for (int rep = 0; rep < 8; ++rep) {
            int flat = rep * 256 + tid;
            int kk = flat >> 5, o4 = flat & 31;
            int o = o4 * 4;
            int c = o >> 6, h = o & 63;
            int k = half * 64 + kk;
            float4 q = *reinterpret_cast<const float4*>(attW1 + (size_t)(c * 128 + k) * 64 + h);
            *reinterpret_cast<float4*>(&Ws[kk][o]) = q;
        }
        __syncthreads();
        gemm16<132, 132>(acc, &Xs[0][0], &Ws[0][0], n0, o0, half * 64);
    }
    int c = o0 >> 6, h0 = o0 & 63;
    float b1j[4], w2j[4];
    #pragma unroll
    for (int j = 0; j < 4; ++j) {
        b1j[j] = attb1[c * 64 + h0 + j];
        w2j[j] = attW2[c * 64 + h0 + j];
    }
    float part[4];
    #pragma unroll
    for (int i = 0; i < 4; ++i) {
        float s = 0.f;
        #pragma unroll
        for (int j = 0; j < 4; ++j) {
            float hv = acc[i][j] + b1j[j];
            hv = hv > 0.f ? hv : 0.f;
            s += hv * w2j[j];
        }
        part[i] = s;
    }
    __syncthreads();
    float* red = &Ws[0][0];          // [32][33]
    float* Ssc = red + 32 * 33;      // [32][2]
    float* Lsc = Ssc + 64;           // [32][2]
    #pragma unroll
    for (int i = 0; i < 4; ++i) red[(n0 + i) * 33 + to] = part[i];
    __syncthreads();
    if (tid < 64) {
        int n = tid >> 1, cc = tid & 1;
        float l = 0.f;
        for (int k = 0; k < 128; k += 4) {
            float4 x = *reinterpret_cast<const float4*>(&Xs[n][k]);
            l += x.x * clsW[(k + 0) * 2 + cc];
            l += x.y * clsW[(k + 1) * 2 + cc];
            l += x.z * clsW[(k + 2) * 2 + cc];
            l += x.w * clsW[(k + 3) * 2 + cc];
        }
        Lsc[n * 2 + cc] = l + clsb[cc];
        float s = 0.f;
        for (int u = 0; u < 16; ++u) s += red[n * 33 + cc * 16 + u];
        s += attb2[cc];
        Ssc[n * 2 + cc] = 1.f / (1.f + expf(-s));
    }
    __syncthreads();
    if (tid < 32) {
        int n = tid;
        float l0 = Lsc[n * 2], l1 = Lsc[n * 2 + 1];
        float m = fmaxf(l0, l1);
        float e0 = expf(l0 - m), e1 = expf(l1 - m);
        float inv = 1.f / (e0 + e1);
        float p0 = e0 * inv, p1 = e1 * inv;
        float na = p0 * Ssc[n * 2] + p1 * Ssc[n * 2 + 1] + att_bias[0];
        int row = row0 + n;
        node_att[row] = na;
        probs_out[row * 2]     = p0;
        probs_out[row * 2 + 1] = p1;
    }
}

// ---------------- MFMA relgate: view_out = sigmoid(agg@gateW+gb) * (agg = X@relW + wsum*relb) ----
__global__ __launch_bounds__(256) void relgate_mfma_kernel(
        const u16* __restrict__ relWb, const float* __restrict__ relb,
        const u16* __restrict__ gateWb, const float* __restrict__ gateb,
        u16* __restrict__ aggB, const float* __restrict__ wsum) {
    __shared__ u16 Xs[128][136];   // 34816 B, stride 272 B (16B-aligned, 2-way banks)
    __shared__ u16 Wt[128][72];    // 18432 B, stride 144 B (16B-aligned, 2-way banks)
    int tid = threadIdx.x;
    int wv = tid >> 6, lane = tid & 63;
    int quad = lane >> 4, l15 = lane & 15;
    int v = blockIdx.y;
    int row0 = blockIdx.x * 128;
    const size_t vbase = (size_t)v * NN;

    // stage X tile (clamp tail rows)
    #pragma unroll
    for (int rep = 0; rep < 8; ++rep) {
        int flat = rep * 256 + tid;
        int n = flat >> 4, c8 = flat & 15;
        int gr = row0 + n; if (gr >= NN) gr = NN - 1;
        uint4 q = *reinterpret_cast<const uint4*>(aggB + (vbase + gr) * DD + c8 * 8);
        *reinterpret_cast<uint4*>(&Xs[n][c8 * 8]) = q;
    }

    f4v acc1[2][8], acc2[2][8];
    #pragma unroll
    for (int rt = 0; rt < 2; ++rt)
        #pragma unroll
        for (int c = 0; c < 8; ++c) {
            acc1[rt][c] = f4v{0.f, 0.f, 0.f, 0.f};
            acc2[rt][c] = f4v{0.f, 0.f, 0.f, 0.f};
        }

    const u16* W1 = relWb + (size_t)v * DD * DD;
    const u16* W2 = gateWb + (size_t)v * DD * DD;

    // GEMM1: acc1 = X @ relW   (K staged in two 64-halves)
    #pragma unroll
    for (int h = 0; h < 2; ++h) {
        #pragma unroll
        for (int rep = 0; rep < 4; ++rep) {
            int flat = rep * 256 + tid;
            int n = flat >> 3, c8 = flat & 7;
            uint4 q = *reinterpret_cast<const uint4*>(W1 + (size_t)n * DD + h * 64 + c8 * 8);
            *reinterpret_cast<uint4*>(&Wt[n][c8 * 8]) = q;
        }
        __syncthreads();
        #pragma unroll
        for (int t = 0; t < 2; ++t) {
            int kl = t * 32 + quad * 8;
            s8v a0 = *reinterpret_cast<const s8v*>(&Xs[wv * 32 + l15][h * 64 + kl]);
            s8v a1 = *reinterpret_cast<const s8v*>(&Xs[wv * 32 + 16 + l15][h * 64 + kl]);
            #pragma unroll
            for (int c = 0; c < 8; ++c) {
                s8v b = *reinterpret_cast<const s8v*>(&Wt[c * 16 + l15][kl]);
                acc1[0][c] = __builtin_amdgcn_mfma_f32_16x16x32_bf16(a0, b, acc1[0][c], 0, 0, 0);
                acc1[1][c] = __builtin_amdgcn_mfma_f32_16x16x32_bf16(a1, b, acc1[1][c], 0, 0, 0);
            }
        }
        __syncthreads();
    }

    // + wsum ⊗ relb   (C-layout: row = quad*4+r, col = l15)
    float wsn[2][4], rb[8];
    #pragma unroll
    for (int rt = 0; rt < 2; ++rt)
        #pragma unroll
        for (int r = 0; r < 4; ++r) {
            int gr = row0 + wv * 32 + rt * 16 + quad * 4 + r;
            wsn[rt][r] = wsum[vbase + (gr < NN ? gr : NN - 1)];
        }
    #pragma unroll
    for (int c = 0; c < 8; ++c) rb[c] = relb[v * DD + c * 16 + l15];
    #pragma unroll
    for (int rt = 0; rt < 2; ++rt)
        #pragma unroll
        for (int c = 0; c < 8; ++c)
            #pragma unroll
            for (int r = 0; r < 4; ++r)
                acc1[rt][c][r] += wsn[rt][r] * rb[c];

    // scatter agg (bf16) into Xs as GEMM2 A-operand
    #pragma unroll
    for (int rt = 0; rt < 2; ++rt)
        #pragma unroll
        for (int c = 0; c < 8; ++c)
            #pragma unroll
            for (int r = 0; r < 4; ++r)
                Xs[wv * 32 + rt * 16 + quad * 4 + r][c * 16 + l15] = f2bf(acc1[rt][c][r]);
    __syncthreads();

    // GEMM2: acc2 = agg @ gateW
    #pragma unroll
    for (int h = 0; h < 2; ++h) {
        #pragma unroll
        for (int rep = 0; rep < 4; ++rep) {
            int flat = rep * 256 + tid;
            int n = flat >> 3, c8 = flat & 7;
            uint4 q = *reinterpret_cast<const uint4*>(W2 + (size_t)n * DD + h * 64 + c8 * 8);
            *reinterpret_cast<uint4*>(&Wt[n][c8 * 8]) = q;
        }
        __syncthreads();
        #pragma unroll
        for (int t = 0; t < 2; ++t) {
            int kl = t * 32 + quad * 8;
            s8v a0 = *reinterpret_cast<const s8v*>(&Xs[wv * 32 + l15][h * 64 + kl]);
            s8v a1 = *reinterpret_cast<const s8v*>(&Xs[wv * 32 + 16 + l15][h * 64 + kl]);
            #pragma unroll
            for (int c = 0; c < 8; ++c) {
                s8v b = *reinterpret_cast<const s8v*>(&Wt[c * 16 + l15][kl]);
                acc2[0][c] = __builtin_amdgcn_mfma_f32_16x16x32_bf16(a0, b, acc2[0][c], 0, 0, 0);
                acc2[1][c] = __builtin_amdgcn_mfma_f32_16x16x32_bf16(a1, b, acc2[1][c], 0, 0, 0);
            }
        }
        __syncthreads();
    }

    // gate & write result into Xs, then coalesced store
    float gb[8];
    #pragma unroll
    for (int c = 0; c < 8; ++c) gb[c] = gateb[v * DD + c * 16 + l15];
    #pragma unroll
    for (int rt = 0; rt < 2; ++rt)
        #pragma unroll
        for (int c = 0; c < 8; ++c)
            #pragma unroll
            for (int r = 0; r < 4; ++r) {
                float g = 1.f / (1.f + expf(-(acc2[rt][c][r] + gb[c])));
                Xs[wv * 32 + rt * 16 + quad * 4 + r][c * 16 + l15] = f2bf(g * acc1[rt][c][r]);
            }
    __syncthreads();
    #pragma unroll
    for (int rep = 0; rep < 8; ++rep) {
        int flat = rep * 256 + tid;
        int n = flat >> 4, c8 = flat & 15;
        int gr = row0 + n;
        if (gr < NN)
            *reinterpret_cast<uint4*>(aggB + (vbase + gr) * DD + c8 * 8) =
                *reinterpret_cast<const uint4*>(&Xs[n][c8 * 8]);
    }
}

// ---------------- fallback VALU relgate (R5 path) ----
__global__ __launch_bounds__(256) void relgate_kernel(
        const float* __restrict__ relW, const float* __restrict__ relb,
        const float* __restrict__ gateW, const float* __restrict__ gateb,
        u16* __restrict__ aggB, const float* __restrict__ wsum) {
    __shared__ float Xs[32][128];
    __shared__ float Ws[64][132];
    int tid = threadIdx.x;
    int v = blockIdx.y;
    int row0 = blockIdx.x * 32;
    u16* base = aggB + ((size_t)v * NN + row0) * DD;
    stage_x_bf16<128, 256>(&Xs[0][0], base, tid);
    int to = tid & 31, tn = tid >> 5;
    int o0 = to * 4, n0 = tn * 4;
    float acc[4][4] = {};
    const float* W1 = relW + (size_t)v * DD * DD;
    for (int half = 0; half < 2; ++half) {
        __syncthreads();
        stage_w_f32<132, 256>(&Ws[0][0], W1 + half * 64 * DD, tid);
        __syncthreads();
        gemm16<128, 132>(acc, &Xs[0][0], &Ws[0][0], n0, o0, half * 64);
    }
    float wsn[4], rb[4];
    #pragma unroll
    for (int i = 0; i < 4; ++i) wsn[i] = wsum[v * NN + row0 + n0 + i];
    #pragma unroll
    for (int j = 0; j < 4; ++j) rb[j] = relb[v * DD + o0 + j];
    #pragma unroll
    for (int i = 0; i < 4; ++i)
        #pragma unroll
        for (int j = 0; j < 4; ++j) acc[i][j] += wsn[i] * rb[j];
    __syncthreads();
    #pragma unroll
    for (int i = 0; i < 4; ++i)
        *reinterpret_cast<float4*>(&Xs[n0 + i][o0]) = make_float4(acc[i][0], acc[i][1], acc[i][2], acc[i][3]);
    float acc2[4][4] = {};
    const float* W2 = gateW + (size_t)v * DD * DD;
    for (int half = 0; half < 2; ++half) {
        __syncthreads();
        stage_w_f32<132, 256>(&Ws[0][0], W2 + half * 64 * DD, tid);
        __syncthreads();
        gemm16<128, 132>(acc2, &Xs[0][0], &Ws[0][0], n0, o0, half * 64);
    }
    float gb[4];
    #pragma unroll
    for (int j = 0; j < 4; ++j) gb[j] = gateb[v * DD + o0 + j];
    #pragma unroll
    for (int i = 0; i < 4; ++i) {
        float g0 = 1.f / (1.f + expf(-(acc2[i][0] + gb[0])));
        float g1 = 1.f / (1.f + expf(-(acc2[i][1] + gb[1])));
        float g2 = 1.f / (1.f + expf(-(acc2[i][2] + gb[2])));
        float g3 = 1.f / (1.f + expf(-(acc2[i][3] + gb[3])));
        ushort4 r;
        r.x = f2bf(g0 * acc[i][0]); r.y = f2bf(g1 * acc[i][1]);
        r.z = f2bf(g2 * acc[i][2]); r.w = f2bf(g3 * acc[i][3]);
        *reinterpret_cast<ushort4*>(base + (size_t)(n0 + i) * DD + o0) = r;
    }
}

// ---------------- view attention scores ----
__global__ __launch_bounds__(128) void vatt_kernel(
        const u16* __restrict__ aggB, const float* __restrict__ view_pref,
        const float* __restrict__ vattW1, const float* __restrict__ vattb1,
        const float* __restrict__ vattW2, const float* __restrict__ vattb2,
        float* __restrict__ vscores) {
    __shared__ float Xs[32][132];
    __shared__ float Ws[128][68];
    int tid = threadIdx.x;
    int v = blockIdx.y;
    int row0 = blockIdx.x * 32;
    const u16* base = aggB + ((size_t)v * NN + row0) * DD;
    #pragma unroll
    for (int rep = 0; rep < 4; ++rep) {
        int flat = rep * 128 + tid;
        int n = flat >> 4, c8 = flat & 15;
        uint4 q = *reinterpret_cast<const uint4*>(base + (size_t)n * DD + c8 * 8);
        float4 pa = *reinterpret_cast<const float4*>(view_pref + v * DD + c8 * 8);
        float4 pb = *reinterpret_cast<const float4*>(view_pref + v * DD + c8 * 8 + 4);
        float* d = &Xs[n][c8 * 8];
        d[0] = bf2f((u16)(q.x & 0xffffu)) * pa.x; d[1] = bf2f((u16)(q.x >> 16)) * pa.y;
        d[2] = bf2f((u16)(q.y & 0xffffu)) * pa.z; d[3] = bf2f((u16)(q.y >> 16)) * pa.w;
        d[4] = bf2f((u16)(q.z & 0xffffu)) * pb.x; d[5] = bf2f((u16)(q.z >> 16)) * pb.y;
        d[6] = bf2f((u16)(q.w & 0xffffu)) * pb.z; d[7] = bf2f((u16)(q.w >> 16)) * pb.w;
    }
    #pragma unroll
    for (int rep = 0; rep < 16; ++rep) {
        int flat = rep * 128 + tid;
        int k = flat >> 4, c4 = flat & 15;
        float4 q = *reinterpret_cast<const float4*>(vattW1 + k * 64 + c4 * 4);
        *reinterpret_cast<float4*>(&Ws[k][c4 * 4]) = q;
    }
    __syncthreads();
    int to = tid & 15, tn = tid >> 4;
    int o0 = to * 4, n0 = tn * 4;
    float acc[4][4] = {};
    gemm16<132, 68>(acc, &Xs[0][0], &Ws[0][0], n0, o0, 0);
    gemm16<132, 68>(acc, &Xs[0][0], &Ws[64][0], n0, o0, 64);
    float b1[4], w2[4];
    #pragma unroll
    for (int j = 0; j < 4; ++j) {
        b1[j] = vattb1[o0 + j];
        w2[j] = vattW2[o0 + j];
    }
    float part[4];
    #pragma unroll
    for (int i = 0; i < 4; ++i) {
        float s = 0.f;
        #pragma unroll
        for (int j = 0; j < 4; ++j) {
            float hv = acc[i][j] + b1[j];
            hv = hv > 0.f ? hv : 0.f;
            s += hv * w2[j];
        }
        part[i] = s;
    }
    __syncthreads();
    float* red = &Ws[0][0];   // [32][17]
    #pragma unroll
    for (int i = 0; i < 4; ++i) red[(n0 + i) * 17 + to] = part[i];
    __syncthreads();
    if (tid < 32) {
        float s = 0.f;
        for (int u = 0; u < 16; ++u) s += red[tid * 17 + u];
        vscores[(size_t)v * NN + row0 + tid] = s + vattb2[0];
    }
}

// ---------------- combine ----
__global__ __launch_bounds__(256) void combine_kernel(
        u16* __restrict__ aggB, const float* __restrict__ vscores,
        const float* __restrict__ node_att) {
    int t = blockIdx.x * 256 + threadIdx.x;
    int n = t >> 5, c4 = t & 31;
    float s0 = vscores[n], s1 = vscores[NN + n], s2 = vscores[2 * NN + n];
    float m = fmaxf(s0, fmaxf(s1, s2));
    float e0 = expf(s0 - m), e1 = expf(s1 - m), e2 = expf(s2 - m);
    float inv = 1.f / (e0 + e1 + e2);
    float w0 = e0 * inv, w1 = e1 * inv, w2 = e2 * inv;
    float na = node_att[n];
    size_t off = (size_t)n * DD + c4 * 4;
    ushort4 q0 = *reinterpret_cast<const ushort4*>(aggB + off);
    ushort4 q1 = *reinterpret_cast<const ushort4*>(aggB + (size_t)NN * DD + off);
    ushort4 q2 = *reinterpret_cast<const ushort4*>(aggB + 2 * (size_t)NN * DD + off);
    ushort4 r;
    r.x = f2bf((bf2f(q0.x) * w0 + bf2f(q1.x) * w1 + bf2f(q2.x) * w2) * na);
    r.y = f2bf((bf2f(q0.y) * w0 + bf2f(q1.y) * w1 + bf2f(q2.y) * w2) * na);
    r.z = f2bf((bf2f(q0.z) * w0 + bf2f(q1.z) * w1 + bf2f(q2.z) * w2) * na);
    r.w = f2bf((bf2f(q0.w) * w0 + bf2f(q1.w) * w1 + bf2f(q2.w) * w2) * na);
    *reinterpret_cast<ushort4*>(aggB + off) = r;
}

// ---------------- final ----
__global__ __launch_bounds__(256) void final_kernel(
        const float* __restrict__ feat, const u16* __restrict__ weightedB,
        const float* __restrict__ Wsf, const float* __restrict__ c1,
        const float* __restrict__ fusW, const float* __restrict__ featW,
        const float* __restrict__ featb, const float* __restrict__ ln_g,
        const float* __restrict__ ln_b, float* __restrict__ outp) {
    __shared__ float Xs[32][128];
    __shared__ float Ws[64][128];
    int tid = threadIdx.x;
    int row0 = blockIdx.x * 32;
    stage_x_f32<128, 256>(&Xs[0][0], feat + (size_t)row0 * DD, tid);
    int to = tid & 31, tn = tid >> 5;
    int o0 = to * 4, n0 = tn * 4;
    float acc1[4][4] = {}, acc2[4][4] = {};
    for (int half = 0; half < 2; ++half) {
        __syncthreads();
        stage_w_f32<128, 256>(&Ws[0][0], Wsf + half * 64 * 128, tid);
        __syncthreads();
        gemm16<128, 128>(acc1, &Xs[0][0], &Ws[0][0], n0, o0, half * 64);
    }
    for (int half = 0; half < 2; ++half) {
        __syncthreads();
        stage_w_f32<128, 256>(&Ws[0][0], featW + half * 64 * 128, tid);
        __syncthreads();
        gemm16<128, 128>(acc2, &Xs[0][0], &Ws[0][0], n0, o0, half * 64);
    }
    __syncthreads();
    stage_x_bf16<128, 256>(&Xs[0][0], weightedB + (size_t)row0 * DD, tid);
    for (int half = 0; half < 2; ++half) {
        __syncthreads();
        stage_w_f32<128, 256>(&Ws[0][0], fusW + (size_t)(128 + half * 64) * 128, tid);
        __syncthreads();
        gemm16<128, 128>(acc1, &Xs[0][0], &Ws[0][0], n0, o0, half * 64);
    }
    float c1j[4], fbj[4], gj[4], bj[4];
    #pragma unroll
    for (int j = 0; j < 4; ++j) {
        c1j[j] = c1[o0 + j];
        fbj[j] = featb[o0 + j];
        gj[j]  = ln_g[o0 + j];
        bj[j]  = ln_b[o0 + j];
    }
    float val[4][4];
    #pragma unroll
    for (int i = 0; i < 4; ++i)
        #pragma unroll
        for (int j = 0; j < 4; ++j) {
            float f = acc1[i][j] + c1j[j];
            f = f > 0.f ? f : 0.f;
            val[i][j] = f + acc2[i][j] + fbj[j];
        }
    __syncthreads();
    float* red_s = &Ws[0][0];            // [32][33]
    float* red_q = red_s + 32 * 33;      // [32][33]
    float* mus   = red_q + 32 * 33;      // [32]
    float* rss   = mus + 32;             // [32]
    #pragma unroll
    for (int i = 0; i < 4; ++i) {
        float s = 0.f, q = 0.f;
        #pragma unroll
        for (int j = 0; j < 4; ++j) { s += val[i][j]; q += val[i][j] * val[i][j]; }
        red_s[(n0 + i) * 33 + to] = s;
        red_q[(n0 + i) * 33 + to] = q;
    }
    __syncthreads();
    if (tid < 32) {
        float s = 0.f, q = 0.f;
        for (int u = 0; u < 32; ++u) { s += red_s[tid * 33 + u]; q += red_q[tid * 33 + u]; }
        float mu = s / 128.f;
        float var = q / 128.f - mu * mu;
        mus[tid] = mu;
        rss[tid] = rsqrtf(var + 1e-5f);
    }
    __syncthreads();
    #pragma unroll
    for (int i = 0; i < 4; ++i) {
        float mu = mus[n0 + i], rs = rss[n0 + i];
        float4 o;
        o.x = (val[i][0] - mu) * rs * gj[0] + bj[0];
        o.y = (val[i][1] - mu) * rs * gj[1] + bj[1];
        o.z = (val[i][2] - mu) * rs * gj[2] + bj[2];
        o.w = (val[i][3] - mu) * rs * gj[3] + bj[3];
        *reinterpret_cast<float4*>(outp + (size_t)(row0 + n0 + i) * DD + o0) = o;
    }
}

extern "C" void kernel_launch(void* const* d_in, const int* in_sizes, int n_in,
                              void* d_out, int out_size, void* d_ws, size_t ws_size,
                              hipStream_t stream) {
    (void)in_sizes; (void)n_in; (void)out_size;
    const float* feat      = (const float*)d_in[0];
    const int*   esrc      = (const int*)d_in[1];
    const int*   edst      = (const int*)d_in[2];
    const float* ew        = (const float*)d_in[3];
    const float* clsW      = (const float*)d_in[4];
    const float* clsb      = (const float*)d_in[5];
    const float* attW1     = (const float*)d_in[6];
    const float* attb1     = (const float*)d_in[7];
    const float* attW2     = (const float*)d_in[8];
    const float* attb2     = (const float*)d_in[9];
    const float* att_bias  = (const float*)d_in[10];
    const float* relW      = (const float*)d_in[11];
    const float* relb      = (const float*)d_in[12];
    const float* gateW     = (const float*)d_in[13];
    const float* gateb     = (const float*)d_in[14];
    const float* view_pref = (const float*)d_in[15];
    const float* vattW1    = (const float*)d_in[16];
    const float* vattb1    = (const float*)d_in[17];
    const float* vattW2    = (const float*)d_in[18];
    const float* vattb2    = (const float*)d_in[19];
    const float* selfW     = (const float*)d_in[20];
    const float* selfb     = (const float*)d_in[21];
    const float* featW     = (const float*)d_in[22];
    const float* featb     = (const float*)d_in[23];
    const float* fusW      = (const float*)d_in[24];
    const float* fusb      = (const float*)d_in[25];
    const float* ln_g      = (const float*)d_in[26];
    const float* ln_b      = (const float*)d_in[27];

    // workspace layout (~94 MiB):
    u16*   aggB = (u16*)d_ws;                                   // [3][N][128] bf16
    float* wsum = (float*)(aggB + (size_t)VV * NN * DD);        // [3][N]
    float* natt = wsum + (size_t)VV * NN;                       // [N]
    float* vsc  = natt + NN;                                    // [3][N]
    float* Wsf  = vsc + (size_t)VV * NN;                        // [128][128]
    float* c1   = Wsf + DD * DD;                                // [128]
    u16* relWb  = (u16*)(c1 + DD);                              // [3][128][128] bf16 (n-major)
    u16* gateWb = relWb + (size_t)VV * DD * DD;                 // [3][128][128] bf16
    int*   C    = (int*)(gateWb + (size_t)VV * DD * DD);        // [3N] csr offsets
    int*   bs   = C + (size_t)TOT;                              // [NB] block sums
    int*   bsrc = bs + NB;                                      // [3E]
    float* bw   = (float*)(bsrc + (size_t)VV * EE);             // [3E]
    size_t needed = (size_t)((char*)(bw + (size_t)VV * EE) - (char*)d_ws);

    float* outp  = (float*)d_out;
    float* probs = outp + (size_t)NN * DD;

    prep_kernel<<<129, 128, 0, stream>>>(selfW, selfb, fusW, fusb, Wsf, c1);
    label_kernel<<<3125, 256, 0, stream>>>(feat, clsW, clsb, attW1, attb1, attW2, attb2,
                                           att_bias, natt, probs);
    if (ws_size >= needed) {
        wprep_kernel<<<384, 128, 0, stream>>>(relW, gateW, relWb, gateWb);
        hipMemsetAsync(C, 0, (size_t)TOT * sizeof(int), stream);
        count_kernel<<<(VV * EE + 255) / 256, 256, 0, stream>>>(edst, C);
        scanA_kernel<<<NB, 256, 0, stream>>>(C, bs);
        scanB_kernel<<<1, 1024, 0, stream>>>(bs);
        scanC_kernel<<<NB, 256, 0, stream>>>(C, bs);
        fill_kernel<<<(VV * EE + 255) / 256, 256, 0, stream>>>(esrc, edst, ew, C, bsrc, bw);
        gather_kernel<<<(VV * NN) / 4, 256, 0, stream>>>(feat, C, bsrc, bw, aggB, wsum);
        relgate_mfma_kernel<<<dim3(RGB, 3), 256, 0, stream>>>(relWb, relb, gateWb, gateb,
                                                              aggB, wsum);
    } else {
        hipMemsetAsync(d_ws, 0,
                       (size_t)VV * NN * DD * sizeof(u16) + (size_t)VV * NN * sizeof(float),
                       stream);
        scatter_kernel<<<187500, 256, 0, stream>>>(esrc, edst, ew, feat, aggB, wsum);
        relgate_kernel<<<dim3(3125, 3), 256, 0, stream>>>(relW, relb, gateW, gateb, aggB, wsum);
    }
    vatt_kernel<<<dim3(3125, 3), 128, 0, stream>>>(aggB, view_pref, vattW1, vattb1,
                                                   vattW2, vattb2, vsc);
    combine_kernel<<<12500, 256, 0, stream>>>(aggB, vsc, natt);
    final_kernel<<<3125, 256, 0, stream>>>(feat, aggB, Wsf, c1, fusW, featW, featb,
                                           ln_g, ln_b, outp);
}

// Round 7
// 795.346 us; speedup vs baseline: 2.0942x; 1.0842x over previous
//
#include <hip/hip_runtime.h>
#include <hip/hip_bf16.h>

#define NN 100000
#define DD 128
#define VV 3
#define EE 500000
#define TOT (VV * NN)                 // 300000 rows
#define NB ((TOT + 255) / 256)        // 1172 scan blocks
#define RGB ((NN + 127) / 128)        // 782 mfma blocks per view

typedef unsigned short u16;
typedef unsigned int u32;
typedef short s8v __attribute__((ext_vector_type(8)));   // 8 bf16 (4 VGPRs)
typedef float f4v __attribute__((ext_vector_type(4)));   // MFMA accumulator

__device__ __forceinline__ float bf2f(u16 u) {
    return __uint_as_float(((u32)u) << 16);
}
__device__ __forceinline__ u16 f2bf(float f) {
    u32 x = __float_as_uint(f);
    u32 r = (x + 0x7fffu + ((x >> 16) & 1u)) >> 16;
    return (u16)r;
}

// packed bf16 atomic add (fallback path only)
__device__ __forceinline__ void atomAddBf16x2(u16* addr, float f0, float f1) {
#if __has_builtin(__builtin_amdgcn_global_atomic_fadd_v2bf16)
    typedef short v2s __attribute__((ext_vector_type(2)));
    typedef v2s __attribute__((address_space(1)))* v2s_gp;
    v2s v;
    v.x = (short)f2bf(f0);
    v.y = (short)f2bf(f1);
    __builtin_amdgcn_global_atomic_fadd_v2bf16((v2s_gp)(void*)addr, v);
#else
    u32* p = (u32*)addr;
    u32 old = *(volatile u32*)p;
    while (true) {
        float lo = bf2f((u16)(old & 0xffffu)) + f0;
        float hi = bf2f((u16)(old >> 16)) + f1;
        u32 nv = (u32)f2bf(lo) | ((u32)f2bf(hi) << 16);
        u32 prev = atomicCAS(p, old, nv);
        if (prev == old) break;
        old = prev;
    }
#endif
}

// ---- generic VALU GEMM accumulate (fallback + small kernels) ----
template<int XSTR, int WSTR>
__device__ __forceinline__ void gemm16(float acc[4][4], const float* Xs,
                                       const float* Ws, int n0, int o0, int kbase) {
    #pragma unroll 4
    for (int kk = 0; kk < 64; kk += 4) {
        float4 w0 = *reinterpret_cast<const float4*>(Ws + (kk + 0) * WSTR + o0);
        float4 w1 = *reinterpret_cast<const float4*>(Ws + (kk + 1) * WSTR + o0);
        float4 w2 = *reinterpret_cast<const float4*>(Ws + (kk + 2) * WSTR + o0);
        float4 w3 = *reinterpret_cast<const float4*>(Ws + (kk + 3) * WSTR + o0);
        #pragma unroll
        for (int i = 0; i < 4; ++i) {
            float4 x = *reinterpret_cast<const float4*>(Xs + (n0 + i) * XSTR + kbase + kk);
            acc[i][0] = fmaf(x.x, w0.x, fmaf(x.y, w1.x, fmaf(x.z, w2.x, fmaf(x.w, w3.x, acc[i][0]))));
            acc[i][1] = fmaf(x.x, w0.y, fmaf(x.y, w1.y, fmaf(x.z, w2.y, fmaf(x.w, w3.y, acc[i][1]))));
            acc[i][2] = fmaf(x.x, w0.z, fmaf(x.y, w1.z, fmaf(x.z, w2.z, fmaf(x.w, w3.z, acc[i][2]))));
            acc[i][3] = fmaf(x.x, w0.w, fmaf(x.y, w1.w, fmaf(x.z, w2.w, fmaf(x.w, w3.w, acc[i][3]))));
        }
    }
}

template<int WSTR, int NT>
__device__ __forceinline__ void stage_w_f32(float* Ws, const float* __restrict__ src, int tid) {
    #pragma unroll
    for (int rep = 0; rep < 2048 / NT; ++rep) {
        int flat = rep * NT + tid;
        int kk = flat >> 5;
        int c4 = flat & 31;
        float4 q = *reinterpret_cast<const float4*>(src + kk * 128 + c4 * 4);
        *reinterpret_cast<float4*>(Ws + kk * WSTR + c4 * 4) = q;
    }
}

template<int XSTR, int NT>
__device__ __forceinline__ void stage_x_f32(float* Xs, const float* __restrict__ src, int tid) {
    #pragma unroll
    for (int rep = 0; rep < 1024 / NT; ++rep) {
        int flat = rep * NT + tid;
        int n = flat >> 5;
        int c4 = flat & 31;
        float4 q = *reinterpret_cast<const float4*>(src + (size_t)n * 128 + c4 * 4);
        *reinterpret_cast<float4*>(Xs + n * XSTR + c4 * 4) = q;
    }
}

template<int XSTR, int NT>
__device__ __forceinline__ void stage_x_bf16(float* Xs, const u16* __restrict__ src, int tid) {
    #pragma unroll
    for (int rep = 0; rep < 512 / NT; ++rep) {
        int flat = rep * NT + tid;
        int n = flat >> 4;
        int c8 = flat & 15;
        uint4 q = *reinterpret_cast<const uint4*>(src + (size_t)n * 128 + c8 * 8);
        float* d = Xs + n * XSTR + c8 * 8;
        d[0] = bf2f((u16)(q.x & 0xffffu)); d[1] = bf2f((u16)(q.x >> 16));
        d[2] = bf2f((u16)(q.y & 0xffffu)); d[3] = bf2f((u16)(q.y >> 16));
        d[4] = bf2f((u16)(q.z & 0xffffu)); d[5] = bf2f((u16)(q.z >> 16));
        d[6] = bf2f((u16)(q.w & 0xffffu)); d[7] = bf2f((u16)(q.w >> 16));
    }
}

// ---------------- prep: Wsf = selfW @ fusW_top ; c1 = selfb @ fusW_top + fusb ----
__global__ void prep_kernel(const float* __restrict__ selfW, const float* __restrict__ selfb,
                            const float* __restrict__ fusW, const float* __restrict__ fusb,
                            float* __restrict__ Wsf, float* __restrict__ c1) {
    int o = threadIdx.x;
    int k = blockIdx.x;
    if (k < 128) {
        float acc = 0.f;
        for (int m = 0; m < 128; ++m)
            acc += selfW[k * 128 + m] * fusW[m * 128 + o];
        Wsf[k * 128 + o] = acc;
    } else {
        float acc = 0.f;
        for (int m = 0; m < 128; ++m)
            acc += selfb[m] * fusW[m * 128 + o];
        c1[o] = acc + fusb[o];
    }
}

// ---------------- wprep: transpose+convert relW/gateW -> bf16 [v][n][k] ----
__global__ __launch_bounds__(128) void wprep_kernel(
        const float* __restrict__ relW, const float* __restrict__ gateW,
        u16* __restrict__ relWb, u16* __restrict__ gateWb) {
    int k = threadIdx.x;
    int n = blockIdx.x & 127;
    int v = blockIdx.x >> 7;
    size_t o = ((size_t)v * 128 + n) * 128 + k;
    size_t i = ((size_t)v * 128 + k) * 128 + n;
    relWb[o]  = f2bf(relW[i]);
    gateWb[o] = f2bf(gateW[i]);
}

// ---------------- wprep2: bf16 n-major Wsf / featW / fusW_bot ----
__global__ __launch_bounds__(128) void wprep2_kernel(
        const float* __restrict__ Wsf, const float* __restrict__ featW,
        const float* __restrict__ fusW,
        u16* __restrict__ WsfB, u16* __restrict__ featWB, u16* __restrict__ fusWbB) {
    int k = threadIdx.x;
    int n = blockIdx.x;
    WsfB[n * 128 + k]   = f2bf(Wsf[k * 128 + n]);
    featWB[n * 128 + k] = f2bf(featW[k * 128 + n]);
    fusWbB[n * 128 + k] = f2bf(fusW[(size_t)(128 + k) * 128 + n]);
}

// ---------------- featconv: feat fp32 -> bf16 ----
__global__ __launch_bounds__(256) void featconv_kernel(
        const float* __restrict__ feat, u16* __restrict__ featB) {
    int t = blockIdx.x * 256 + threadIdx.x;   // 3.2M float4 chunks
    float4 q = *reinterpret_cast<const float4*>(feat + (size_t)t * 4);
    ushort4 r;
    r.x = f2bf(q.x); r.y = f2bf(q.y); r.z = f2bf(q.z); r.w = f2bf(q.w);
    *reinterpret_cast<ushort4*>(featB + (size_t)t * 4) = r;
}

// ================= CSR build (hierarchical scan) + gather =================

__global__ __launch_bounds__(256) void count_kernel(
        const int* __restrict__ edst, int* __restrict__ C) {
    int t = blockIdx.x * 256 + threadIdx.x;
    if (t >= VV * EE) return;
    int v = t / EE;
    atomicAdd(&C[v * NN + edst[t]], 1);
}

__global__ __launch_bounds__(256) void scanA_kernel(
        const int* __restrict__ C, int* __restrict__ bs) {
    int b = blockIdx.x, t = threadIdx.x;
    int i = b * 256 + t;
    int v = (i < TOT) ? C[i] : 0;
    __shared__ int s[256];
    s[t] = v;
    __syncthreads();
    #pragma unroll
    for (int off = 128; off > 0; off >>= 1) {
        if (t < off) s[t] += s[t + off];
        __syncthreads();
    }
    if (t == 0) bs[b] = s[0];
}

__global__ __launch_bounds__(1024) void scanB_kernel(int* __restrict__ bs) {
    __shared__ int s[2048];
    int t = threadIdx.x;
    int v0 = (t < NB) ? bs[t] : 0;
    int v1 = (t + 1024 < NB) ? bs[t + 1024] : 0;
    s[t] = v0; s[t + 1024] = v1;
    __syncthreads();
    #pragma unroll
    for (int off = 1; off < 2048; off <<= 1) {
        int x0 = (t >= off) ? s[t - off] : 0;
        int x1 = (t + 1024 >= off) ? s[t + 1024 - off] : 0;
        __syncthreads();
        s[t] += x0; s[t + 1024] += x1;
        __syncthreads();
    }
    if (t < NB) bs[t] = s[t] - v0;
    if (t + 1024 < NB) bs[t + 1024] = s[t + 1024] - v1;
}

__global__ __launch_bounds__(256) void scanC_kernel(
        int* __restrict__ C, const int* __restrict__ bs) {
    int b = blockIdx.x, t = threadIdx.x;
    int i = b * 256 + t;
    int v = (i < TOT) ? C[i] : 0;
    __shared__ int s[256];
    s[t] = v;
    __syncthreads();
    #pragma unroll
    for (int off = 1; off < 256; off <<= 1) {
        int x = (t >= off) ? s[t - off] : 0;
        __syncthreads();
        s[t] += x;
        __syncthreads();
    }
    if (i < TOT) C[i] = s[t] - v + bs[b];
}

__global__ __launch_bounds__(256) void fill_kernel(
        const int* __restrict__ esrc, const int* __restrict__ edst,
        const float* __restrict__ ew, int* __restrict__ C,
        int* __restrict__ bsrc, float* __restrict__ bw) {
    int t = blockIdx.x * 256 + threadIdx.x;
    if (t >= VV * EE) return;
    int v = t / EE;
    int pos = atomicAdd(&C[v * NN + edst[t]], 1);
    bsrc[pos] = esrc[t];
    bw[pos] = ew[t];
}

// one wave per (v,dst) row, bf16 feat reads (256B/row)
__global__ __launch_bounds__(256) void gather_kernel(
        const u16* __restrict__ featB, const int* __restrict__ C,
        const int* __restrict__ bsrc, const float* __restrict__ bw,
        u16* __restrict__ aggB, float* __restrict__ wsum) {
    int wid = (blockIdx.x * 256 + threadIdx.x) >> 6;
    int lane = threadIdx.x & 63;
    int end = C[wid];
    int start = (wid == 0) ? 0 : C[wid - 1];
    float a0 = 0.f, a1 = 0.f, wacc = 0.f;
    for (int e = start; e < end; ++e) {
        int src = bsrc[e];
        float w = bw[e];
        u32 p = *reinterpret_cast<const u32*>(featB + (size_t)src * DD + lane * 2);
        a0 = fmaf(w, bf2f((u16)(p & 0xffffu)), a0);
        a1 = fmaf(w, bf2f((u16)(p >> 16)), a1);
        wacc += w;
    }
    u32 packed = (u32)f2bf(a0) | ((u32)f2bf(a1) << 16);
    *reinterpret_cast<u32*>(aggB + (size_t)wid * DD + lane * 2) = packed;
    if (lane == 0) wsum[wid] = wacc;
}

// ================= fallback: atomic scatter (R3 path) =================
__global__ __launch_bounds__(256) void scatter_kernel(
        const int* __restrict__ esrc, const int* __restrict__ edst,
        const float* __restrict__ ew, const float* __restrict__ feat,
        u16* __restrict__ aggB, float* __restrict__ wsum) {
    long long t = (long long)blockIdx.x * 256 + threadIdx.x;
    int lane = (int)(t & 31);
    int eg = (int)(t >> 5);
    int v = eg / EE;
    int src = 0, dst = 0; float w = 0.f;
    if (lane == 0) {
        src = esrc[eg]; dst = edst[eg]; w = ew[eg];
    }
    src = __shfl(src, 0, 32);
    dst = __shfl(dst, 0, 32);
    w   = __shfl(w, 0, 32);
    const float* fr = feat + (size_t)src * DD + lane * 4;
    float4 q = *reinterpret_cast<const float4*>(fr);
    u16* outp = aggB + ((size_t)v * NN + dst) * DD + lane * 4;
    atomAddBf16x2(outp,     w * q.x, w * q.y);
    atomAddBf16x2(outp + 2, w * q.z, w * q.w);
    if (lane == 0) atomicAdd(wsum + v * NN + dst, w);
}

// ---------------- label-aware attention ----
__global__ __launch_bounds__(256) void label_kernel(
        const float* __restrict__ feat, const float* __restrict__ clsW, const float* __restrict__ clsb,
        const float* __restrict__ attW1, const float* __restrict__ attb1,
        const float* __restrict__ attW2, const float* __restrict__ attb2,
        const float* __restrict__ att_bias,
        float* __restrict__ node_att, float* __restrict__ probs_out) {
    __shared__ float Xs[32][132];
    __shared__ float Ws[64][132];
    int tid = threadIdx.x;
    int row0 = blockIdx.x * 32;
    stage_x_f32<132, 256>(&Xs[0][0], feat + (size_t)row0 * DD, tid);
    int to = tid & 31, tn = tid >> 5;
    int o0 = to * 4, n0 = tn * 4;
    float acc[4][4] = {};
    for (int half = 0; half < 2; ++half) {
        __syncthreads();
        #pragma unroll
        for (int rep = 0; rep < 8; ++rep) {
            int flat = rep * 256 + tid;
            int kk = flat >> 5, o4 = flat & 31;
            int o = o4 * 4;
            int c = o >> 6, h = o & 63;
            int k = half * 64 + kk;
            float4 q = *reinterpret_cast<const float4*>(attW1 + (size_t)(c * 128 + k) * 64 + h);
            *reinterpret_cast<float4*>(&Ws[kk][o]) = q;
        }
        __syncthreads();
        gemm16<132, 132>(acc, &Xs[0][0], &Ws[0][0], n0, o0, half * 64);
    }
    int c = o0 >> 6, h0 = o0 & 63;
    float b1j[4], w2j[4];
    #pragma unroll
    for (int j = 0; j < 4; ++j) {
        b1j[j] = attb1[c * 64 + h0 + j];
        w2j[j] = attW2[c * 64 + h0 + j];
    }
    float part[4];
    #pragma unroll
    for (int i = 0; i < 4; ++i) {
        float s = 0.f;
        #pragma unroll
        for (int j = 0; j < 4; ++j) {
            float hv = acc[i][j] + b1j[j];
            hv = hv > 0.f ? hv : 0.f;
            s += hv * w2j[j];
        }
        part[i] = s;
    }
    __syncthreads();
    float* red = &Ws[0][0];          // [32][33]
    float* Ssc = red + 32 * 33;      // [32][2]
    float* Lsc = Ssc + 64;           // [32][2]
    #pragma unroll
    for (int i = 0; i < 4; ++i) red[(n0 + i) * 33 + to] = part[i];
    __syncthreads();
    if (tid < 64) {
        int n = tid >> 1, cc = tid & 1;
        float l = 0.f;
        for (int k = 0; k < 128; k += 4) {
            float4 x = *reinterpret_cast<const float4*>(&Xs[n][k]);
            l += x.x * clsW[(k + 0) * 2 + cc];
            l += x.y * clsW[(k + 1) * 2 + cc];
            l += x.z * clsW[(k + 2) * 2 + cc];
            l += x.w * clsW[(k + 3) * 2 + cc];
        }
        Lsc[n * 2 + cc] = l + clsb[cc];
        float s = 0.f;
        for (int u = 0; u < 16; ++u) s += red[n * 33 + cc * 16 + u];
        s += attb2[cc];
        Ssc[n * 2 + cc] = 1.f / (1.f + expf(-s));
    }
    __syncthreads();
    if (tid < 32) {
        int n = tid;
        float l0 = Lsc[n * 2], l1 = Lsc[n * 2 + 1];
        float m = fmaxf(l0, l1);
        float e0 = expf(l0 - m), e1 = expf(l1 - m);
        float inv = 1.f / (e0 + e1);
        float p0 = e0 * inv, p1 = e1 * inv;
        float na = p0 * Ssc[n * 2] + p1 * Ssc[n * 2 + 1] + att_bias[0];
        int row = row0 + n;
        node_att[row] = na;
        probs_out[row * 2]     = p0;
        probs_out[row * 2 + 1] = p1;
    }
}

// ---------------- MFMA relgate ----
__global__ __launch_bounds__(256) void relgate_mfma_kernel(
        const u16* __restrict__ relWb, const float* __restrict__ relb,
        const u16* __restrict__ gateWb, const float* __restrict__ gateb,
        u16* __restrict__ aggB, const float* __restrict__ wsum) {
    __shared__ u16 Xs[128][136];
    __shared__ u16 Wt[128][72];
    int tid = threadIdx.x;
    int wv = tid >> 6, lane = tid & 63;
    int quad = lane >> 4, l15 = lane & 15;
    int v = blockIdx.y;
    int row0 = blockIdx.x * 128;
    const size_t vbase = (size_t)v * NN;

    #pragma unroll
    for (int rep = 0; rep < 8; ++rep) {
        int flat = rep * 256 + tid;
        int n = flat >> 4, c8 = flat & 15;
        int gr = row0 + n; if (gr >= NN) gr = NN - 1;
        uint4 q = *reinterpret_cast<const uint4*>(aggB + (vbase + gr) * DD + c8 * 8);
        *reinterpret_cast<uint4*>(&Xs[n][c8 * 8]) = q;
    }

    f4v acc1[2][8], acc2[2][8];
    #pragma unroll
    for (int rt = 0; rt < 2; ++rt)
        #pragma unroll
        for (int c = 0; c < 8; ++c) {
            acc1[rt][c] = f4v{0.f, 0.f, 0.f, 0.f};
            acc2[rt][c] = f4v{0.f, 0.f, 0.f, 0.f};
        }

    const u16* W1 = relWb + (size_t)v * DD * DD;
    const u16* W2 = gateWb + (size_t)v * DD * DD;

    #pragma unroll
    for (int h = 0; h < 2; ++h) {
        #pragma unroll
        for (int rep = 0; rep < 4; ++rep) {
            int flat = rep * 256 + tid;
            int n = flat >> 3, c8 = flat & 7;
            uint4 q = *reinterpret_cast<const uint4*>(W1 + (size_t)n * DD + h * 64 + c8 * 8);
            *reinterpret_cast<uint4*>(&Wt[n][c8 * 8]) = q;
        }
        __syncthreads();
        #pragma unroll
        for (int t = 0; t < 2; ++t) {
            int kl = t * 32 + quad * 8;
            s8v a0 = *reinterpret_cast<const s8v*>(&Xs[wv * 32 + l15][h * 64 + kl]);
            s8v a1 = *reinterpret_cast<const s8v*>(&Xs[wv * 32 + 16 + l15][h * 64 + kl]);
            #pragma unroll
            for (int c = 0; c < 8; ++c) {
                s8v b = *reinterpret_cast<const s8v*>(&Wt[c * 16 + l15][kl]);
                acc1[0][c] = __builtin_amdgcn_mfma_f32_16x16x32_bf16(a0, b, acc1[0][c], 0, 0, 0);
                acc1[1][c] = __builtin_amdgcn_mfma_f32_16x16x32_bf16(a1, b, acc1[1][c], 0, 0, 0);
            }
        }
        __syncthreads();
    }

    float wsn[2][4], rb[8];
    #pragma unroll
    for (int rt = 0; rt < 2; ++rt)
        #pragma unroll
        for (int r = 0; r < 4; ++r) {
            int gr = row0 + wv * 32 + rt * 16 + quad * 4 + r;
            wsn[rt][r] = wsum[vbase + (gr < NN ? gr : NN - 1)];
        }
    #pragma unroll
    for (int c = 0; c < 8; ++c) rb[c] = relb[v * DD + c * 16 + l15];
    #pragma unroll
    for (int rt = 0; rt < 2; ++rt)
        #pragma unroll
        for (int c = 0; c < 8; ++c)
            #pragma unroll
            for (int r = 0; r < 4; ++r)
                acc1[rt][c][r] += wsn[rt][r] * rb[c];

    #pragma unroll
    for (int rt = 0; rt < 2; ++rt)
        #pragma unroll
        for (int c = 0; c < 8; ++c)
            #pragma unroll
            for (int r = 0; r < 4; ++r)
                Xs[wv * 32 + rt * 16 + quad * 4 + r][c * 16 + l15] = f2bf(acc1[rt][c][r]);
    __syncthreads();

    #pragma unroll
    for (int h = 0; h < 2; ++h) {
        #pragma unroll
        for (int rep = 0; rep < 4; ++rep) {
            int flat = rep * 256 + tid;
            int n = flat >> 3, c8 = flat & 7;
            uint4 q = *reinterpret_cast<const uint4*>(W2 + (size_t)n * DD + h * 64 + c8 * 8);
            *reinterpret_cast<uint4*>(&Wt[n][c8 * 8]) = q;
        }
        __syncthreads();
        #pragma unroll
        for (int t = 0; t < 2; ++t) {
            int kl = t * 32 + quad * 8;
            s8v a0 = *reinterpret_cast<const s8v*>(&Xs[wv * 32 + l15][h * 64 + kl]);
            s8v a1 = *reinterpret_cast<const s8v*>(&Xs[wv * 32 + 16 + l15][h * 64 + kl]);
            #pragma unroll
            for (int c = 0; c < 8; ++c) {
                s8v b = *reinterpret_cast<const s8v*>(&Wt[c * 16 + l15][kl]);
                acc2[0][c] = __builtin_amdgcn_mfma_f32_16x16x32_bf16(a0, b, acc2[0][c], 0, 0, 0);
                acc2[1][c] = __builtin_amdgcn_mfma_f32_16x16x32_bf16(a1, b, acc2[1][c], 0, 0, 0);
            }
        }
        __syncthreads();
    }

    float gb[8];
    #pragma unroll
    for (int c = 0; c < 8; ++c) gb[c] = gateb[v * DD + c * 16 + l15];
    #pragma unroll
    for (int rt = 0; rt < 2; ++rt)
        #pragma unroll
        for (int c = 0; c < 8; ++c)
            #pragma unroll
            for (int r = 0; r < 4; ++r) {
                float g = 1.f / (1.f + expf(-(acc2[rt][c][r] + gb[c])));
                Xs[wv * 32 + rt * 16 + quad * 4 + r][c * 16 + l15] = f2bf(g * acc1[rt][c][r]);
            }
    __syncthreads();
    #pragma unroll
    for (int rep = 0; rep < 8; ++rep) {
        int flat = rep * 256 + tid;
        int n = flat >> 4, c8 = flat & 15;
        int gr = row0 + n;
        if (gr < NN)
            *reinterpret_cast<uint4*>(aggB + (vbase + gr) * DD + c8 * 8) =
                *reinterpret_cast<const uint4*>(&Xs[n][c8 * 8]);
    }
}

// ---------------- fallback VALU relgate ----
__global__ __launch_bounds__(256) void relgate_kernel(
        const float* __restrict__ relW, const float* __restrict__ relb,
        const float* __restrict__ gateW, const float* __restrict__ gateb,
        u16* __restrict__ aggB, const float* __restrict__ wsum) {
    __shared__ float Xs[32][128];
    __shared__ float Ws[64][132];
    int tid = threadIdx.x;
    int v = blockIdx.y;
    int row0 = blockIdx.x * 32;
    u16* base = aggB + ((size_t)v * NN + row0) * DD;
    stage_x_bf16<128, 256>(&Xs[0][0], base, tid);
    int to = tid & 31, tn = tid >> 5;
    int o0 = to * 4, n0 = tn * 4;
    float acc[4][4] = {};
    const float* W1 = relW + (size_t)v * DD * DD;
    for (int half = 0; half < 2; ++half) {
        __syncthreads();
        stage_w_f32<132, 256>(&Ws[0][0], W1 + half * 64 * DD, tid);
        __syncthreads();
        gemm16<128, 132>(acc, &Xs[0][0], &Ws[0][0], n0, o0, half * 64);
    }
    float wsn[4], rb[4];
    #pragma unroll
    for (int i = 0; i < 4; ++i) wsn[i] = wsum[v * NN + row0 + n0 + i];
    #pragma unroll
    for (int j = 0; j < 4; ++j) rb[j] = relb[v * DD + o0 + j];
    #pragma unroll
    for (int i = 0; i < 4; ++i)
        #pragma unroll
        for (int j = 0; j < 4; ++j) acc[i][j] += wsn[i] * rb[j];
    __syncthreads();
    #pragma unroll
    for (int i = 0; i < 4; ++i)
        *reinterpret_cast<float4*>(&Xs[n0 + i][o0]) = make_float4(acc[i][0], acc[i][1], acc[i][2], acc[i][3]);
    float acc2[4][4] = {};
    const float* W2 = gateW + (size_t)v * DD * DD;
    for (int half = 0; half < 2; ++half) {
        __syncthreads();
        stage_w_f32<132, 256>(&Ws[0][0], W2 + half * 64 * DD, tid);
        __syncthreads();
        gemm16<128, 132>(acc2, &Xs[0][0], &Ws[0][0], n0, o0, half * 64);
    }
    float gb[4];
    #pragma unroll
    for (int j = 0; j < 4; ++j) gb[j] = gateb[v * DD + o0 + j];
    #pragma unroll
    for (int i = 0; i < 4; ++i) {
        float g0 = 1.f / (1.f + expf(-(acc2[i][0] + gb[0])));
        float g1 = 1.f / (1.f + expf(-(acc2[i][1] + gb[1])));
        float g2 = 1.f / (1.f + expf(-(acc2[i][2] + gb[2])));
        float g3 = 1.f / (1.f + expf(-(acc2[i][3] + gb[3])));
        ushort4 r;
        r.x = f2bf(g0 * acc[i][0]); r.y = f2bf(g1 * acc[i][1]);
        r.z = f2bf(g2 * acc[i][2]); r.w = f2bf(g3 * acc[i][3]);
        *reinterpret_cast<ushort4*>(base + (size_t)(n0 + i) * DD + o0) = r;
    }
}

// ---------------- view attention scores ----
__global__ __launch_bounds__(128) void vatt_kernel(
        const u16* __restrict__ aggB, const float* __restrict__ view_pref,
        const float* __restrict__ vattW1, const float* __restrict__ vattb1,
        const float* __restrict__ vattW2, const float* __restrict__ vattb2,
        float* __restrict__ vscores) {
    __shared__ float Xs[32][132];
    __shared__ float Ws[128][68];
    int tid = threadIdx.x;
    int v = blockIdx.y;
    int row0 = blockIdx.x * 32;
    const u16* base = aggB + ((size_t)v * NN + row0) * DD;
    #pragma unroll
    for (int rep = 0; rep < 4; ++rep) {
        int flat = rep * 128 + tid;
        int n = flat >> 4, c8 = flat & 15;
        uint4 q = *reinterpret_cast<const uint4*>(base + (size_t)n * DD + c8 * 8);
        float4 pa = *reinterpret_cast<const float4*>(view_pref + v * DD + c8 * 8);
        float4 pb = *reinterpret_cast<const float4*>(view_pref + v * DD + c8 * 8 + 4);
        float* d = &Xs[n][c8 * 8];
        d[0] = bf2f((u16)(q.x & 0xffffu)) * pa.x; d[1] = bf2f((u16)(q.x >> 16)) * pa.y;
        d[2] = bf2f((u16)(q.y & 0xffffu)) * pa.z; d[3] = bf2f((u16)(q.y >> 16)) * pa.w;
        d[4] = bf2f((u16)(q.z & 0xffffu)) * pb.x; d[5] = bf2f((u16)(q.z >> 16)) * pb.y;
        d[6] = bf2f((u16)(q.w & 0xffffu)) * pb.z; d[7] = bf2f((u16)(q.w >> 16)) * pb.w;
    }
    #pragma unroll
    for (int rep = 0; rep < 16; ++rep) {
        int flat = rep * 128 + tid;
        int k = flat >> 4, c4 = flat & 15;
        float4 q = *reinterpret_cast<const float4*>(vattW1 + k * 64 + c4 * 4);
        *reinterpret_cast<float4*>(&Ws[k][c4 * 4]) = q;
    }
    __syncthreads();
    int to = tid & 15, tn = tid >> 4;
    int o0 = to * 4, n0 = tn * 4;
    float acc[4][4] = {};
    gemm16<132, 68>(acc, &Xs[0][0], &Ws[0][0], n0, o0, 0);
    gemm16<132, 68>(acc, &Xs[0][0], &Ws[64][0], n0, o0, 64);
    float b1[4], w2[4];
    #pragma unroll
    for (int j = 0; j < 4; ++j) {
        b1[j] = vattb1[o0 + j];
        w2[j] = vattW2[o0 + j];
    }
    float part[4];
    #pragma unroll
    for (int i = 0; i < 4; ++i) {
        float s = 0.f;
        #pragma unroll
        for (int j = 0; j < 4; ++j) {
            float hv = acc[i][j] + b1[j];
            hv = hv > 0.f ? hv : 0.f;
            s += hv * w2[j];
        }
        part[i] = s;
    }
    __syncthreads();
    float* red = &Ws[0][0];   // [32][17]
    #pragma unroll
    for (int i = 0; i < 4; ++i) red[(n0 + i) * 17 + to] = part[i];
    __syncthreads();
    if (tid < 32) {
        float s = 0.f;
        for (int u = 0; u < 16; ++u) s += red[tid * 17 + u];
        vscores[(size_t)v * NN + row0 + tid] = s + vattb2[0];
    }
}

// ---------------- combine ----
__global__ __launch_bounds__(256) void combine_kernel(
        u16* __restrict__ aggB, const float* __restrict__ vscores,
        const float* __restrict__ node_att) {
    int t = blockIdx.x * 256 + threadIdx.x;
    int n = t >> 5, c4 = t & 31;
    float s0 = vscores[n], s1 = vscores[NN + n], s2 = vscores[2 * NN + n];
    float m = fmaxf(s0, fmaxf(s1, s2));
    float e0 = expf(s0 - m), e1 = expf(s1 - m), e2 = expf(s2 - m);
    float inv = 1.f / (e0 + e1 + e2);
    float w0 = e0 * inv, w1 = e1 * inv, w2 = e2 * inv;
    float na = node_att[n];
    size_t off = (size_t)n * DD + c4 * 4;
    ushort4 q0 = *reinterpret_cast<const ushort4*>(aggB + off);
    ushort4 q1 = *reinterpret_cast<const ushort4*>(aggB + (size_t)NN * DD + off);
    ushort4 q2 = *reinterpret_cast<const ushort4*>(aggB + 2 * (size_t)NN * DD + off);
    ushort4 r;
    r.x = f2bf((bf2f(q0.x) * w0 + bf2f(q1.x) * w1 + bf2f(q2.x) * w2) * na);
    r.y = f2bf((bf2f(q0.y) * w0 + bf2f(q1.y) * w1 + bf2f(q2.y) * w2) * na);
    r.z = f2bf((bf2f(q0.z) * w0 + bf2f(q1.z) * w1 + bf2f(q2.z) * w2) * na);
    r.w = f2bf((bf2f(q0.w) * w0 + bf2f(q1.w) * w1 + bf2f(q2.w) * w2) * na);
    *reinterpret_cast<ushort4*>(aggB + off) = r;
}

// ---------------- MFMA final: out = LN(relu(feat@Wsf + w@fusWb + c1) + feat@featW + featb) ----
__global__ __launch_bounds__(256) void final_mfma_kernel(
        const u16* __restrict__ featB, const u16* __restrict__ weightedB,
        const u16* __restrict__ WsfB, const u16* __restrict__ featWB,
        const u16* __restrict__ fusWbB,
        const float* __restrict__ c1, const float* __restrict__ featb,
        const float* __restrict__ ln_g, const float* __restrict__ ln_b,
        float* __restrict__ outp) {
    __shared__ u16 Xs[128][136];
    __shared__ u16 Wt[128][72];
    int tid = threadIdx.x;
    int wv = tid >> 6, lane = tid & 63;
    int quad = lane >> 4, l15 = lane & 15;
    int row0 = blockIdx.x * 128;

    // stage feat tile
    #pragma unroll
    for (int rep = 0; rep < 8; ++rep) {
        int flat = rep * 256 + tid;
        int n = flat >> 4, c8 = flat & 15;
        int gr = row0 + n; if (gr >= NN) gr = NN - 1;
        uint4 q = *reinterpret_cast<const uint4*>(featB + (size_t)gr * DD + c8 * 8);
        *reinterpret_cast<uint4*>(&Xs[n][c8 * 8]) = q;
    }

    f4v acc1[2][8], acc2[2][8];
    #pragma unroll
    for (int rt = 0; rt < 2; ++rt)
        #pragma unroll
        for (int c = 0; c < 8; ++c) {
            acc1[rt][c] = f4v{0.f, 0.f, 0.f, 0.f};
            acc2[rt][c] = f4v{0.f, 0.f, 0.f, 0.f};
        }

    // acc1 = feat@Wsf ; acc2 = feat@featW
    #pragma unroll
    for (int h = 0; h < 2; ++h) {
        #pragma unroll
        for (int rep = 0; rep < 4; ++rep) {
            int flat = rep * 256 + tid;
            int n = flat >> 3, c8 = flat & 7;
            uint4 q = *reinterpret_cast<const uint4*>(WsfB + (size_t)n * DD + h * 64 + c8 * 8);
            *reinterpret_cast<uint4*>(&Wt[n][c8 * 8]) = q;
        }
        __syncthreads();
        #pragma unroll
        for (int t = 0; t < 2; ++t) {
            int kl = t * 32 + quad * 8;
            s8v a0 = *reinterpret_cast<const s8v*>(&Xs[wv * 32 + l15][h * 64 + kl]);
            s8v a1 = *reinterpret_cast<const s8v*>(&Xs[wv * 32 + 16 + l15][h * 64 + kl]);
            #pragma unroll
            for (int c = 0; c < 8; ++c) {
                s8v b = *reinterpret_cast<const s8v*>(&Wt[c * 16 + l15][kl]);
                acc1[0][c] = __builtin_amdgcn_mfma_f32_16x16x32_bf16(a0, b, acc1[0][c], 0, 0, 0);
                acc1[1][c] = __builtin_amdgcn_mfma_f32_16x16x32_bf16(a1, b, acc1[1][c], 0, 0, 0);
            }
        }
        __syncthreads();
        #pragma unroll
        for (int rep = 0; rep < 4; ++rep) {
            int flat = rep * 256 + tid;
            int n = flat >> 3, c8 = flat & 7;
            uint4 q = *reinterpret_cast<const uint4*>(featWB + (size_t)n * DD + h * 64 + c8 * 8);
            *reinterpret_cast<uint4*>(&Wt[n][c8 * 8]) = q;
        }
        __syncthreads();
        #pragma unroll
        for (int t = 0; t < 2; ++t) {
            int kl = t * 32 + quad * 8;
            s8v a0 = *reinterpret_cast<const s8v*>(&Xs[wv * 32 + l15][h * 64 + kl]);
            s8v a1 = *reinterpret_cast<const s8v*>(&Xs[wv * 32 + 16 + l15][h * 64 + kl]);
            #pragma unroll
            for (int c = 0; c < 8; ++c) {
                s8v b = *reinterpret_cast<const s8v*>(&Wt[c * 16 + l15][kl]);
                acc2[0][c] = __builtin_amdgcn_mfma_f32_16x16x32_bf16(a0, b, acc2[0][c], 0, 0, 0);
                acc2[1][c] = __builtin_amdgcn_mfma_f32_16x16x32_bf16(a1, b, acc2[1][c], 0, 0, 0);
            }
        }
        __syncthreads();
    }

    // restage weighted tile, acc1 += weighted@fusW_bot
    #pragma unroll
    for (int rep = 0; rep < 8; ++rep) {
        int flat = rep * 256 + tid;
        int n = flat >> 4, c8 = flat & 15;
        int gr = row0 + n; if (gr >= NN) gr = NN - 1;
        uint4 q = *reinterpret_cast<const uint4*>(weightedB + (size_t)gr * DD + c8 * 8);
        *reinterpret_cast<uint4*>(&Xs[n][c8 * 8]) = q;
    }
    #pragma unroll
    for (int h = 0; h < 2; ++h) {
        #pragma unroll
        for (int rep = 0; rep < 4; ++rep) {
            int flat = rep * 256 + tid;
            int n = flat >> 3, c8 = flat & 7;
            uint4 q = *reinterpret_cast<const uint4*>(fusWbB + (size_t)n * DD + h * 64 + c8 * 8);
            *reinterpret_cast<uint4*>(&Wt[n][c8 * 8]) = q;
        }
        __syncthreads();
        #pragma unroll
        for (int t = 0; t < 2; ++t) {
            int kl = t * 32 + quad * 8;
            s8v a0 = *reinterpret_cast<const s8v*>(&Xs[wv * 32 + l15][h * 64 + kl]);
            s8v a1 = *reinterpret_cast<const s8v*>(&Xs[wv * 32 + 16 + l15][h * 64 + kl]);
            #pragma unroll
            for (int c = 0; c < 8; ++c) {
                s8v b = *reinterpret_cast<const s8v*>(&Wt[c * 16 + l15][kl]);
                acc1[0][c] = __builtin_amdgcn_mfma_f32_16x16x32_bf16(a0, b, acc1[0][c], 0, 0, 0);
                acc1[1][c] = __builtin_amdgcn_mfma_f32_16x16x32_bf16(a1, b, acc1[1][c], 0, 0, 0);
            }
        }
        __syncthreads();
    }

    // epilogue: val (into acc1) = relu(acc1 + c1) + acc2 + featb ; LN via quad shfl
    float c1j[8], fbj[8], gj[8], bj[8];
    #pragma unroll
    for (int c = 0; c < 8; ++c) {
        int col = c * 16 + l15;
        c1j[c] = c1[col];
        fbj[c] = featb[col];
        gj[c]  = ln_g[col];
        bj[c]  = ln_b[col];
    }
    #pragma unroll
    for (int rt = 0; rt < 2; ++rt)
        #pragma unroll
        for (int c = 0; c < 8; ++c)
            #pragma unroll
            for (int r = 0; r < 4; ++r) {
                float f = acc1[rt][c][r] + c1j[c];
                f = f > 0.f ? f : 0.f;
                acc1[rt][c][r] = f + acc2[rt][c][r] + fbj[c];
            }
    #pragma unroll
    for (int rt = 0; rt < 2; ++rt)
        #pragma unroll
        for (int r = 0; r < 4; ++r) {
            float s = 0.f, q = 0.f;
            #pragma unroll
            for (int c = 0; c < 8; ++c) {
                float x = acc1[rt][c][r];
                s += x; q += x * x;
            }
            #pragma unroll
            for (int m = 1; m < 16; m <<= 1) {
                s += __shfl_xor(s, m);
                q += __shfl_xor(q, m);
            }
            float mu = s * (1.f / 128.f);
            float var = q * (1.f / 128.f) - mu * mu;
            float rs = rsqrtf(var + 1e-5f);
            int gr = row0 + wv * 32 + rt * 16 + quad * 4 + r;
            if (gr < NN) {
                #pragma unroll
                for (int c = 0; c < 8; ++c)
                    outp[(size_t)gr * DD + c * 16 + l15] =
                        (acc1[rt][c][r] - mu) * rs * gj[c] + bj[c];
            }
        }
}

// ---------------- fallback VALU final ----
__global__ __launch_bounds__(256) void final_kernel(
        const float* __restrict__ feat, const u16* __restrict__ weightedB,
        const float* __restrict__ Wsf, const float* __restrict__ c1,
        const float* __restrict__ fusW, const float* __restrict__ featW,
        const float* __restrict__ featb, const float* __restrict__ ln_g,
        const float* __restrict__ ln_b, float* __restrict__ outp) {
    __shared__ float Xs[32][128];
    __shared__ float Ws[64][128];
    int tid = threadIdx.x;
    int row0 = blockIdx.x * 32;
    stage_x_f32<128, 256>(&Xs[0][0], feat + (size_t)row0 * DD, tid);
    int to = tid & 31, tn = tid >> 5;
    int o0 = to * 4, n0 = tn * 4;
    float acc1[4][4] = {}, acc2[4][4] = {};
    for (int half = 0; half < 2; ++half) {
        __syncthreads();
        stage_w_f32<128, 256>(&Ws[0][0], Wsf + half * 64 * 128, tid);
        __syncthreads();
        gemm16<128, 128>(acc1, &Xs[0][0], &Ws[0][0], n0, o0, half * 64);
    }
    for (int half = 0; half < 2; ++half) {
        __syncthreads();
        stage_w_f32<128, 256>(&Ws[0][0], featW + half * 64 * 128, tid);
        __syncthreads();
        gemm16<128, 128>(acc2, &Xs[0][0], &Ws[0][0], n0, o0, half * 64);
    }
    __syncthreads();
    stage_x_bf16<128, 256>(&Xs[0][0], weightedB + (size_t)row0 * DD, tid);
    for (int half = 0; half < 2; ++half) {
        __syncthreads();
        stage_w_f32<128, 256>(&Ws[0][0], fusW + (size_t)(128 + half * 64) * 128, tid);
        __syncthreads();
        gemm16<128, 128>(acc1, &Xs[0][0], &Ws[0][0], n0, o0, half * 64);
    }
    float c1j[4], fbj[4], gj[4], bj[4];
    #pragma unroll
    for (int j = 0; j < 4; ++j) {
        c1j[j] = c1[o0 + j];
        fbj[j] = featb[o0 + j];
        gj[j]  = ln_g[o0 + j];
        bj[j]  = ln_b[o0 + j];
    }
    float val[4][4];
    #pragma unroll
    for (int i = 0; i < 4; ++i)
        #pragma unroll
        for (int j = 0; j < 4; ++j) {
            float f = acc1[i][j] + c1j[j];
            f = f > 0.f ? f : 0.f;
            val[i][j] = f + acc2[i][j] + fbj[j];
        }
    __syncthreads();
    float* red_s = &Ws[0][0];
    float* red_q = red_s + 32 * 33;
    float* mus   = red_q + 32 * 33;
    float* rss   = mus + 32;
    #pragma unroll
    for (int i = 0; i < 4; ++i) {
        float s = 0.f, q = 0.f;
        #pragma unroll
        for (int j = 0; j < 4; ++j) { s += val[i][j]; q += val[i][j] * val[i][j]; }
        red_s[(n0 + i) * 33 + to] = s;
        red_q[(n0 + i) * 33 + to] = q;
    }
    __syncthreads();
    if (tid < 32) {
        float s = 0.f, q = 0.f;
        for (int u = 0; u < 32; ++u) { s += red_s[tid * 33 + u]; q += red_q[tid * 33 + u]; }
        float mu = s / 128.f;
        float var = q / 128.f - mu * mu;
        mus[tid] = mu;
        rss[tid] = rsqrtf(var + 1e-5f);
    }
    __syncthreads();
    #pragma unroll
    for (int i = 0; i < 4; ++i) {
        float mu = mus[n0 + i], rs = rss[n0 + i];
        float4 o;
        o.x = (val[i][0] - mu) * rs * gj[0] + bj[0];
        o.y = (val[i][1] - mu) * rs * gj[1] + bj[1];
        o.z = (val[i][2] - mu) * rs * gj[2] + bj[2];
        o.w = (val[i][3] - mu) * rs * gj[3] + bj[3];
        *reinterpret_cast<float4*>(outp + (size_t)(row0 + n0 + i) * DD + o0) = o;
    }
}

extern "C" void kernel_launch(void* const* d_in, const int* in_sizes, int n_in,
                              void* d_out, int out_size, void* d_ws, size_t ws_size,
                              hipStream_t stream) {
    (void)in_sizes; (void)n_in; (void)out_size;
    const float* feat      = (const float*)d_in[0];
    const int*   esrc      = (const int*)d_in[1];
    const int*   edst      = (const int*)d_in[2];
    const float* ew        = (const float*)d_in[3];
    const float* clsW      = (const float*)d_in[4];
    const float* clsb      = (const float*)d_in[5];
    const float* attW1     = (const float*)d_in[6];
    const float* attb1     = (const float*)d_in[7];
    const float* attW2     = (const float*)d_in[8];
    const float* attb2     = (const float*)d_in[9];
    const float* att_bias  = (const float*)d_in[10];
    const float* relW      = (const float*)d_in[11];
    const float* relb      = (const float*)d_in[12];
    const float* gateW     = (const float*)d_in[13];
    const float* gateb     = (const float*)d_in[14];
    const float* view_pref = (const float*)d_in[15];
    const float* vattW1    = (const float*)d_in[16];
    const float* vattb1    = (const float*)d_in[17];
    const float* vattW2    = (const float*)d_in[18];
    const float* vattb2    = (const float*)d_in[19];
    const float* selfW     = (const float*)d_in[20];
    const float* selfb     = (const float*)d_in[21];
    const float* featW     = (const float*)d_in[22];
    const float* featb     = (const float*)d_in[23];
    const float* fusW      = (const float*)d_in[24];
    const float* fusb      = (const float*)d_in[25];
    const float* ln_g      = (const float*)d_in[26];
    const float* ln_b      = (const float*)d_in[27];

    // workspace layout (~120 MiB):
    u16*   aggB = (u16*)d_ws;                                   // [3][N][128] bf16
    float* wsum = (float*)(aggB + (size_t)VV * NN * DD);        // [3][N]
    float* natt = wsum + (size_t)VV * NN;                       // [N]
    float* vsc  = natt + NN;                                    // [3][N]
    float* Wsf  = vsc + (size_t)VV * NN;                        // [128][128]
    float* c1   = Wsf + DD * DD;                                // [128]
    u16* relWb  = (u16*)(c1 + DD);                              // [3][128][128] bf16
    u16* gateWb = relWb + (size_t)VV * DD * DD;                 // [3][128][128] bf16
    u16* WsfB   = gateWb + (size_t)VV * DD * DD;                // [128][128] bf16
    u16* featWB = WsfB + DD * DD;                               // [128][128] bf16
    u16* fusWbB = featWB + DD * DD;                             // [128][128] bf16
    int*   C    = (int*)(fusWbB + DD * DD);                     // [3N]
    int*   bs   = C + (size_t)TOT;                              // [NB]
    int*   bsrc = bs + NB;                                      // [3E]
    float* bw   = (float*)(bsrc + (size_t)VV * EE);             // [3E]
    u16* featB  = (u16*)(bw + (size_t)VV * EE);                 // [N][128] bf16
    size_t needed = (size_t)((char*)(featB + (size_t)NN * DD) - (char*)d_ws);

    float* outp  = (float*)d_out;
    float* probs = outp + (size_t)NN * DD;

    prep_kernel<<<129, 128, 0, stream>>>(selfW, selfb, fusW, fusb, Wsf, c1);
    label_kernel<<<3125, 256, 0, stream>>>(feat, clsW, clsb, attW1, attb1, attW2, attb2,
                                           att_bias, natt, probs);
    if (ws_size >= needed) {
        featconv_kernel<<<12500, 256, 0, stream>>>(feat, featB);
        wprep_kernel<<<384, 128, 0, stream>>>(relW, gateW, relWb, gateWb);
        wprep2_kernel<<<128, 128, 0, stream>>>(Wsf, featW, fusW, WsfB, featWB, fusWbB);
        hipMemsetAsync(C, 0, (size_t)TOT * sizeof(int), stream);
        count_kernel<<<(VV * EE + 255) / 256, 256, 0, stream>>>(edst, C);
        scanA_kernel<<<NB, 256, 0, stream>>>(C, bs);
        scanB_kernel<<<1, 1024, 0, stream>>>(bs);
        scanC_kernel<<<NB, 256, 0, stream>>>(C, bs);
        fill_kernel<<<(VV * EE + 255) / 256, 256, 0, stream>>>(esrc, edst, ew, C, bsrc, bw);
        gather_kernel<<<(VV * NN) / 4, 256, 0, stream>>>(featB, C, bsrc, bw, aggB, wsum);
        relgate_mfma_kernel<<<dim3(RGB, 3), 256, 0, stream>>>(relWb, relb, gateWb, gateb,
                                                              aggB, wsum);
        vatt_kernel<<<dim3(3125, 3), 128, 0, stream>>>(aggB, view_pref, vattW1, vattb1,
                                                       vattW2, vattb2, vsc);
        combine_kernel<<<12500, 256, 0, stream>>>(aggB, vsc, natt);
        final_mfma_kernel<<<RGB, 256, 0, stream>>>(featB, aggB, WsfB, featWB, fusWbB,
                                                   c1, featb, ln_g, ln_b, outp);
    } else {
        hipMemsetAsync(d_ws, 0,
                       (size_t)VV * NN * DD * sizeof(u16) + (size_t)VV * NN * sizeof(float),
                       stream);
        scatter_kernel<<<187500, 256, 0, stream>>>(esrc, edst, ew, feat, aggB, wsum);
        relgate_kernel<<<dim3(3125, 3), 256, 0, stream>>>(relW, relb, gateW, gateb, aggB, wsum);
        vatt_kernel<<<dim3(3125, 3), 128, 0, stream>>>(aggB, view_pref, vattW1, vattb1,
                                                       vattW2, vattb2, vsc);
        combine_kernel<<<12500, 256, 0, stream>>>(aggB, vsc, natt);
        final_kernel<<<3125, 256, 0, stream>>>(feat, aggB, Wsf, c1, fusW, featW, featb,
                                               ln_g, ln_b, outp);
    }
}

// Round 8
// 722.103 us; speedup vs baseline: 2.3066x; 1.1014x over previous
//
#include <hip/hip_runtime.h>
#include <hip/hip_bf16.h>

#define NN 100000
#define DD 128
#define VV 3
#define EE 500000
#define TOT (VV * NN)                 // 300000 rows
#define NB ((TOT + 255) / 256)        // 1172 scan blocks
#define RGB ((NN + 127) / 128)        // 782 mfma blocks

typedef unsigned short u16;
typedef unsigned int u32;
typedef short s8v __attribute__((ext_vector_type(8)));   // 8 bf16 (4 VGPRs)
typedef float f4v __attribute__((ext_vector_type(4)));   // MFMA accumulator

__device__ __forceinline__ float bf2f(u16 u) {
    return __uint_as_float(((u32)u) << 16);
}
__device__ __forceinline__ u16 f2bf(float f) {
    u32 x = __float_as_uint(f);
    u32 r = (x + 0x7fffu + ((x >> 16) & 1u)) >> 16;
    return (u16)r;
}

// packed bf16 atomic add (fallback path only)
__device__ __forceinline__ void atomAddBf16x2(u16* addr, float f0, float f1) {
#if __has_builtin(__builtin_amdgcn_global_atomic_fadd_v2bf16)
    typedef short v2s __attribute__((ext_vector_type(2)));
    typedef v2s __attribute__((address_space(1)))* v2s_gp;
    v2s v;
    v.x = (short)f2bf(f0);
    v.y = (short)f2bf(f1);
    __builtin_amdgcn_global_atomic_fadd_v2bf16((v2s_gp)(void*)addr, v);
#else
    u32* p = (u32*)addr;
    u32 old = *(volatile u32*)p;
    while (true) {
        float lo = bf2f((u16)(old & 0xffffu)) + f0;
        float hi = bf2f((u16)(old >> 16)) + f1;
        u32 nv = (u32)f2bf(lo) | ((u32)f2bf(hi) << 16);
        u32 prev = atomicCAS(p, old, nv);
        if (prev == old) break;
        old = prev;
    }
#endif
}

// ---- generic VALU GEMM accumulate (fallback + small kernels) ----
template<int XSTR, int WSTR>
__device__ __forceinline__ void gemm16(float acc[4][4], const float* Xs,
                                       const float* Ws, int n0, int o0, int kbase) {
    #pragma unroll 4
    for (int kk = 0; kk < 64; kk += 4) {
        float4 w0 = *reinterpret_cast<const float4*>(Ws + (kk + 0) * WSTR + o0);
        float4 w1 = *reinterpret_cast<const float4*>(Ws + (kk + 1) * WSTR + o0);
        float4 w2 = *reinterpret_cast<const float4*>(Ws + (kk + 2) * WSTR + o0);
        float4 w3 = *reinterpret_cast<const float4*>(Ws + (kk + 3) * WSTR + o0);
        #pragma unroll
        for (int i = 0; i < 4; ++i) {
            float4 x = *reinterpret_cast<const float4*>(Xs + (n0 + i) * XSTR + kbase + kk);
            acc[i][0] = fmaf(x.x, w0.x, fmaf(x.y, w1.x, fmaf(x.z, w2.x, fmaf(x.w, w3.x, acc[i][0]))));
            acc[i][1] = fmaf(x.x, w0.y, fmaf(x.y, w1.y, fmaf(x.z, w2.y, fmaf(x.w, w3.y, acc[i][1]))));
            acc[i][2] = fmaf(x.x, w0.z, fmaf(x.y, w1.z, fmaf(x.z, w2.z, fmaf(x.w, w3.z, acc[i][2]))));
            acc[i][3] = fmaf(x.x, w0.w, fmaf(x.y, w1.w, fmaf(x.z, w2.w, fmaf(x.w, w3.w, acc[i][3]))));
        }
    }
}

template<int WSTR, int NT>
__device__ __forceinline__ void stage_w_f32(float* Ws, const float* __restrict__ src, int tid) {
    #pragma unroll
    for (int rep = 0; rep < 2048 / NT; ++rep) {
        int flat = rep * NT + tid;
        int kk = flat >> 5;
        int c4 = flat & 31;
        float4 q = *reinterpret_cast<const float4*>(src + kk * 128 + c4 * 4);
        *reinterpret_cast<float4*>(Ws + kk * WSTR + c4 * 4) = q;
    }
}

template<int XSTR, int NT>
__device__ __forceinline__ void stage_x_f32(float* Xs, const float* __restrict__ src, int tid) {
    #pragma unroll
    for (int rep = 0; rep < 1024 / NT; ++rep) {
        int flat = rep * NT + tid;
        int n = flat >> 5;
        int c4 = flat & 31;
        float4 q = *reinterpret_cast<const float4*>(src + (size_t)n * 128 + c4 * 4);
        *reinterpret_cast<float4*>(Xs + n * XSTR + c4 * 4) = q;
    }
}

template<int XSTR, int NT>
__device__ __forceinline__ void stage_x_bf16(float* Xs, const u16* __restrict__ src, int tid) {
    #pragma unroll
    for (int rep = 0; rep < 512 / NT; ++rep) {
        int flat = rep * NT + tid;
        int n = flat >> 4;
        int c8 = flat & 15;
        uint4 q = *reinterpret_cast<const uint4*>(src + (size_t)n * 128 + c8 * 8);
        float* d = Xs + n * XSTR + c8 * 8;
        d[0] = bf2f((u16)(q.x & 0xffffu)); d[1] = bf2f((u16)(q.x >> 16));
        d[2] = bf2f((u16)(q.y & 0xffffu)); d[3] = bf2f((u16)(q.y >> 16));
        d[4] = bf2f((u16)(q.z & 0xffffu)); d[5] = bf2f((u16)(q.z >> 16));
        d[6] = bf2f((u16)(q.w & 0xffffu)); d[7] = bf2f((u16)(q.w >> 16));
    }
}

// ---------------- prep: Wsf = selfW @ fusW_top ; c1 = selfb @ fusW_top + fusb ----
__global__ void prep_kernel(const float* __restrict__ selfW, const float* __restrict__ selfb,
                            const float* __restrict__ fusW, const float* __restrict__ fusb,
                            float* __restrict__ Wsf, float* __restrict__ c1) {
    int o = threadIdx.x;
    int k = blockIdx.x;
    if (k < 128) {
        float acc = 0.f;
        for (int m = 0; m < 128; ++m)
            acc += selfW[k * 128 + m] * fusW[m * 128 + o];
        Wsf[k * 128 + o] = acc;
    } else {
        float acc = 0.f;
        for (int m = 0; m < 128; ++m)
            acc += selfb[m] * fusW[m * 128 + o];
        c1[o] = acc + fusb[o];
    }
}

// ---------------- wprep: transpose+convert relW/gateW -> bf16 [v][n][k] ----
__global__ __launch_bounds__(128) void wprep_kernel(
        const float* __restrict__ relW, const float* __restrict__ gateW,
        u16* __restrict__ relWb, u16* __restrict__ gateWb) {
    int k = threadIdx.x;
    int n = blockIdx.x & 127;
    int v = blockIdx.x >> 7;
    size_t o = ((size_t)v * 128 + n) * 128 + k;
    size_t i = ((size_t)v * 128 + k) * 128 + n;
    relWb[o]  = f2bf(relW[i]);
    gateWb[o] = f2bf(gateW[i]);
}

// ---------------- wprep2: bf16 n-major Wsf / featW / fusW_bot ----
__global__ __launch_bounds__(128) void wprep2_kernel(
        const float* __restrict__ Wsf, const float* __restrict__ featW,
        const float* __restrict__ fusW,
        u16* __restrict__ WsfB, u16* __restrict__ featWB, u16* __restrict__ fusWbB) {
    int k = threadIdx.x;
    int n = blockIdx.x;
    WsfB[n * 128 + k]   = f2bf(Wsf[k * 128 + n]);
    featWB[n * 128 + k] = f2bf(featW[k * 128 + n]);
    fusWbB[n * 128 + k] = f2bf(fusW[(size_t)(128 + k) * 128 + n]);
}

// ---------------- wprep3: attW1 [c][k][h] -> bf16 n-major [o=c*64+h][k] ----
__global__ __launch_bounds__(128) void wprep3_kernel(
        const float* __restrict__ attW1, u16* __restrict__ attW1B) {
    int k = threadIdx.x;
    int o = blockIdx.x;                 // 0..127
    int c = o >> 6, h = o & 63;
    attW1B[o * 128 + k] = f2bf(attW1[((size_t)c * 128 + k) * 64 + h]);
}

// ---------------- featconv: feat fp32 -> bf16 ----
__global__ __launch_bounds__(256) void featconv_kernel(
        const float* __restrict__ feat, u16* __restrict__ featB) {
    int t = blockIdx.x * 256 + threadIdx.x;   // 3.2M float4 chunks
    float4 q = *reinterpret_cast<const float4*>(feat + (size_t)t * 4);
    ushort4 r;
    r.x = f2bf(q.x); r.y = f2bf(q.y); r.z = f2bf(q.z); r.w = f2bf(q.w);
    *reinterpret_cast<ushort4*>(featB + (size_t)t * 4) = r;
}

// ================= CSR build (hierarchical scan) + gather =================

__global__ __launch_bounds__(256) void count_kernel(
        const int* __restrict__ edst, int* __restrict__ C) {
    int t = blockIdx.x * 256 + threadIdx.x;
    if (t >= VV * EE) return;
    int v = t / EE;
    atomicAdd(&C[v * NN + edst[t]], 1);
}

__global__ __launch_bounds__(256) void scanA_kernel(
        const int* __restrict__ C, int* __restrict__ bs) {
    int b = blockIdx.x, t = threadIdx.x;
    int i = b * 256 + t;
    int v = (i < TOT) ? C[i] : 0;
    __shared__ int s[256];
    s[t] = v;
    __syncthreads();
    #pragma unroll
    for (int off = 128; off > 0; off >>= 1) {
        if (t < off) s[t] += s[t + off];
        __syncthreads();
    }
    if (t == 0) bs[b] = s[0];
}

__global__ __launch_bounds__(1024) void scanB_kernel(int* __restrict__ bs) {
    __shared__ int s[2048];
    int t = threadIdx.x;
    int v0 = (t < NB) ? bs[t] : 0;
    int v1 = (t + 1024 < NB) ? bs[t + 1024] : 0;
    s[t] = v0; s[t + 1024] = v1;
    __syncthreads();
    #pragma unroll
    for (int off = 1; off < 2048; off <<= 1) {
        int x0 = (t >= off) ? s[t - off] : 0;
        int x1 = (t + 1024 >= off) ? s[t + 1024 - off] : 0;
        __syncthreads();
        s[t] += x0; s[t + 1024] += x1;
        __syncthreads();
    }
    if (t < NB) bs[t] = s[t] - v0;
    if (t + 1024 < NB) bs[t + 1024] = s[t + 1024] - v1;
}

__global__ __launch_bounds__(256) void scanC_kernel(
        int* __restrict__ C, const int* __restrict__ bs) {
    int b = blockIdx.x, t = threadIdx.x;
    int i = b * 256 + t;
    int v = (i < TOT) ? C[i] : 0;
    __shared__ int s[256];
    s[t] = v;
    __syncthreads();
    #pragma unroll
    for (int off = 1; off < 256; off <<= 1) {
        int x = (t >= off) ? s[t - off] : 0;
        __syncthreads();
        s[t] += x;
        __syncthreads();
    }
    if (i < TOT) C[i] = s[t] - v + bs[b];
}

// fill: packed (src, w) per bucket slot; C becomes inclusive row ends
__global__ __launch_bounds__(256) void fill_kernel(
        const int* __restrict__ esrc, const int* __restrict__ edst,
        const float* __restrict__ ew, int* __restrict__ C,
        int2* __restrict__ bsw) {
    int t = blockIdx.x * 256 + threadIdx.x;
    if (t >= VV * EE) return;
    int v = t / EE;
    int pos = atomicAdd(&C[v * NN + edst[t]], 1);
    int2 p;
    p.x = esrc[t];
    p.y = __float_as_int(ew[t]);
    bsw[pos] = p;
}

// one wave per (v,dst) row, unroll-4 to overlap the load chains
__global__ __launch_bounds__(256) void gather_kernel(
        const u16* __restrict__ featB, const int* __restrict__ C,
        const int2* __restrict__ bsw,
        u16* __restrict__ aggB, float* __restrict__ wsum) {
    int wid = (blockIdx.x * 256 + threadIdx.x) >> 6;
    int lane = threadIdx.x & 63;
    int end = C[wid];
    int start = (wid == 0) ? 0 : C[wid - 1];
    float a0 = 0.f, a1 = 0.f, wacc = 0.f;
    int e = start;
    for (; e + 4 <= end; e += 4) {
        int2 p0 = bsw[e], p1 = bsw[e + 1], p2 = bsw[e + 2], p3 = bsw[e + 3];
        u32 f0 = *reinterpret_cast<const u32*>(featB + (size_t)p0.x * DD + lane * 2);
        u32 f1 = *reinterpret_cast<const u32*>(featB + (size_t)p1.x * DD + lane * 2);
        u32 f2 = *reinterpret_cast<const u32*>(featB + (size_t)p2.x * DD + lane * 2);
        u32 f3 = *reinterpret_cast<const u32*>(featB + (size_t)p3.x * DD + lane * 2);
        float w0 = __int_as_float(p0.y), w1 = __int_as_float(p1.y);
        float w2 = __int_as_float(p2.y), w3 = __int_as_float(p3.y);
        a0 = fmaf(w0, bf2f((u16)(f0 & 0xffffu)), a0);
        a1 = fmaf(w0, bf2f((u16)(f0 >> 16)), a1);
        a0 = fmaf(w1, bf2f((u16)(f1 & 0xffffu)), a0);
        a1 = fmaf(w1, bf2f((u16)(f1 >> 16)), a1);
        a0 = fmaf(w2, bf2f((u16)(f2 & 0xffffu)), a0);
        a1 = fmaf(w2, bf2f((u16)(f2 >> 16)), a1);
        a0 = fmaf(w3, bf2f((u16)(f3 & 0xffffu)), a0);
        a1 = fmaf(w3, bf2f((u16)(f3 >> 16)), a1);
        wacc += (w0 + w1) + (w2 + w3);
    }
    for (; e < end; ++e) {
        int2 p = bsw[e];
        float w = __int_as_float(p.y);
        u32 f = *reinterpret_cast<const u32*>(featB + (size_t)p.x * DD + lane * 2);
        a0 = fmaf(w, bf2f((u16)(f & 0xffffu)), a0);
        a1 = fmaf(w, bf2f((u16)(f >> 16)), a1);
        wacc += w;
    }
    u32 packed = (u32)f2bf(a0) | ((u32)f2bf(a1) << 16);
    *reinterpret_cast<u32*>(aggB + (size_t)wid * DD + lane * 2) = packed;
    if (lane == 0) wsum[wid] = wacc;
}

// ================= fallback: atomic scatter (R3 path) =================
__global__ __launch_bounds__(256) void scatter_kernel(
        const int* __restrict__ esrc, const int* __restrict__ edst,
        const float* __restrict__ ew, const float* __restrict__ feat,
        u16* __restrict__ aggB, float* __restrict__ wsum) {
    long long t = (long long)blockIdx.x * 256 + threadIdx.x;
    int lane = (int)(t & 31);
    int eg = (int)(t >> 5);
    int v = eg / EE;
    int src = 0, dst = 0; float w = 0.f;
    if (lane == 0) {
        src = esrc[eg]; dst = edst[eg]; w = ew[eg];
    }
    src = __shfl(src, 0, 32);
    dst = __shfl(dst, 0, 32);
    w   = __shfl(w, 0, 32);
    const float* fr = feat + (size_t)src * DD + lane * 4;
    float4 q = *reinterpret_cast<const float4*>(fr);
    u16* outp = aggB + ((size_t)v * NN + dst) * DD + lane * 4;
    atomAddBf16x2(outp,     w * q.x, w * q.y);
    atomAddBf16x2(outp + 2, w * q.z, w * q.w);
    if (lane == 0) atomicAdd(wsum + v * NN + dst, w);
}

// ---------------- MFMA label attention: node_att + class_probs ----
__global__ __launch_bounds__(256) void label_mfma_kernel(
        const u16* __restrict__ featB, const u16* __restrict__ attW1B,
        const float* __restrict__ clsW, const float* __restrict__ clsb,
        const float* __restrict__ attb1, const float* __restrict__ attW2,
        const float* __restrict__ attb2, const float* __restrict__ att_bias,
        float* __restrict__ node_att, float* __restrict__ probs_out) {
    __shared__ u16 Xs[128][136];
    __shared__ u16 Wt[128][72];
    int tid = threadIdx.x;
    int wv = tid >> 6, lane = tid & 63;
    int quad = lane >> 4, l15 = lane & 15;
    int row0 = blockIdx.x * 128;

    #pragma unroll
    for (int rep = 0; rep < 8; ++rep) {
        int flat = rep * 256 + tid;
        int n = flat >> 4, c8 = flat & 15;
        int gr = row0 + n; if (gr >= NN) gr = NN - 1;
        uint4 q = *reinterpret_cast<const uint4*>(featB + (size_t)gr * DD + c8 * 8);
        *reinterpret_cast<uint4*>(&Xs[n][c8 * 8]) = q;
    }

    f4v acc[2][8];
    #pragma unroll
    for (int rt = 0; rt < 2; ++rt)
        #pragma unroll
        for (int c = 0; c < 8; ++c)
            acc[rt][c] = f4v{0.f, 0.f, 0.f, 0.f};

    #pragma unroll
    for (int h = 0; h < 2; ++h) {
        #pragma unroll
        for (int rep = 0; rep < 4; ++rep) {
            int flat = rep * 256 + tid;
            int n = flat >> 3, c8 = flat & 7;
            uint4 q = *reinterpret_cast<const uint4*>(attW1B + (size_t)n * DD + h * 64 + c8 * 8);
            *reinterpret_cast<uint4*>(&Wt[n][c8 * 8]) = q;
        }
        __syncthreads();
        #pragma unroll
        for (int t = 0; t < 2; ++t) {
            int kl = t * 32 + quad * 8;
            s8v a0 = *reinterpret_cast<const s8v*>(&Xs[wv * 32 + l15][h * 64 + kl]);
            s8v a1 = *reinterpret_cast<const s8v*>(&Xs[wv * 32 + 16 + l15][h * 64 + kl]);
            #pragma unroll
            for (int c = 0; c < 8; ++c) {
                s8v b = *reinterpret_cast<const s8v*>(&Wt[c * 16 + l15][kl]);
                acc[0][c] = __builtin_amdgcn_mfma_f32_16x16x32_bf16(a0, b, acc[0][c], 0, 0, 0);
                acc[1][c] = __builtin_amdgcn_mfma_f32_16x16x32_bf16(a1, b, acc[1][c], 0, 0, 0);
            }
        }
        __syncthreads();
    }

    // per-lane invariants
    float ab1[8], aw2[8];
    #pragma unroll
    for (int c = 0; c < 8; ++c) {
        int col = c * 16 + l15;
        ab1[c] = attb1[col];          // attb1 flat [2][64] == col
        aw2[c] = attW2[col];          // attW2 flat [2][64] == col
    }
    float cw0[8], cw1[8];
    #pragma unroll
    for (int j = 0; j < 8; ++j) {
        int k = l15 * 8 + j;
        cw0[j] = clsW[k * 2];
        cw1[j] = clsW[k * 2 + 1];
    }
    float cb0 = clsb[0], cb1 = clsb[1];
    float b20 = attb2[0], b21 = attb2[1];
    float abias = att_bias[0];

    #pragma unroll
    for (int rt = 0; rt < 2; ++rt)
        #pragma unroll
        for (int r = 0; r < 4; ++r) {
            int n = wv * 32 + rt * 16 + quad * 4 + r;
            int gr = row0 + n;
            // score partials per class
            float p0 = 0.f, p1 = 0.f;
            #pragma unroll
            for (int c = 0; c < 4; ++c) {
                float hv = acc[rt][c][r] + ab1[c];
                hv = hv > 0.f ? hv : 0.f;
                p0 += hv * aw2[c];
            }
            #pragma unroll
            for (int c = 4; c < 8; ++c) {
                float hv = acc[rt][c][r] + ab1[c];
                hv = hv > 0.f ? hv : 0.f;
                p1 += hv * aw2[c];
            }
            // logits from LDS feat row
            uint4 q = *reinterpret_cast<const uint4*>(&Xs[n][l15 * 8]);
            float f[8];
            f[0] = bf2f((u16)(q.x & 0xffffu)); f[1] = bf2f((u16)(q.x >> 16));
            f[2] = bf2f((u16)(q.y & 0xffffu)); f[3] = bf2f((u16)(q.y >> 16));
            f[4] = bf2f((u16)(q.z & 0xffffu)); f[5] = bf2f((u16)(q.z >> 16));
            f[6] = bf2f((u16)(q.w & 0xffffu)); f[7] = bf2f((u16)(q.w >> 16));
            float l0 = 0.f, l1 = 0.f;
            #pragma unroll
            for (int j = 0; j < 8; ++j) {
                l0 = fmaf(f[j], cw0[j], l0);
                l1 = fmaf(f[j], cw1[j], l1);
            }
            #pragma unroll
            for (int m = 1; m < 16; m <<= 1) {
                p0 += __shfl_xor(p0, m);
                p1 += __shfl_xor(p1, m);
                l0 += __shfl_xor(l0, m);
                l1 += __shfl_xor(l1, m);
            }
            if (l15 == 0 && gr < NN) {
                float s0 = 1.f / (1.f + expf(-(p0 + b20)));
                float s1 = 1.f / (1.f + expf(-(p1 + b21)));
                l0 += cb0; l1 += cb1;
                float mm = fmaxf(l0, l1);
                float e0 = expf(l0 - mm), e1 = expf(l1 - mm);
                float inv = 1.f / (e0 + e1);
                float q0 = e0 * inv, q1 = e1 * inv;
                node_att[gr] = q0 * s0 + q1 * s1 + abias;
                probs_out[gr * 2]     = q0;
                probs_out[gr * 2 + 1] = q1;
            }
        }
}

// ---------------- fallback VALU label ----
__global__ __launch_bounds__(256) void label_kernel(
        const float* __restrict__ feat, const float* __restrict__ clsW, const float* __restrict__ clsb,
        const float* __restrict__ attW1, const float* __restrict__ attb1,
        const float* __restrict__ attW2, const float* __restrict__ attb2,
        const float* __restrict__ att_bias,
        float* __restrict__ node_att, float* __restrict__ probs_out) {
    __shared__ float Xs[32][132];
    __shared__ float Ws[64][132];
    int tid = threadIdx.x;
    int row0 = blockIdx.x * 32;
    stage_x_f32<132, 256>(&Xs[0][0], feat + (size_t)row0 * DD, tid);
    int to = tid & 31, tn = tid >> 5;
    int o0 = to * 4, n0 = tn * 4;
    float acc[4][4] = {};
    for (int half = 0; half < 2; ++half) {
        __syncthreads();
        #pragma unroll
        for (int rep = 0; rep < 8; ++rep) {
            int flat = rep * 256 + tid;
            int kk = flat >> 5, o4 = flat & 31;
            int o = o4 * 4;
            int c = o >> 6, h = o & 63;
            int k = half * 64 + kk;
            float4 q = *reinterpret_cast<const float4*>(attW1 + (size_t)(c * 128 + k) * 64 + h);
            *reinterpret_cast<float4*>(&Ws[kk][o]) = q;
        }
        __syncthreads();
        gemm16<132, 132>(acc, &Xs[0][0], &Ws[0][0], n0, o0, half * 64);
    }
    int c = o0 >> 6, h0 = o0 & 63;
    float b1j[4], w2j[4];
    #pragma unroll
    for (int j = 0; j < 4; ++j) {
        b1j[j] = attb1[c * 64 + h0 + j];
        w2j[j] = attW2[c * 64 + h0 + j];
    }
    float part[4];
    #pragma unroll
    for (int i = 0; i < 4; ++i) {
        float s = 0.f;
        #pragma unroll
        for (int j = 0; j < 4; ++j) {
            float hv = acc[i][j] + b1j[j];
            hv = hv > 0.f ? hv : 0.f;
            s += hv * w2j[j];
        }
        part[i] = s;
    }
    __syncthreads();
    float* red = &Ws[0][0];          // [32][33]
    float* Ssc = red + 32 * 33;      // [32][2]
    float* Lsc = Ssc + 64;           // [32][2]
    #pragma unroll
    for (int i = 0; i < 4; ++i) red[(n0 + i) * 33 + to] = part[i];
    __syncthreads();
    if (tid < 64) {
        int n = tid >> 1, cc = tid & 1;
        float l = 0.f;
        for (int k = 0; k < 128; k += 4) {
            float4 x = *reinterpret_cast<const float4*>(&Xs[n][k]);
            l += x.x * clsW[(k + 0) * 2 + cc];
            l += x.y * clsW[(k + 1) * 2 + cc];
            l += x.z * clsW[(k + 2) * 2 + cc];
            l += x.w * clsW[(k + 3) * 2 + cc];
        }
        Lsc[n * 2 + cc] = l + clsb[cc];
        float s = 0.f;
        for (int u = 0; u < 16; ++u) s += red[n * 33 + cc * 16 + u];
        s += attb2[cc];
        Ssc[n * 2 + cc] = 1.f / (1.f + expf(-s));
    }
    __syncthreads();
    if (tid < 32) {
        int n = tid;
        float l0 = Lsc[n * 2], l1 = Lsc[n * 2 + 1];
        float m = fmaxf(l0, l1);
        float e0 = expf(l0 - m), e1 = expf(l1 - m);
        float inv = 1.f / (e0 + e1);
        float p0 = e0 * inv, p1 = e1 * inv;
        float na = p0 * Ssc[n * 2] + p1 * Ssc[n * 2 + 1] + att_bias[0];
        int row = row0 + n;
        node_att[row] = na;
        probs_out[row * 2]     = p0;
        probs_out[row * 2 + 1] = p1;
    }
}

// ---------------- MFMA relgate ----
__global__ __launch_bounds__(256) void relgate_mfma_kernel(
        const u16* __restrict__ relWb, const float* __restrict__ relb,
        const u16* __restrict__ gateWb, const float* __restrict__ gateb,
        u16* __restrict__ aggB, const float* __restrict__ wsum) {
    __shared__ u16 Xs[128][136];
    __shared__ u16 Wt[128][72];
    int tid = threadIdx.x;
    int wv = tid >> 6, lane = tid & 63;
    int quad = lane >> 4, l15 = lane & 15;
    int v = blockIdx.y;
    int row0 = blockIdx.x * 128;
    const size_t vbase = (size_t)v * NN;

    #pragma unroll
    for (int rep = 0; rep < 8; ++rep) {
        int flat = rep * 256 + tid;
        int n = flat >> 4, c8 = flat & 15;
        int gr = row0 + n; if (gr >= NN) gr = NN - 1;
        uint4 q = *reinterpret_cast<const uint4*>(aggB + (vbase + gr) * DD + c8 * 8);
        *reinterpret_cast<uint4*>(&Xs[n][c8 * 8]) = q;
    }

    f4v acc1[2][8], acc2[2][8];
    #pragma unroll
    for (int rt = 0; rt < 2; ++rt)
        #pragma unroll
        for (int c = 0; c < 8; ++c) {
            acc1[rt][c] = f4v{0.f, 0.f, 0.f, 0.f};
            acc2[rt][c] = f4v{0.f, 0.f, 0.f, 0.f};
        }

    const u16* W1 = relWb + (size_t)v * DD * DD;
    const u16* W2 = gateWb + (size_t)v * DD * DD;

    #pragma unroll
    for (int h = 0; h < 2; ++h) {
        #pragma unroll
        for (int rep = 0; rep < 4; ++rep) {
            int flat = rep * 256 + tid;
            int n = flat >> 3, c8 = flat & 7;
            uint4 q = *reinterpret_cast<const uint4*>(W1 + (size_t)n * DD + h * 64 + c8 * 8);
            *reinterpret_cast<uint4*>(&Wt[n][c8 * 8]) = q;
        }
        __syncthreads();
        #pragma unroll
        for (int t = 0; t < 2; ++t) {
            int kl = t * 32 + quad * 8;
            s8v a0 = *reinterpret_cast<const s8v*>(&Xs[wv * 32 + l15][h * 64 + kl]);
            s8v a1 = *reinterpret_cast<const s8v*>(&Xs[wv * 32 + 16 + l15][h * 64 + kl]);
            #pragma unroll
            for (int c = 0; c < 8; ++c) {
                s8v b = *reinterpret_cast<const s8v*>(&Wt[c * 16 + l15][kl]);
                acc1[0][c] = __builtin_amdgcn_mfma_f32_16x16x32_bf16(a0, b, acc1[0][c], 0, 0, 0);
                acc1[1][c] = __builtin_amdgcn_mfma_f32_16x16x32_bf16(a1, b, acc1[1][c], 0, 0, 0);
            }
        }
        __syncthreads();
    }

    float wsn[2][4], rb[8];
    #pragma unroll
    for (int rt = 0; rt < 2; ++rt)
        #pragma unroll
        for (int r = 0; r < 4; ++r) {
            int gr = row0 + wv * 32 + rt * 16 + quad * 4 + r;
            wsn[rt][r] = wsum[vbase + (gr < NN ? gr : NN - 1)];
        }
    #pragma unroll
    for (int c = 0; c < 8; ++c) rb[c] = relb[v * DD + c * 16 + l15];
    #pragma unroll
    for (int rt = 0; rt < 2; ++rt)
        #pragma unroll
        for (int c = 0; c < 8; ++c)
            #pragma unroll
            for (int r = 0; r < 4; ++r)
                acc1[rt][c][r] += wsn[rt][r] * rb[c];

    #pragma unroll
    for (int rt = 0; rt < 2; ++rt)
        #pragma unroll
        for (int c = 0; c < 8; ++c)
            #pragma unroll
            for (int r = 0; r < 4; ++r)
                Xs[wv * 32 + rt * 16 + quad * 4 + r][c * 16 + l15] = f2bf(acc1[rt][c][r]);
    __syncthreads();

    #pragma unroll
    for (int h = 0; h < 2; ++h) {
        #pragma unroll
        for (int rep = 0; rep < 4; ++rep) {
            int flat = rep * 256 + tid;
            int n = flat >> 3, c8 = flat & 7;
            uint4 q = *reinterpret_cast<const uint4*>(W2 + (size_t)n * DD + h * 64 + c8 * 8);
            *reinterpret_cast<uint4*>(&Wt[n][c8 * 8]) = q;
        }
        __syncthreads();
        #pragma unroll
        for (int t = 0; t < 2; ++t) {
            int kl = t * 32 + quad * 8;
            s8v a0 = *reinterpret_cast<const s8v*>(&Xs[wv * 32 + l15][h * 64 + kl]);
            s8v a1 = *reinterpret_cast<const s8v*>(&Xs[wv * 32 + 16 + l15][h * 64 + kl]);
            #pragma unroll
            for (int c = 0; c < 8; ++c) {
                s8v b = *reinterpret_cast<const s8v*>(&Wt[c * 16 + l15][kl]);
                acc2[0][c] = __builtin_amdgcn_mfma_f32_16x16x32_bf16(a0, b, acc2[0][c], 0, 0, 0);
                acc2[1][c] = __builtin_amdgcn_mfma_f32_16x16x32_bf16(a1, b, acc2[1][c], 0, 0, 0);
            }
        }
        __syncthreads();
    }

    float gb[8];
    #pragma unroll
    for (int c = 0; c < 8; ++c) gb[c] = gateb[v * DD + c * 16 + l15];
    #pragma unroll
    for (int rt = 0; rt < 2; ++rt)
        #pragma unroll
        for (int c = 0; c < 8; ++c)
            #pragma unroll
            for (int r = 0; r < 4; ++r) {
                float g = 1.f / (1.f + expf(-(acc2[rt][c][r] + gb[c])));
                Xs[wv * 32 + rt * 16 + quad * 4 + r][c * 16 + l15] = f2bf(g * acc1[rt][c][r]);
            }
    __syncthreads();
    #pragma unroll
    for (int rep = 0; rep < 8; ++rep) {
        int flat = rep * 256 + tid;
        int n = flat >> 4, c8 = flat & 15;
        int gr = row0 + n;
        if (gr < NN)
            *reinterpret_cast<uint4*>(aggB + (vbase + gr) * DD + c8 * 8) =
                *reinterpret_cast<const uint4*>(&Xs[n][c8 * 8]);
    }
}

// ---------------- fallback VALU relgate ----
__global__ __launch_bounds__(256) void relgate_kernel(
        const float* __restrict__ relW, const float* __restrict__ relb,
        const float* __restrict__ gateW, const float* __restrict__ gateb,
        u16* __restrict__ aggB, const float* __restrict__ wsum) {
    __shared__ float Xs[32][128];
    __shared__ float Ws[64][132];
    int tid = threadIdx.x;
    int v = blockIdx.y;
    int row0 = blockIdx.x * 32;
    u16* base = aggB + ((size_t)v * NN + row0) * DD;
    stage_x_bf16<128, 256>(&Xs[0][0], base, tid);
    int to = tid & 31, tn = tid >> 5;
    int o0 = to * 4, n0 = tn * 4;
    float acc[4][4] = {};
    const float* W1 = relW + (size_t)v * DD * DD;
    for (int half = 0; half < 2; ++half) {
        __syncthreads();
        stage_w_f32<132, 256>(&Ws[0][0], W1 + half * 64 * DD, tid);
        __syncthreads();
        gemm16<128, 132>(acc, &Xs[0][0], &Ws[0][0], n0, o0, half * 64);
    }
    float wsn[4], rb[4];
    #pragma unroll
    for (int i = 0; i < 4; ++i) wsn[i] = wsum[v * NN + row0 + n0 + i];
    #pragma unroll
    for (int j = 0; j < 4; ++j) rb[j] = relb[v * DD + o0 + j];
    #pragma unroll
    for (int i = 0; i < 4; ++i)
        #pragma unroll
        for (int j = 0; j < 4; ++j) acc[i][j] += wsn[i] * rb[j];
    __syncthreads();
    #pragma unroll
    for (int i = 0; i < 4; ++i)
        *reinterpret_cast<float4*>(&Xs[n0 + i][o0]) = make_float4(acc[i][0], acc[i][1], acc[i][2], acc[i][3]);
    float acc2[4][4] = {};
    const float* W2 = gateW + (size_t)v * DD * DD;
    for (int half = 0; half < 2; ++half) {
        __syncthreads();
        stage_w_f32<132, 256>(&Ws[0][0], W2 + half * 64 * DD, tid);
        __syncthreads();
        gemm16<128, 132>(acc2, &Xs[0][0], &Ws[0][0], n0, o0, half * 64);
    }
    float gb[4];
    #pragma unroll
    for (int j = 0; j < 4; ++j) gb[j] = gateb[v * DD + o0 + j];
    #pragma unroll
    for (int i = 0; i < 4; ++i) {
        float g0 = 1.f / (1.f + expf(-(acc2[i][0] + gb[0])));
        float g1 = 1.f / (1.f + expf(-(acc2[i][1] + gb[1])));
        float g2 = 1.f / (1.f + expf(-(acc2[i][2] + gb[2])));
        float g3 = 1.f / (1.f + expf(-(acc2[i][3] + gb[3])));
        ushort4 r;
        r.x = f2bf(g0 * acc[i][0]); r.y = f2bf(g1 * acc[i][1]);
        r.z = f2bf(g2 * acc[i][2]); r.w = f2bf(g3 * acc[i][3]);
        *reinterpret_cast<ushort4*>(base + (size_t)(n0 + i) * DD + o0) = r;
    }
}

// ---------------- view attention scores ----
__global__ __launch_bounds__(128) void vatt_kernel(
        const u16* __restrict__ aggB, const float* __restrict__ view_pref,
        const float* __restrict__ vattW1, const float* __restrict__ vattb1,
        const float* __restrict__ vattW2, const float* __restrict__ vattb2,
        float* __restrict__ vscores) {
    __shared__ float Xs[32][132];
    __shared__ float Ws[128][68];
    int tid = threadIdx.x;
    int v = blockIdx.y;
    int row0 = blockIdx.x * 32;
    const u16* base = aggB + ((size_t)v * NN + row0) * DD;
    #pragma unroll
    for (int rep = 0; rep < 4; ++rep) {
        int flat = rep * 128 + tid;
        int n = flat >> 4, c8 = flat & 15;
        uint4 q = *reinterpret_cast<const uint4*>(base + (size_t)n * DD + c8 * 8);
        float4 pa = *reinterpret_cast<const float4*>(view_pref + v * DD + c8 * 8);
        float4 pb = *reinterpret_cast<const float4*>(view_pref + v * DD + c8 * 8 + 4);
        float* d = &Xs[n][c8 * 8];
        d[0] = bf2f((u16)(q.x & 0xffffu)) * pa.x; d[1] = bf2f((u16)(q.x >> 16)) * pa.y;
        d[2] = bf2f((u16)(q.y & 0xffffu)) * pa.z; d[3] = bf2f((u16)(q.y >> 16)) * pa.w;
        d[4] = bf2f((u16)(q.z & 0xffffu)) * pb.x; d[5] = bf2f((u16)(q.z >> 16)) * pb.y;
        d[6] = bf2f((u16)(q.w & 0xffffu)) * pb.z; d[7] = bf2f((u16)(q.w >> 16)) * pb.w;
    }
    #pragma unroll
    for (int rep = 0; rep < 16; ++rep) {
        int flat = rep * 128 + tid;
        int k = flat >> 4, c4 = flat & 15;
        float4 q = *reinterpret_cast<const float4*>(vattW1 + k * 64 + c4 * 4);
        *reinterpret_cast<float4*>(&Ws[k][c4 * 4]) = q;
    }
    __syncthreads();
    int to = tid & 15, tn = tid >> 4;
    int o0 = to * 4, n0 = tn * 4;
    float acc[4][4] = {};
    gemm16<132, 68>(acc, &Xs[0][0], &Ws[0][0], n0, o0, 0);
    gemm16<132, 68>(acc, &Xs[0][0], &Ws[64][0], n0, o0, 64);
    float b1[4], w2[4];
    #pragma unroll
    for (int j = 0; j < 4; ++j) {
        b1[j] = vattb1[o0 + j];
        w2[j] = vattW2[o0 + j];
    }
    float part[4];
    #pragma unroll
    for (int i = 0; i < 4; ++i) {
        float s = 0.f;
        #pragma unroll
        for (int j = 0; j < 4; ++j) {
            float hv = acc[i][j] + b1[j];
            hv = hv > 0.f ? hv : 0.f;
            s += hv * w2[j];
        }
        part[i] = s;
    }
    __syncthreads();
    float* red = &Ws[0][0];   // [32][17]
    #pragma unroll
    for (int i = 0; i < 4; ++i) red[(n0 + i) * 17 + to] = part[i];
    __syncthreads();
    if (tid < 32) {
        float s = 0.f;
        for (int u = 0; u < 16; ++u) s += red[tid * 17 + u];
        vscores[(size_t)v * NN + row0 + tid] = s + vattb2[0];
    }
}

// ---------------- combine ----
__global__ __launch_bounds__(256) void combine_kernel(
        u16* __restrict__ aggB, const float* __restrict__ vscores,
        const float* __restrict__ node_att) {
    int t = blockIdx.x * 256 + threadIdx.x;
    int n = t >> 5, c4 = t & 31;
    float s0 = vscores[n], s1 = vscores[NN + n], s2 = vscores[2 * NN + n];
    float m = fmaxf(s0, fmaxf(s1, s2));
    float e0 = expf(s0 - m), e1 = expf(s1 - m), e2 = expf(s2 - m);
    float inv = 1.f / (e0 + e1 + e2);
    float w0 = e0 * inv, w1 = e1 * inv, w2 = e2 * inv;
    float na = node_att[n];
    size_t off = (size_t)n * DD + c4 * 4;
    ushort4 q0 = *reinterpret_cast<const ushort4*>(aggB + off);
    ushort4 q1 = *reinterpret_cast<const ushort4*>(aggB + (size_t)NN * DD + off);
    ushort4 q2 = *reinterpret_cast<const ushort4*>(aggB + 2 * (size_t)NN * DD + off);
    ushort4 r;
    r.x = f2bf((bf2f(q0.x) * w0 + bf2f(q1.x) * w1 + bf2f(q2.x) * w2) * na);
    r.y = f2bf((bf2f(q0.y) * w0 + bf2f(q1.y) * w1 + bf2f(q2.y) * w2) * na);
    r.z = f2bf((bf2f(q0.z) * w0 + bf2f(q1.z) * w1 + bf2f(q2.z) * w2) * na);
    r.w = f2bf((bf2f(q0.w) * w0 + bf2f(q1.w) * w1 + bf2f(q2.w) * w2) * na);
    *reinterpret_cast<ushort4*>(aggB + off) = r;
}

// ---------------- MFMA final ----
__global__ __launch_bounds__(256) void final_mfma_kernel(
        const u16* __restrict__ featB, const u16* __restrict__ weightedB,
        const u16* __restrict__ WsfB, const u16* __restrict__ featWB,
        const u16* __restrict__ fusWbB,
        const float* __restrict__ c1, const float* __restrict__ featb,
        const float* __restrict__ ln_g, const float* __restrict__ ln_b,
        float* __restrict__ outp) {
    __shared__ u16 Xs[128][136];
    __shared__ u16 Wt[128][72];
    int tid = threadIdx.x;
    int wv = tid >> 6, lane = tid & 63;
    int quad = lane >> 4, l15 = lane & 15;
    int row0 = blockIdx.x * 128;

    #pragma unroll
    for (int rep = 0; rep < 8; ++rep) {
        int flat = rep * 256 + tid;
        int n = flat >> 4, c8 = flat & 15;
        int gr = row0 + n; if (gr >= NN) gr = NN - 1;
        uint4 q = *reinterpret_cast<const uint4*>(featB + (size_t)gr * DD + c8 * 8);
        *reinterpret_cast<uint4*>(&Xs[n][c8 * 8]) = q;
    }

    f4v acc1[2][8], acc2[2][8];
    #pragma unroll
    for (int rt = 0; rt < 2; ++rt)
        #pragma unroll
        for (int c = 0; c < 8; ++c) {
            acc1[rt][c] = f4v{0.f, 0.f, 0.f, 0.f};
            acc2[rt][c] = f4v{0.f, 0.f, 0.f, 0.f};
        }

    #pragma unroll
    for (int h = 0; h < 2; ++h) {
        #pragma unroll
        for (int rep = 0; rep < 4; ++rep) {
            int flat = rep * 256 + tid;
            int n = flat >> 3, c8 = flat & 7;
            uint4 q = *reinterpret_cast<const uint4*>(WsfB + (size_t)n * DD + h * 64 + c8 * 8);
            *reinterpret_cast<uint4*>(&Wt[n][c8 * 8]) = q;
        }
        __syncthreads();
        #pragma unroll
        for (int t = 0; t < 2; ++t) {
            int kl = t * 32 + quad * 8;
            s8v a0 = *reinterpret_cast<const s8v*>(&Xs[wv * 32 + l15][h * 64 + kl]);
            s8v a1 = *reinterpret_cast<const s8v*>(&Xs[wv * 32 + 16 + l15][h * 64 + kl]);
            #pragma unroll
            for (int c = 0; c < 8; ++c) {
                s8v b = *reinterpret_cast<const s8v*>(&Wt[c * 16 + l15][kl]);
                acc1[0][c] = __builtin_amdgcn_mfma_f32_16x16x32_bf16(a0, b, acc1[0][c], 0, 0, 0);
                acc1[1][c] = __builtin_amdgcn_mfma_f32_16x16x32_bf16(a1, b, acc1[1][c], 0, 0, 0);
            }
        }
        __syncthreads();
        #pragma unroll
        for (int rep = 0; rep < 4; ++rep) {
            int flat = rep * 256 + tid;
            int n = flat >> 3, c8 = flat & 7;
            uint4 q = *reinterpret_cast<const uint4*>(featWB + (size_t)n * DD + h * 64 + c8 * 8);
            *reinterpret_cast<uint4*>(&Wt[n][c8 * 8]) = q;
        }
        __syncthreads();
        #pragma unroll
        for (int t = 0; t < 2; ++t) {
            int kl = t * 32 + quad * 8;
            s8v a0 = *reinterpret_cast<const s8v*>(&Xs[wv * 32 + l15][h * 64 + kl]);
            s8v a1 = *reinterpret_cast<const s8v*>(&Xs[wv * 32 + 16 + l15][h * 64 + kl]);
            #pragma unroll
            for (int c = 0; c < 8; ++c) {
                s8v b = *reinterpret_cast<const s8v*>(&Wt[c * 16 + l15][kl]);
                acc2[0][c] = __builtin_amdgcn_mfma_f32_16x16x32_bf16(a0, b, acc2[0][c], 0, 0, 0);
                acc2[1][c] = __builtin_amdgcn_mfma_f32_16x16x32_bf16(a1, b, acc2[1][c], 0, 0, 0);
            }
        }
        __syncthreads();
    }

    #pragma unroll
    for (int rep = 0; rep < 8; ++rep) {
        int flat = rep * 256 + tid;
        int n = flat >> 4, c8 = flat & 15;
        int gr = row0 + n; if (gr >= NN) gr = NN - 1;
        uint4 q = *reinterpret_cast<const uint4*>(weightedB + (size_t)gr * DD + c8 * 8);
        *reinterpret_cast<uint4*>(&Xs[n][c8 * 8]) = q;
    }
    #pragma unroll
    for (int h = 0; h < 2; ++h) {
        #pragma unroll
        for (int rep = 0; rep < 4; ++rep) {
            int flat = rep * 256 + tid;
            int n = flat >> 3, c8 = flat & 7;
            uint4 q = *reinterpret_cast<const uint4*>(fusWbB + (size_t)n * DD + h * 64 + c8 * 8);
            *reinterpret_cast<uint4*>(&Wt[n][c8 * 8]) = q;
        }
        __syncthreads();
        #pragma unroll
        for (int t = 0; t < 2; ++t) {
            int kl = t * 32 + quad * 8;
            s8v a0 = *reinterpret_cast<const s8v*>(&Xs[wv * 32 + l15][h * 64 + kl]);
            s8v a1 = *reinterpret_cast<const s8v*>(&Xs[wv * 32 + 16 + l15][h * 64 + kl]);
            #pragma unroll
            for (int c = 0; c < 8; ++c) {
                s8v b = *reinterpret_cast<const s8v*>(&Wt[c * 16 + l15][kl]);
                acc1[0][c] = __builtin_amdgcn_mfma_f32_16x16x32_bf16(a0, b, acc1[0][c], 0, 0, 0);
                acc1[1][c] = __builtin_amdgcn_mfma_f32_16x16x32_bf16(a1, b, acc1[1][c], 0, 0, 0);
            }
        }
        __syncthreads();
    }

    float c1j[8], fbj[8], gj[8], bj[8];
    #pragma unroll
    for (int c = 0; c < 8; ++c) {
        int col = c * 16 + l15;
        c1j[c] = c1[col];
        fbj[c] = featb[col];
        gj[c]  = ln_g[col];
        bj[c]  = ln_b[col];
    }
    #pragma unroll
    for (int rt = 0; rt < 2; ++rt)
        #pragma unroll
        for (int c = 0; c < 8; ++c)
            #pragma unroll
            for (int r = 0; r < 4; ++r) {
                float f = acc1[rt][c][r] + c1j[c];
                f = f > 0.f ? f : 0.f;
                acc1[rt][c][r] = f + acc2[rt][c][r] + fbj[c];
            }
    #pragma unroll
    for (int rt = 0; rt < 2; ++rt)
        #pragma unroll
        for (int r = 0; r < 4; ++r) {
            float s = 0.f, q = 0.f;
            #pragma unroll
            for (int c = 0; c < 8; ++c) {
                float x = acc1[rt][c][r];
                s += x; q += x * x;
            }
            #pragma unroll
            for (int m = 1; m < 16; m <<= 1) {
                s += __shfl_xor(s, m);
                q += __shfl_xor(q, m);
            }
            float mu = s * (1.f / 128.f);
            float var = q * (1.f / 128.f) - mu * mu;
            float rs = rsqrtf(var + 1e-5f);
            int gr = row0 + wv * 32 + rt * 16 + quad * 4 + r;
            if (gr < NN) {
                #pragma unroll
                for (int c = 0; c < 8; ++c)
                    outp[(size_t)gr * DD + c * 16 + l15] =
                        (acc1[rt][c][r] - mu) * rs * gj[c] + bj[c];
            }
        }
}

// ---------------- fallback VALU final ----
__global__ __launch_bounds__(256) void final_kernel(
        const float* __restrict__ feat, const u16* __restrict__ weightedB,
        const float* __restrict__ Wsf, const float* __restrict__ c1,
        const float* __restrict__ fusW, const float* __restrict__ featW,
        const float* __restrict__ featb, const float* __restrict__ ln_g,
        const float* __restrict__ ln_b, float* __restrict__ outp) {
    __shared__ float Xs[32][128];
    __shared__ float Ws[64][128];
    int tid = threadIdx.x;
    int row0 = blockIdx.x * 32;
    stage_x_f32<128, 256>(&Xs[0][0], feat + (size_t)row0 * DD, tid);
    int to = tid & 31, tn = tid >> 5;
    int o0 = to * 4, n0 = tn * 4;
    float acc1[4][4] = {}, acc2[4][4] = {};
    for (int half = 0; half < 2; ++half) {
        __syncthreads();
        stage_w_f32<128, 256>(&Ws[0][0], Wsf + half * 64 * 128, tid);
        __syncthreads();
        gemm16<128, 128>(acc1, &Xs[0][0], &Ws[0][0], n0, o0, half * 64);
    }
    for (int half = 0; half < 2; ++half) {
        __syncthreads();
        stage_w_f32<128, 256>(&Ws[0][0], featW + half * 64 * 128, tid);
        __syncthreads();
        gemm16<128, 128>(acc2, &Xs[0][0], &Ws[0][0], n0, o0, half * 64);
    }
    __syncthreads();
    stage_x_bf16<128, 256>(&Xs[0][0], weightedB + (size_t)row0 * DD, tid);
    for (int half = 0; half < 2; ++half) {
        __syncthreads();
        stage_w_f32<128, 256>(&Ws[0][0], fusW + (size_t)(128 + half * 64) * 128, tid);
        __syncthreads();
        gemm16<128, 128>(acc1, &Xs[0][0], &Ws[0][0], n0, o0, half * 64);
    }
    float c1j[4], fbj[4], gj[4], bj[4];
    #pragma unroll
    for (int j = 0; j < 4; ++j) {
        c1j[j] = c1[o0 + j];
        fbj[j] = featb[o0 + j];
        gj[j]  = ln_g[o0 + j];
        bj[j]  = ln_b[o0 + j];
    }
    float val[4][4];
    #pragma unroll
    for (int i = 0; i < 4; ++i)
        #pragma unroll
        for (int j = 0; j < 4; ++j) {
            float f = acc1[i][j] + c1j[j];
            f = f > 0.f ? f : 0.f;
            val[i][j] = f + acc2[i][j] + fbj[j];
        }
    __syncthreads();
    float* red_s = &Ws[0][0];
    float* red_q = red_s + 32 * 33;
    float* mus   = red_q + 32 * 33;
    float* rss   = mus + 32;
    #pragma unroll
    for (int i = 0; i < 4; ++i) {
        float s = 0.f, q = 0.f;
        #pragma unroll
        for (int j = 0; j < 4; ++j) { s += val[i][j]; q += val[i][j] * val[i][j]; }
        red_s[(n0 + i) * 33 + to] = s;
        red_q[(n0 + i) * 33 + to] = q;
    }
    __syncthreads();
    if (tid < 32) {
        float s = 0.f, q = 0.f;
        for (int u = 0; u < 32; ++u) { s += red_s[tid * 33 + u]; q += red_q[tid * 33 + u]; }
        float mu = s / 128.f;
        float var = q / 128.f - mu * mu;
        mus[tid] = mu;
        rss[tid] = rsqrtf(var + 1e-5f);
    }
    __syncthreads();
    #pragma unroll
    for (int i = 0; i < 4; ++i) {
        float mu = mus[n0 + i], rs = rss[n0 + i];
        float4 o;
        o.x = (val[i][0] - mu) * rs * gj[0] + bj[0];
        o.y = (val[i][1] - mu) * rs * gj[1] + bj[1];
        o.z = (val[i][2] - mu) * rs * gj[2] + bj[2];
        o.w = (val[i][3] - mu) * rs * gj[3] + bj[3];
        *reinterpret_cast<float4*>(outp + (size_t)(row0 + n0 + i) * DD + o0) = o;
    }
}

extern "C" void kernel_launch(void* const* d_in, const int* in_sizes, int n_in,
                              void* d_out, int out_size, void* d_ws, size_t ws_size,
                              hipStream_t stream) {
    (void)in_sizes; (void)n_in; (void)out_size;
    const float* feat      = (const float*)d_in[0];
    const int*   esrc      = (const int*)d_in[1];
    const int*   edst      = (const int*)d_in[2];
    const float* ew        = (const float*)d_in[3];
    const float* clsW      = (const float*)d_in[4];
    const float* clsb      = (const float*)d_in[5];
    const float* attW1     = (const float*)d_in[6];
    const float* attb1     = (const float*)d_in[7];
    const float* attW2     = (const float*)d_in[8];
    const float* attb2     = (const float*)d_in[9];
    const float* att_bias  = (const float*)d_in[10];
    const float* relW      = (const float*)d_in[11];
    const float* relb      = (const float*)d_in[12];
    const float* gateW     = (const float*)d_in[13];
    const float* gateb     = (const float*)d_in[14];
    const float* view_pref = (const float*)d_in[15];
    const float* vattW1    = (const float*)d_in[16];
    const float* vattb1    = (const float*)d_in[17];
    const float* vattW2    = (const float*)d_in[18];
    const float* vattb2    = (const float*)d_in[19];
    const float* selfW     = (const float*)d_in[20];
    const float* selfb     = (const float*)d_in[21];
    const float* featW     = (const float*)d_in[22];
    const float* featb     = (const float*)d_in[23];
    const float* fusW      = (const float*)d_in[24];
    const float* fusb      = (const float*)d_in[25];
    const float* ln_g      = (const float*)d_in[26];
    const float* ln_b      = (const float*)d_in[27];

    // workspace layout (~120 MiB):
    u16*   aggB = (u16*)d_ws;                                   // [3][N][128] bf16
    float* wsum = (float*)(aggB + (size_t)VV * NN * DD);        // [3][N]
    float* natt = wsum + (size_t)VV * NN;                       // [N]
    float* vsc  = natt + NN;                                    // [3][N]
    float* Wsf  = vsc + (size_t)VV * NN;                        // [128][128]
    float* c1   = Wsf + DD * DD;                                // [128]
    u16* relWb  = (u16*)(c1 + DD);                              // [3][128][128] bf16
    u16* gateWb = relWb + (size_t)VV * DD * DD;                 // [3][128][128] bf16
    u16* WsfB   = gateWb + (size_t)VV * DD * DD;                // [128][128] bf16
    u16* featWB = WsfB + DD * DD;                               // [128][128] bf16
    u16* fusWbB = featWB + DD * DD;                             // [128][128] bf16
    u16* attW1B = fusWbB + DD * DD;                             // [128][128] bf16
    int*   C    = (int*)(attW1B + DD * DD);                     // [3N]
    int*   bs   = C + (size_t)TOT;                              // [NB]
    int2*  bsw  = (int2*)(bs + NB + 1);                         // [3E] packed (src,w), 8B aligned
    u16* featB  = (u16*)(bsw + (size_t)VV * EE);                // [N][128] bf16
    size_t needed = (size_t)((char*)(featB + (size_t)NN * DD) - (char*)d_ws);

    float* outp  = (float*)d_out;
    float* probs = outp + (size_t)NN * DD;

    prep_kernel<<<129, 128, 0, stream>>>(selfW, selfb, fusW, fusb, Wsf, c1);
    if (ws_size >= needed) {
        featconv_kernel<<<12500, 256, 0, stream>>>(feat, featB);
        wprep_kernel<<<384, 128, 0, stream>>>(relW, gateW, relWb, gateWb);
        wprep2_kernel<<<128, 128, 0, stream>>>(Wsf, featW, fusW, WsfB, featWB, fusWbB);
        wprep3_kernel<<<128, 128, 0, stream>>>(attW1, attW1B);
        label_mfma_kernel<<<RGB, 256, 0, stream>>>(featB, attW1B, clsW, clsb, attb1,
                                                   attW2, attb2, att_bias, natt, probs);
        hipMemsetAsync(C, 0, (size_t)TOT * sizeof(int), stream);
        count_kernel<<<(VV * EE + 255) / 256, 256, 0, stream>>>(edst, C);
        scanA_kernel<<<NB, 256, 0, stream>>>(C, bs);
        scanB_kernel<<<1, 1024, 0, stream>>>(bs);
        scanC_kernel<<<NB, 256, 0, stream>>>(C, bs);
        fill_kernel<<<(VV * EE + 255) / 256, 256, 0, stream>>>(esrc, edst, ew, C, bsw);
        gather_kernel<<<(VV * NN) / 4, 256, 0, stream>>>(featB, C, bsw, aggB, wsum);
        relgate_mfma_kernel<<<dim3(RGB, 3), 256, 0, stream>>>(relWb, relb, gateWb, gateb,
                                                              aggB, wsum);
        vatt_kernel<<<dim3(3125, 3), 128, 0, stream>>>(aggB, view_pref, vattW1, vattb1,
                                                       vattW2, vattb2, vsc);
        combine_kernel<<<12500, 256, 0, stream>>>(aggB, vsc, natt);
        final_mfma_kernel<<<RGB, 256, 0, stream>>>(featB, aggB, WsfB, featWB, fusWbB,
                                                   c1, featb, ln_g, ln_b, outp);
    } else {
        label_kernel<<<3125, 256, 0, stream>>>(feat, clsW, clsb, attW1, attb1, attW2, attb2,
                                               att_bias, natt, probs);
        hipMemsetAsync(d_ws, 0,
                       (size_t)VV * NN * DD * sizeof(u16) + (size_t)VV * NN * sizeof(float),
                       stream);
        scatter_kernel<<<187500, 256, 0, stream>>>(esrc, edst, ew, feat, aggB, wsum);
        relgate_kernel<<<dim3(3125, 3), 256, 0, stream>>>(relW, relb, gateW, gateb, aggB, wsum);
        vatt_kernel<<<dim3(3125, 3), 128, 0, stream>>>(aggB, view_pref, vattW1, vattb1,
                                                       vattW2, vattb2, vsc);
        combine_kernel<<<12500, 256, 0, stream>>>(aggB, vsc, natt);
        final_kernel<<<3125, 256, 0, stream>>>(feat, aggB, Wsf, c1, fusW, featW, featb,
                                               ln_g, ln_b, outp);
    }
}

// Round 9
// 674.044 us; speedup vs baseline: 2.4711x; 1.0713x over previous
//
#include <hip/hip_runtime.h>
#include <hip/hip_bf16.h>

#define NN 100000
#define DD 128
#define VV 3
#define EE 500000
#define TOT (VV * NN)                 // 300000 rows
#define NB ((TOT + 255) / 256)        // 1172 scan blocks
#define RGB ((NN + 127) / 128)        // 782 mfma blocks

typedef unsigned short u16;
typedef unsigned int u32;
typedef short s8v __attribute__((ext_vector_type(8)));   // 8 bf16 (4 VGPRs)
typedef float f4v __attribute__((ext_vector_type(4)));   // MFMA accumulator

__device__ __forceinline__ float bf2f(u16 u) {
    return __uint_as_float(((u32)u) << 16);
}
__device__ __forceinline__ u16 f2bf(float f) {
    u32 x = __float_as_uint(f);
    u32 r = (x + 0x7fffu + ((x >> 16) & 1u)) >> 16;
    return (u16)r;
}

// packed bf16 atomic add (fallback path only)
__device__ __forceinline__ void atomAddBf16x2(u16* addr, float f0, float f1) {
#if __has_builtin(__builtin_amdgcn_global_atomic_fadd_v2bf16)
    typedef short v2s __attribute__((ext_vector_type(2)));
    typedef v2s __attribute__((address_space(1)))* v2s_gp;
    v2s v;
    v.x = (short)f2bf(f0);
    v.y = (short)f2bf(f1);
    __builtin_amdgcn_global_atomic_fadd_v2bf16((v2s_gp)(void*)addr, v);
#else
    u32* p = (u32*)addr;
    u32 old = *(volatile u32*)p;
    while (true) {
        float lo = bf2f((u16)(old & 0xffffu)) + f0;
        float hi = bf2f((u16)(old >> 16)) + f1;
        u32 nv = (u32)f2bf(lo) | ((u32)f2bf(hi) << 16);
        u32 prev = atomicCAS(p, old, nv);
        if (prev == old) break;
        old = prev;
    }
#endif
}

// ---- generic VALU GEMM accumulate (fallback path) ----
template<int XSTR, int WSTR>
__device__ __forceinline__ void gemm16(float acc[4][4], const float* Xs,
                                       const float* Ws, int n0, int o0, int kbase) {
    #pragma unroll 4
    for (int kk = 0; kk < 64; kk += 4) {
        float4 w0 = *reinterpret_cast<const float4*>(Ws + (kk + 0) * WSTR + o0);
        float4 w1 = *reinterpret_cast<const float4*>(Ws + (kk + 1) * WSTR + o0);
        float4 w2 = *reinterpret_cast<const float4*>(Ws + (kk + 2) * WSTR + o0);
        float4 w3 = *reinterpret_cast<const float4*>(Ws + (kk + 3) * WSTR + o0);
        #pragma unroll
        for (int i = 0; i < 4; ++i) {
            float4 x = *reinterpret_cast<const float4*>(Xs + (n0 + i) * XSTR + kbase + kk);
            acc[i][0] = fmaf(x.x, w0.x, fmaf(x.y, w1.x, fmaf(x.z, w2.x, fmaf(x.w, w3.x, acc[i][0]))));
            acc[i][1] = fmaf(x.x, w0.y, fmaf(x.y, w1.y, fmaf(x.z, w2.y, fmaf(x.w, w3.y, acc[i][1]))));
            acc[i][2] = fmaf(x.x, w0.z, fmaf(x.y, w1.z, fmaf(x.z, w2.z, fmaf(x.w, w3.z, acc[i][2]))));
            acc[i][3] = fmaf(x.x, w0.w, fmaf(x.y, w1.w, fmaf(x.z, w2.w, fmaf(x.w, w3.w, acc[i][3]))));
        }
    }
}

template<int WSTR, int NT>
__device__ __forceinline__ void stage_w_f32(float* Ws, const float* __restrict__ src, int tid) {
    #pragma unroll
    for (int rep = 0; rep < 2048 / NT; ++rep) {
        int flat = rep * NT + tid;
        int kk = flat >> 5;
        int c4 = flat & 31;
        float4 q = *reinterpret_cast<const float4*>(src + kk * 128 + c4 * 4);
        *reinterpret_cast<float4*>(Ws + kk * WSTR + c4 * 4) = q;
    }
}

template<int XSTR, int NT>
__device__ __forceinline__ void stage_x_f32(float* Xs, const float* __restrict__ src, int tid) {
    #pragma unroll
    for (int rep = 0; rep < 1024 / NT; ++rep) {
        int flat = rep * NT + tid;
        int n = flat >> 5;
        int c4 = flat & 31;
        float4 q = *reinterpret_cast<const float4*>(src + (size_t)n * 128 + c4 * 4);
        *reinterpret_cast<float4*>(Xs + n * XSTR + c4 * 4) = q;
    }
}

template<int XSTR, int NT>
__device__ __forceinline__ void stage_x_bf16(float* Xs, const u16* __restrict__ src, int tid) {
    #pragma unroll
    for (int rep = 0; rep < 512 / NT; ++rep) {
        int flat = rep * NT + tid;
        int n = flat >> 4;
        int c8 = flat & 15;
        uint4 q = *reinterpret_cast<const uint4*>(src + (size_t)n * 128 + c8 * 8);
        float* d = Xs + n * XSTR + c8 * 8;
        d[0] = bf2f((u16)(q.x & 0xffffu)); d[1] = bf2f((u16)(q.x >> 16));
        d[2] = bf2f((u16)(q.y & 0xffffu)); d[3] = bf2f((u16)(q.y >> 16));
        d[4] = bf2f((u16)(q.z & 0xffffu)); d[5] = bf2f((u16)(q.z >> 16));
        d[6] = bf2f((u16)(q.w & 0xffffu)); d[7] = bf2f((u16)(q.w >> 16));
    }
}

// ---------------- prep: Wsf = selfW @ fusW_top ; c1 = selfb @ fusW_top + fusb ----
__global__ void prep_kernel(const float* __restrict__ selfW, const float* __restrict__ selfb,
                            const float* __restrict__ fusW, const float* __restrict__ fusb,
                            float* __restrict__ Wsf, float* __restrict__ c1) {
    int o = threadIdx.x;
    int k = blockIdx.x;
    if (k < 128) {
        float acc = 0.f;
        for (int m = 0; m < 128; ++m)
            acc += selfW[k * 128 + m] * fusW[m * 128 + o];
        Wsf[k * 128 + o] = acc;
    } else {
        float acc = 0.f;
        for (int m = 0; m < 128; ++m)
            acc += selfb[m] * fusW[m * 128 + o];
        c1[o] = acc + fusb[o];
    }
}

// ---------------- wprep: transpose+convert relW/gateW -> bf16 [v][n][k] ----
__global__ __launch_bounds__(128) void wprep_kernel(
        const float* __restrict__ relW, const float* __restrict__ gateW,
        u16* __restrict__ relWb, u16* __restrict__ gateWb) {
    int k = threadIdx.x;
    int n = blockIdx.x & 127;
    int v = blockIdx.x >> 7;
    size_t o = ((size_t)v * 128 + n) * 128 + k;
    size_t i = ((size_t)v * 128 + k) * 128 + n;
    relWb[o]  = f2bf(relW[i]);
    gateWb[o] = f2bf(gateW[i]);
}

// ---------------- wprep2: bf16 n-major Wsf / featW / fusW_bot ----
__global__ __launch_bounds__(128) void wprep2_kernel(
        const float* __restrict__ Wsf, const float* __restrict__ featW,
        const float* __restrict__ fusW,
        u16* __restrict__ WsfB, u16* __restrict__ featWB, u16* __restrict__ fusWbB) {
    int k = threadIdx.x;
    int n = blockIdx.x;
    WsfB[n * 128 + k]   = f2bf(Wsf[k * 128 + n]);
    featWB[n * 128 + k] = f2bf(featW[k * 128 + n]);
    fusWbB[n * 128 + k] = f2bf(fusW[(size_t)(128 + k) * 128 + n]);
}

// ---------------- wprep3: attW1 [c][k][h] -> bf16 n-major [o=c*64+h][k] ----
__global__ __launch_bounds__(128) void wprep3_kernel(
        const float* __restrict__ attW1, u16* __restrict__ attW1B) {
    int k = threadIdx.x;
    int o = blockIdx.x;                 // 0..127
    int c = o >> 6, h = o & 63;
    attW1B[o * 128 + k] = f2bf(attW1[((size_t)c * 128 + k) * 64 + h]);
}

// ---------------- wprep4: vattW1p[v][h][k] = bf16(view_pref[v][k] * vattW1[k][h]) ----
__global__ __launch_bounds__(128) void wprep4_kernel(
        const float* __restrict__ vattW1, const float* __restrict__ view_pref,
        u16* __restrict__ vattW1p) {
    int k = threadIdx.x;
    int h = blockIdx.x & 63;
    int v = blockIdx.x >> 6;            // 0..2
    vattW1p[((size_t)v * 64 + h) * 128 + k] =
        f2bf(view_pref[v * 128 + k] * vattW1[k * 64 + h]);
}

// ---------------- featconv: feat fp32 -> bf16 ----
__global__ __launch_bounds__(256) void featconv_kernel(
        const float* __restrict__ feat, u16* __restrict__ featB) {
    int t = blockIdx.x * 256 + threadIdx.x;   // 3.2M float4 chunks
    float4 q = *reinterpret_cast<const float4*>(feat + (size_t)t * 4);
    ushort4 r;
    r.x = f2bf(q.x); r.y = f2bf(q.y); r.z = f2bf(q.z); r.w = f2bf(q.w);
    *reinterpret_cast<ushort4*>(featB + (size_t)t * 4) = r;
}

// ================= CSR build (hierarchical scan) + gather =================

__global__ __launch_bounds__(256) void count_kernel(
        const int* __restrict__ edst, int* __restrict__ C) {
    int t = blockIdx.x * 256 + threadIdx.x;
    if (t >= VV * EE) return;
    int v = t / EE;
    atomicAdd(&C[v * NN + edst[t]], 1);
}

__global__ __launch_bounds__(256) void scanA_kernel(
        const int* __restrict__ C, int* __restrict__ bs) {
    int b = blockIdx.x, t = threadIdx.x;
    int i = b * 256 + t;
    int v = (i < TOT) ? C[i] : 0;
    __shared__ int s[256];
    s[t] = v;
    __syncthreads();
    #pragma unroll
    for (int off = 128; off > 0; off >>= 1) {
        if (t < off) s[t] += s[t + off];
        __syncthreads();
    }
    if (t == 0) bs[b] = s[0];
}

__global__ __launch_bounds__(1024) void scanB_kernel(int* __restrict__ bs) {
    __shared__ int s[2048];
    int t = threadIdx.x;
    int v0 = (t < NB) ? bs[t] : 0;
    int v1 = (t + 1024 < NB) ? bs[t + 1024] : 0;
    s[t] = v0; s[t + 1024] = v1;
    __syncthreads();
    #pragma unroll
    for (int off = 1; off < 2048; off <<= 1) {
        int x0 = (t >= off) ? s[t - off] : 0;
        int x1 = (t + 1024 >= off) ? s[t + 1024 - off] : 0;
        __syncthreads();
        s[t] += x0; s[t + 1024] += x1;
        __syncthreads();
    }
    if (t < NB) bs[t] = s[t] - v0;
    if (t + 1024 < NB) bs[t + 1024] = s[t + 1024] - v1;
}

__global__ __launch_bounds__(256) void scanC_kernel(
        int* __restrict__ C, const int* __restrict__ bs) {
    int b = blockIdx.x, t = threadIdx.x;
    int i = b * 256 + t;
    int v = (i < TOT) ? C[i] : 0;
    __shared__ int s[256];
    s[t] = v;
    __syncthreads();
    #pragma unroll
    for (int off = 1; off < 256; off <<= 1) {
        int x = (t >= off) ? s[t - off] : 0;
        __syncthreads();
        s[t] += x;
        __syncthreads();
    }
    if (i < TOT) C[i] = s[t] - v + bs[b];
}

// fill: packed (src, w) per bucket slot; C becomes inclusive row ends
__global__ __launch_bounds__(256) void fill_kernel(
        const int* __restrict__ esrc, const int* __restrict__ edst,
        const float* __restrict__ ew, int* __restrict__ C,
        int2* __restrict__ bsw) {
    int t = blockIdx.x * 256 + threadIdx.x;
    if (t >= VV * EE) return;
    int v = t / EE;
    int pos = atomicAdd(&C[v * NN + edst[t]], 1);
    int2 p;
    p.x = esrc[t];
    p.y = __float_as_int(ew[t]);
    bsw[pos] = p;
}

// one wave per (v,dst) row, unroll-4 to overlap the load chains
__global__ __launch_bounds__(256) void gather_kernel(
        const u16* __restrict__ featB, const int* __restrict__ C,
        const int2* __restrict__ bsw,
        u16* __restrict__ aggB, float* __restrict__ wsum) {
    int wid = (blockIdx.x * 256 + threadIdx.x) >> 6;
    int lane = threadIdx.x & 63;
    int end = C[wid];
    int start = (wid == 0) ? 0 : C[wid - 1];
    float a0 = 0.f, a1 = 0.f, wacc = 0.f;
    int e = start;
    for (; e + 4 <= end; e += 4) {
        int2 p0 = bsw[e], p1 = bsw[e + 1], p2 = bsw[e + 2], p3 = bsw[e + 3];
        u32 f0 = *reinterpret_cast<const u32*>(featB + (size_t)p0.x * DD + lane * 2);
        u32 f1 = *reinterpret_cast<const u32*>(featB + (size_t)p1.x * DD + lane * 2);
        u32 f2 = *reinterpret_cast<const u32*>(featB + (size_t)p2.x * DD + lane * 2);
        u32 f3 = *reinterpret_cast<const u32*>(featB + (size_t)p3.x * DD + lane * 2);
        float w0 = __int_as_float(p0.y), w1 = __int_as_float(p1.y);
        float w2 = __int_as_float(p2.y), w3 = __int_as_float(p3.y);
        a0 = fmaf(w0, bf2f((u16)(f0 & 0xffffu)), a0);
        a1 = fmaf(w0, bf2f((u16)(f0 >> 16)), a1);
        a0 = fmaf(w1, bf2f((u16)(f1 & 0xffffu)), a0);
        a1 = fmaf(w1, bf2f((u16)(f1 >> 16)), a1);
        a0 = fmaf(w2, bf2f((u16)(f2 & 0xffffu)), a0);
        a1 = fmaf(w2, bf2f((u16)(f2 >> 16)), a1);
        a0 = fmaf(w3, bf2f((u16)(f3 & 0xffffu)), a0);
        a1 = fmaf(w3, bf2f((u16)(f3 >> 16)), a1);
        wacc += (w0 + w1) + (w2 + w3);
    }
    for (; e < end; ++e) {
        int2 p = bsw[e];
        float w = __int_as_float(p.y);
        u32 f = *reinterpret_cast<const u32*>(featB + (size_t)p.x * DD + lane * 2);
        a0 = fmaf(w, bf2f((u16)(f & 0xffffu)), a0);
        a1 = fmaf(w, bf2f((u16)(f >> 16)), a1);
        wacc += w;
    }
    u32 packed = (u32)f2bf(a0) | ((u32)f2bf(a1) << 16);
    *reinterpret_cast<u32*>(aggB + (size_t)wid * DD + lane * 2) = packed;
    if (lane == 0) wsum[wid] = wacc;
}

// ================= fallback: atomic scatter (R3 path) =================
__global__ __launch_bounds__(256) void scatter_kernel(
        const int* __restrict__ esrc, const int* __restrict__ edst,
        const float* __restrict__ ew, const float* __restrict__ feat,
        u16* __restrict__ aggB, float* __restrict__ wsum) {
    long long t = (long long)blockIdx.x * 256 + threadIdx.x;
    int lane = (int)(t & 31);
    int eg = (int)(t >> 5);
    int v = eg / EE;
    int src = 0, dst = 0; float w = 0.f;
    if (lane == 0) {
        src = esrc[eg]; dst = edst[eg]; w = ew[eg];
    }
    src = __shfl(src, 0, 32);
    dst = __shfl(dst, 0, 32);
    w   = __shfl(w, 0, 32);
    const float* fr = feat + (size_t)src * DD + lane * 4;
    float4 q = *reinterpret_cast<const float4*>(fr);
    u16* outp = aggB + ((size_t)v * NN + dst) * DD + lane * 4;
    atomAddBf16x2(outp,     w * q.x, w * q.y);
    atomAddBf16x2(outp + 2, w * q.z, w * q.w);
    if (lane == 0) atomicAdd(wsum + v * NN + dst, w);
}

// ---------------- MFMA label attention: node_att + class_probs ----
__global__ __launch_bounds__(256) void label_mfma_kernel(
        const u16* __restrict__ featB, const u16* __restrict__ attW1B,
        const float* __restrict__ clsW, const float* __restrict__ clsb,
        const float* __restrict__ attb1, const float* __restrict__ attW2,
        const float* __restrict__ attb2, const float* __restrict__ att_bias,
        float* __restrict__ node_att, float* __restrict__ probs_out) {
    __shared__ u16 Xs[128][136];
    __shared__ u16 Wt[128][72];
    int tid = threadIdx.x;
    int wv = tid >> 6, lane = tid & 63;
    int quad = lane >> 4, l15 = lane & 15;
    int row0 = blockIdx.x * 128;

    #pragma unroll
    for (int rep = 0; rep < 8; ++rep) {
        int flat = rep * 256 + tid;
        int n = flat >> 4, c8 = flat & 15;
        int gr = row0 + n; if (gr >= NN) gr = NN - 1;
        uint4 q = *reinterpret_cast<const uint4*>(featB + (size_t)gr * DD + c8 * 8);
        *reinterpret_cast<uint4*>(&Xs[n][c8 * 8]) = q;
    }

    f4v acc[2][8];
    #pragma unroll
    for (int rt = 0; rt < 2; ++rt)
        #pragma unroll
        for (int c = 0; c < 8; ++c)
            acc[rt][c] = f4v{0.f, 0.f, 0.f, 0.f};

    #pragma unroll
    for (int h = 0; h < 2; ++h) {
        #pragma unroll
        for (int rep = 0; rep < 4; ++rep) {
            int flat = rep * 256 + tid;
            int n = flat >> 3, c8 = flat & 7;
            uint4 q = *reinterpret_cast<const uint4*>(attW1B + (size_t)n * DD + h * 64 + c8 * 8);
            *reinterpret_cast<uint4*>(&Wt[n][c8 * 8]) = q;
        }
        __syncthreads();
        #pragma unroll
        for (int t = 0; t < 2; ++t) {
            int kl = t * 32 + quad * 8;
            s8v a0 = *reinterpret_cast<const s8v*>(&Xs[wv * 32 + l15][h * 64 + kl]);
            s8v a1 = *reinterpret_cast<const s8v*>(&Xs[wv * 32 + 16 + l15][h * 64 + kl]);
            #pragma unroll
            for (int c = 0; c < 8; ++c) {
                s8v b = *reinterpret_cast<const s8v*>(&Wt[c * 16 + l15][kl]);
                acc[0][c] = __builtin_amdgcn_mfma_f32_16x16x32_bf16(a0, b, acc[0][c], 0, 0, 0);
                acc[1][c] = __builtin_amdgcn_mfma_f32_16x16x32_bf16(a1, b, acc[1][c], 0, 0, 0);
            }
        }
        __syncthreads();
    }

    float ab1[8], aw2[8];
    #pragma unroll
    for (int c = 0; c < 8; ++c) {
        int col = c * 16 + l15;
        ab1[c] = attb1[col];
        aw2[c] = attW2[col];
    }
    float cw0[8], cw1[8];
    #pragma unroll
    for (int j = 0; j < 8; ++j) {
        int k = l15 * 8 + j;
        cw0[j] = clsW[k * 2];
        cw1[j] = clsW[k * 2 + 1];
    }
    float cb0 = clsb[0], cb1 = clsb[1];
    float b20 = attb2[0], b21 = attb2[1];
    float abias = att_bias[0];

    #pragma unroll
    for (int rt = 0; rt < 2; ++rt)
        #pragma unroll
        for (int r = 0; r < 4; ++r) {
            int n = wv * 32 + rt * 16 + quad * 4 + r;
            int gr = row0 + n;
            float p0 = 0.f, p1 = 0.f;
            #pragma unroll
            for (int c = 0; c < 4; ++c) {
                float hv = acc[rt][c][r] + ab1[c];
                hv = hv > 0.f ? hv : 0.f;
                p0 += hv * aw2[c];
            }
            #pragma unroll
            for (int c = 4; c < 8; ++c) {
                float hv = acc[rt][c][r] + ab1[c];
                hv = hv > 0.f ? hv : 0.f;
                p1 += hv * aw2[c];
            }
            uint4 q = *reinterpret_cast<const uint4*>(&Xs[n][l15 * 8]);
            float f[8];
            f[0] = bf2f((u16)(q.x & 0xffffu)); f[1] = bf2f((u16)(q.x >> 16));
            f[2] = bf2f((u16)(q.y & 0xffffu)); f[3] = bf2f((u16)(q.y >> 16));
            f[4] = bf2f((u16)(q.z & 0xffffu)); f[5] = bf2f((u16)(q.z >> 16));
            f[6] = bf2f((u16)(q.w & 0xffffu)); f[7] = bf2f((u16)(q.w >> 16));
            float l0 = 0.f, l1 = 0.f;
            #pragma unroll
            for (int j = 0; j < 8; ++j) {
                l0 = fmaf(f[j], cw0[j], l0);
                l1 = fmaf(f[j], cw1[j], l1);
            }
            #pragma unroll
            for (int m = 1; m < 16; m <<= 1) {
                p0 += __shfl_xor(p0, m);
                p1 += __shfl_xor(p1, m);
                l0 += __shfl_xor(l0, m);
                l1 += __shfl_xor(l1, m);
            }
            if (l15 == 0 && gr < NN) {
                float s0 = 1.f / (1.f + expf(-(p0 + b20)));
                float s1 = 1.f / (1.f + expf(-(p1 + b21)));
                l0 += cb0; l1 += cb1;
                float mm = fmaxf(l0, l1);
                float e0 = expf(l0 - mm), e1 = expf(l1 - mm);
                float inv = 1.f / (e0 + e1);
                float q0 = e0 * inv, q1 = e1 * inv;
                node_att[gr] = q0 * s0 + q1 * s1 + abias;
                probs_out[gr * 2]     = q0;
                probs_out[gr * 2 + 1] = q1;
            }
        }
}

// ---------------- fallback VALU label ----
__global__ __launch_bounds__(256) void label_kernel(
        const float* __restrict__ feat, const float* __restrict__ clsW, const float* __restrict__ clsb,
        const float* __restrict__ attW1, const float* __restrict__ attb1,
        const float* __restrict__ attW2, const float* __restrict__ attb2,
        const float* __restrict__ att_bias,
        float* __restrict__ node_att, float* __restrict__ probs_out) {
    __shared__ float Xs[32][132];
    __shared__ float Ws[64][132];
    int tid = threadIdx.x;
    int row0 = blockIdx.x * 32;
    stage_x_f32<132, 256>(&Xs[0][0], feat + (size_t)row0 * DD, tid);
    int to = tid & 31, tn = tid >> 5;
    int o0 = to * 4, n0 = tn * 4;
    float acc[4][4] = {};
    for (int half = 0; half < 2; ++half) {
        __syncthreads();
        #pragma unroll
        for (int rep = 0; rep < 8; ++rep) {
            int flat = rep * 256 + tid;
            int kk = flat >> 5, o4 = flat & 31;
            int o = o4 * 4;
            int c = o >> 6, h = o & 63;
            int k = half * 64 + kk;
            float4 q = *reinterpret_cast<const float4*>(attW1 + (size_t)(c * 128 + k) * 64 + h);
            *reinterpret_cast<float4*>(&Ws[kk][o]) = q;
        }
        __syncthreads();
        gemm16<132, 132>(acc, &Xs[0][0], &Ws[0][0], n0, o0, half * 64);
    }
    int c = o0 >> 6, h0 = o0 & 63;
    float b1j[4], w2j[4];
    #pragma unroll
    for (int j = 0; j < 4; ++j) {
        b1j[j] = attb1[c * 64 + h0 + j];
        w2j[j] = attW2[c * 64 + h0 + j];
    }
    float part[4];
    #pragma unroll
    for (int i = 0; i < 4; ++i) {
        float s = 0.f;
        #pragma unroll
        for (int j = 0; j < 4; ++j) {
            float hv = acc[i][j] + b1j[j];
            hv = hv > 0.f ? hv : 0.f;
            s += hv * w2j[j];
        }
        part[i] = s;
    }
    __syncthreads();
    float* red = &Ws[0][0];          // [32][33]
    float* Ssc = red + 32 * 33;      // [32][2]
    float* Lsc = Ssc + 64;           // [32][2]
    #pragma unroll
    for (int i = 0; i < 4; ++i) red[(n0 + i) * 33 + to] = part[i];
    __syncthreads();
    if (tid < 64) {
        int n = tid >> 1, cc = tid & 1;
        float l = 0.f;
        for (int k = 0; k < 128; k += 4) {
            float4 x = *reinterpret_cast<const float4*>(&Xs[n][k]);
            l += x.x * clsW[(k + 0) * 2 + cc];
            l += x.y * clsW[(k + 1) * 2 + cc];
            l += x.z * clsW[(k + 2) * 2 + cc];
            l += x.w * clsW[(k + 3) * 2 + cc];
        }
        Lsc[n * 2 + cc] = l + clsb[cc];
        float s = 0.f;
        for (int u = 0; u < 16; ++u) s += red[n * 33 + cc * 16 + u];
        s += attb2[cc];
        Ssc[n * 2 + cc] = 1.f / (1.f + expf(-s));
    }
    __syncthreads();
    if (tid < 32) {
        int n = tid;
        float l0 = Lsc[n * 2], l1 = Lsc[n * 2 + 1];
        float m = fmaxf(l0, l1);
        float e0 = expf(l0 - m), e1 = expf(l1 - m);
        float inv = 1.f / (e0 + e1);
        float p0 = e0 * inv, p1 = e1 * inv;
        float na = p0 * Ssc[n * 2] + p1 * Ssc[n * 2 + 1] + att_bias[0];
        int row = row0 + n;
        node_att[row] = na;
        probs_out[row * 2]     = p0;
        probs_out[row * 2 + 1] = p1;
    }
}

// ---------------- MFMA relgate + fused view-score ----
__global__ __launch_bounds__(256) void relgate_mfma_kernel(
        const u16* __restrict__ relWb, const float* __restrict__ relb,
        const u16* __restrict__ gateWb, const float* __restrict__ gateb,
        const u16* __restrict__ vattW1p, const float* __restrict__ vattb1,
        const float* __restrict__ vattW2, const float* __restrict__ vattb2,
        u16* __restrict__ aggB, const float* __restrict__ wsum,
        float* __restrict__ vscores) {
    __shared__ u16 Xs[128][136];
    __shared__ u16 Wt[128][72];
    int tid = threadIdx.x;
    int wv = tid >> 6, lane = tid & 63;
    int quad = lane >> 4, l15 = lane & 15;
    int v = blockIdx.y;
    int row0 = blockIdx.x * 128;
    const size_t vbase = (size_t)v * NN;

    #pragma unroll
    for (int rep = 0; rep < 8; ++rep) {
        int flat = rep * 256 + tid;
        int n = flat >> 4, c8 = flat & 15;
        int gr = row0 + n; if (gr >= NN) gr = NN - 1;
        uint4 q = *reinterpret_cast<const uint4*>(aggB + (vbase + gr) * DD + c8 * 8);
        *reinterpret_cast<uint4*>(&Xs[n][c8 * 8]) = q;
    }

    f4v acc1[2][8], acc2[2][8];
    #pragma unroll
    for (int rt = 0; rt < 2; ++rt)
        #pragma unroll
        for (int c = 0; c < 8; ++c) {
            acc1[rt][c] = f4v{0.f, 0.f, 0.f, 0.f};
            acc2[rt][c] = f4v{0.f, 0.f, 0.f, 0.f};
        }

    const u16* W1 = relWb + (size_t)v * DD * DD;
    const u16* W2 = gateWb + (size_t)v * DD * DD;

    #pragma unroll
    for (int h = 0; h < 2; ++h) {
        #pragma unroll
        for (int rep = 0; rep < 4; ++rep) {
            int flat = rep * 256 + tid;
            int n = flat >> 3, c8 = flat & 7;
            uint4 q = *reinterpret_cast<const uint4*>(W1 + (size_t)n * DD + h * 64 + c8 * 8);
            *reinterpret_cast<uint4*>(&Wt[n][c8 * 8]) = q;
        }
        __syncthreads();
        #pragma unroll
        for (int t = 0; t < 2; ++t) {
            int kl = t * 32 + quad * 8;
            s8v a0 = *reinterpret_cast<const s8v*>(&Xs[wv * 32 + l15][h * 64 + kl]);
            s8v a1 = *reinterpret_cast<const s8v*>(&Xs[wv * 32 + 16 + l15][h * 64 + kl]);
            #pragma unroll
            for (int c = 0; c < 8; ++c) {
                s8v b = *reinterpret_cast<const s8v*>(&Wt[c * 16 + l15][kl]);
                acc1[0][c] = __builtin_amdgcn_mfma_f32_16x16x32_bf16(a0, b, acc1[0][c], 0, 0, 0);
                acc1[1][c] = __builtin_amdgcn_mfma_f32_16x16x32_bf16(a1, b, acc1[1][c], 0, 0, 0);
            }
        }
        __syncthreads();
    }

    float wsn[2][4], rb[8];
    #pragma unroll
    for (int rt = 0; rt < 2; ++rt)
        #pragma unroll
        for (int r = 0; r < 4; ++r) {
            int gr = row0 + wv * 32 + rt * 16 + quad * 4 + r;
            wsn[rt][r] = wsum[vbase + (gr < NN ? gr : NN - 1)];
        }
    #pragma unroll
    for (int c = 0; c < 8; ++c) rb[c] = relb[v * DD + c * 16 + l15];
    #pragma unroll
    for (int rt = 0; rt < 2; ++rt)
        #pragma unroll
        for (int c = 0; c < 8; ++c)
            #pragma unroll
            for (int r = 0; r < 4; ++r)
                acc1[rt][c][r] += wsn[rt][r] * rb[c];

    #pragma unroll
    for (int rt = 0; rt < 2; ++rt)
        #pragma unroll
        for (int c = 0; c < 8; ++c)
            #pragma unroll
            for (int r = 0; r < 4; ++r)
                Xs[wv * 32 + rt * 16 + quad * 4 + r][c * 16 + l15] = f2bf(acc1[rt][c][r]);
    __syncthreads();

    #pragma unroll
    for (int h = 0; h < 2; ++h) {
        #pragma unroll
        for (int rep = 0; rep < 4; ++rep) {
            int flat = rep * 256 + tid;
            int n = flat >> 3, c8 = flat & 7;
            uint4 q = *reinterpret_cast<const uint4*>(W2 + (size_t)n * DD + h * 64 + c8 * 8);
            *reinterpret_cast<uint4*>(&Wt[n][c8 * 8]) = q;
        }
        __syncthreads();
        #pragma unroll
        for (int t = 0; t < 2; ++t) {
            int kl = t * 32 + quad * 8;
            s8v a0 = *reinterpret_cast<const s8v*>(&Xs[wv * 32 + l15][h * 64 + kl]);
            s8v a1 = *reinterpret_cast<const s8v*>(&Xs[wv * 32 + 16 + l15][h * 64 + kl]);
            #pragma unroll
            for (int c = 0; c < 8; ++c) {
                s8v b = *reinterpret_cast<const s8v*>(&Wt[c * 16 + l15][kl]);
                acc2[0][c] = __builtin_amdgcn_mfma_f32_16x16x32_bf16(a0, b, acc2[0][c], 0, 0, 0);
                acc2[1][c] = __builtin_amdgcn_mfma_f32_16x16x32_bf16(a1, b, acc2[1][c], 0, 0, 0);
            }
        }
        __syncthreads();
    }

    // gate: view_out -> Xs (bf16)
    float gb[8];
    #pragma unroll
    for (int c = 0; c < 8; ++c) gb[c] = gateb[v * DD + c * 16 + l15];
    #pragma unroll
    for (int rt = 0; rt < 2; ++rt)
        #pragma unroll
        for (int c = 0; c < 8; ++c)
            #pragma unroll
            for (int r = 0; r < 4; ++r) {
                float g = 1.f / (1.f + expf(-(acc2[rt][c][r] + gb[c])));
                Xs[wv * 32 + rt * 16 + quad * 4 + r][c * 16 + l15] = f2bf(g * acc1[rt][c][r]);
            }

    // stage folded view-score weights: Wt[h*64 + n][k-half] = vattW1p[v][n][k]
    {
        const u16* Wv = vattW1p + (size_t)v * 64 * DD;
        #pragma unroll
        for (int rep = 0; rep < 4; ++rep) {
            int flat = rep * 256 + tid;       // 0..1023 uint4 chunks
            int n = flat >> 4, c8 = flat & 15;
            uint4 q = *reinterpret_cast<const uint4*>(Wv + (size_t)n * DD + c8 * 8);
            int half = c8 >> 3;
            *reinterpret_cast<uint4*>(&Wt[half * 64 + n][(c8 & 7) * 8]) = q;
        }
    }
    __syncthreads();

    // store view_out
    #pragma unroll
    for (int rep = 0; rep < 8; ++rep) {
        int flat = rep * 256 + tid;
        int n = flat >> 4, c8 = flat & 15;
        int gr = row0 + n;
        if (gr < NN)
            *reinterpret_cast<uint4*>(aggB + (vbase + gr) * DD + c8 * 8) =
                *reinterpret_cast<const uint4*>(&Xs[n][c8 * 8]);
    }

    // fused view-score GEMM: acc3 = view_out @ (view_pref ⊙ vattW1)
    f4v acc3[2][4];
    #pragma unroll
    for (int rt = 0; rt < 2; ++rt)
        #pragma unroll
        for (int c = 0; c < 4; ++c)
            acc3[rt][c] = f4v{0.f, 0.f, 0.f, 0.f};
    #pragma unroll
    for (int h = 0; h < 2; ++h) {
        #pragma unroll
        for (int t = 0; t < 2; ++t) {
            int kl = t * 32 + quad * 8;
            s8v a0 = *reinterpret_cast<const s8v*>(&Xs[wv * 32 + l15][h * 64 + kl]);
            s8v a1 = *reinterpret_cast<const s8v*>(&Xs[wv * 32 + 16 + l15][h * 64 + kl]);
            #pragma unroll
            for (int c = 0; c < 4; ++c) {
                s8v b = *reinterpret_cast<const s8v*>(&Wt[h * 64 + c * 16 + l15][kl]);
                acc3[0][c] = __builtin_amdgcn_mfma_f32_16x16x32_bf16(a0, b, acc3[0][c], 0, 0, 0);
                acc3[1][c] = __builtin_amdgcn_mfma_f32_16x16x32_bf16(a1, b, acc3[1][c], 0, 0, 0);
            }
        }
    }
    float vb1[4], vw2[4];
    #pragma unroll
    for (int c = 0; c < 4; ++c) {
        int col = c * 16 + l15;
        vb1[c] = vattb1[col];
        vw2[c] = vattW2[col];
    }
    float vb2 = vattb2[0];
    #pragma unroll
    for (int rt = 0; rt < 2; ++rt)
        #pragma unroll
        for (int r = 0; r < 4; ++r) {
            float p = 0.f;
            #pragma unroll
            for (int c = 0; c < 4; ++c) {
                float hv = acc3[rt][c][r] + vb1[c];
                hv = hv > 0.f ? hv : 0.f;
                p += hv * vw2[c];
            }
            #pragma unroll
            for (int m = 1; m < 16; m <<= 1)
                p += __shfl_xor(p, m);
            int gr = row0 + wv * 32 + rt * 16 + quad * 4 + r;
            if (l15 == 0 && gr < NN)
                vscores[vbase + gr] = p + vb2;
        }
}

// ---------------- fallback VALU relgate ----
__global__ __launch_bounds__(256) void relgate_kernel(
        const float* __restrict__ relW, const float* __restrict__ relb,
        const float* __restrict__ gateW, const float* __restrict__ gateb,
        u16* __restrict__ aggB, const float* __restrict__ wsum) {
    __shared__ float Xs[32][128];
    __shared__ float Ws[64][132];
    int tid = threadIdx.x;
    int v = blockIdx.y;
    int row0 = blockIdx.x * 32;
    u16* base = aggB + ((size_t)v * NN + row0) * DD;
    stage_x_bf16<128, 256>(&Xs[0][0], base, tid);
    int to = tid & 31, tn = tid >> 5;
    int o0 = to * 4, n0 = tn * 4;
    float acc[4][4] = {};
    const float* W1 = relW + (size_t)v * DD * DD;
    for (int half = 0; half < 2; ++half) {
        __syncthreads();
        stage_w_f32<132, 256>(&Ws[0][0], W1 + half * 64 * DD, tid);
        __syncthreads();
        gemm16<128, 132>(acc, &Xs[0][0], &Ws[0][0], n0, o0, half * 64);
    }
    float wsn[4], rb[4];
    #pragma unroll
    for (int i = 0; i < 4; ++i) wsn[i] = wsum[v * NN + row0 + n0 + i];
    #pragma unroll
    for (int j = 0; j < 4; ++j) rb[j] = relb[v * DD + o0 + j];
    #pragma unroll
    for (int i = 0; i < 4; ++i)
        #pragma unroll
        for (int j = 0; j < 4; ++j) acc[i][j] += wsn[i] * rb[j];
    __syncthreads();
    #pragma unroll
    for (int i = 0; i < 4; ++i)
        *reinterpret_cast<float4*>(&Xs[n0 + i][o0]) = make_float4(acc[i][0], acc[i][1], acc[i][2], acc[i][3]);
    float acc2[4][4] = {};
    const float* W2 = gateW + (size_t)v * DD * DD;
    for (int half = 0; half < 2; ++half) {
        __syncthreads();
        stage_w_f32<132, 256>(&Ws[0][0], W2 + half * 64 * DD, tid);
        __syncthreads();
        gemm16<128, 132>(acc2, &Xs[0][0], &Ws[0][0], n0, o0, half * 64);
    }
    float gb[4];
    #pragma unroll
    for (int j = 0; j < 4; ++j) gb[j] = gateb[v * DD + o0 + j];
    #pragma unroll
    for (int i = 0; i < 4; ++i) {
        float g0 = 1.f / (1.f + expf(-(acc2[i][0] + gb[0])));
        float g1 = 1.f / (1.f + expf(-(acc2[i][1] + gb[1])));
        float g2 = 1.f / (1.f + expf(-(acc2[i][2] + gb[2])));
        float g3 = 1.f / (1.f + expf(-(acc2[i][3] + gb[3])));
        ushort4 r;
        r.x = f2bf(g0 * acc[i][0]); r.y = f2bf(g1 * acc[i][1]);
        r.z = f2bf(g2 * acc[i][2]); r.w = f2bf(g3 * acc[i][3]);
        *reinterpret_cast<ushort4*>(base + (size_t)(n0 + i) * DD + o0) = r;
    }
}

// ---------------- fallback view attention scores ----
__global__ __launch_bounds__(128) void vatt_kernel(
        const u16* __restrict__ aggB, const float* __restrict__ view_pref,
        const float* __restrict__ vattW1, const float* __restrict__ vattb1,
        const float* __restrict__ vattW2, const float* __restrict__ vattb2,
        float* __restrict__ vscores) {
    __shared__ float Xs[32][132];
    __shared__ float Ws[128][68];
    int tid = threadIdx.x;
    int v = blockIdx.y;
    int row0 = blockIdx.x * 32;
    const u16* base = aggB + ((size_t)v * NN + row0) * DD;
    #pragma unroll
    for (int rep = 0; rep < 4; ++rep) {
        int flat = rep * 128 + tid;
        int n = flat >> 4, c8 = flat & 15;
        uint4 q = *reinterpret_cast<const uint4*>(base + (size_t)n * DD + c8 * 8);
        float4 pa = *reinterpret_cast<const float4*>(view_pref + v * DD + c8 * 8);
        float4 pb = *reinterpret_cast<const float4*>(view_pref + v * DD + c8 * 8 + 4);
        float* d = &Xs[n][c8 * 8];
        d[0] = bf2f((u16)(q.x & 0xffffu)) * pa.x; d[1] = bf2f((u16)(q.x >> 16)) * pa.y;
        d[2] = bf2f((u16)(q.y & 0xffffu)) * pa.z; d[3] = bf2f((u16)(q.y >> 16)) * pa.w;
        d[4] = bf2f((u16)(q.z & 0xffffu)) * pb.x; d[5] = bf2f((u16)(q.z >> 16)) * pb.y;
        d[6] = bf2f((u16)(q.w & 0xffffu)) * pb.z; d[7] = bf2f((u16)(q.w >> 16)) * pb.w;
    }
    #pragma unroll
    for (int rep = 0; rep < 16; ++rep) {
        int flat = rep * 128 + tid;
        int k = flat >> 4, c4 = flat & 15;
        float4 q = *reinterpret_cast<const float4*>(vattW1 + k * 64 + c4 * 4);
        *reinterpret_cast<float4*>(&Ws[k][c4 * 4]) = q;
    }
    __syncthreads();
    int to = tid & 15, tn = tid >> 4;
    int o0 = to * 4, n0 = tn * 4;
    float acc[4][4] = {};
    gemm16<132, 68>(acc, &Xs[0][0], &Ws[0][0], n0, o0, 0);
    gemm16<132, 68>(acc, &Xs[0][0], &Ws[64][0], n0, o0, 64);
    float b1[4], w2[4];
    #pragma unroll
    for (int j = 0; j < 4; ++j) {
        b1[j] = vattb1[o0 + j];
        w2[j] = vattW2[o0 + j];
    }
    float part[4];
    #pragma unroll
    for (int i = 0; i < 4; ++i) {
        float s = 0.f;
        #pragma unroll
        for (int j = 0; j < 4; ++j) {
            float hv = acc[i][j] + b1[j];
            hv = hv > 0.f ? hv : 0.f;
            s += hv * w2[j];
        }
        part[i] = s;
    }
    __syncthreads();
    float* red = &Ws[0][0];   // [32][17]
    #pragma unroll
    for (int i = 0; i < 4; ++i) red[(n0 + i) * 17 + to] = part[i];
    __syncthreads();
    if (tid < 32) {
        float s = 0.f;
        for (int u = 0; u < 16; ++u) s += red[tid * 17 + u];
        vscores[(size_t)v * NN + row0 + tid] = s + vattb2[0];
    }
}

// ---------------- fallback combine ----
__global__ __launch_bounds__(256) void combine_kernel(
        u16* __restrict__ aggB, const float* __restrict__ vscores,
        const float* __restrict__ node_att) {
    int t = blockIdx.x * 256 + threadIdx.x;
    int n = t >> 5, c4 = t & 31;
    float s0 = vscores[n], s1 = vscores[NN + n], s2 = vscores[2 * NN + n];
    float m = fmaxf(s0, fmaxf(s1, s2));
    float e0 = expf(s0 - m), e1 = expf(s1 - m), e2 = expf(s2 - m);
    float inv = 1.f / (e0 + e1 + e2);
    float w0 = e0 * inv, w1 = e1 * inv, w2 = e2 * inv;
    float na = node_att[n];
    size_t off = (size_t)n * DD + c4 * 4;
    ushort4 q0 = *reinterpret_cast<const ushort4*>(aggB + off);
    ushort4 q1 = *reinterpret_cast<const ushort4*>(aggB + (size_t)NN * DD + off);
    ushort4 q2 = *reinterpret_cast<const ushort4*>(aggB + 2 * (size_t)NN * DD + off);
    ushort4 r;
    r.x = f2bf((bf2f(q0.x) * w0 + bf2f(q1.x) * w1 + bf2f(q2.x) * w2) * na);
    r.y = f2bf((bf2f(q0.y) * w0 + bf2f(q1.y) * w1 + bf2f(q2.y) * w2) * na);
    r.z = f2bf((bf2f(q0.z) * w0 + bf2f(q1.z) * w1 + bf2f(q2.z) * w2) * na);
    r.w = f2bf((bf2f(q0.w) * w0 + bf2f(q1.w) * w1 + bf2f(q2.w) * w2) * na);
    *reinterpret_cast<ushort4*>(aggB + off) = r;
}

// ---------------- MFMA final + fused combine ----
__global__ __launch_bounds__(256) void final_mfma_kernel(
        const u16* __restrict__ featB, const u16* __restrict__ aggB,
        const float* __restrict__ vsc, const float* __restrict__ natt,
        const u16* __restrict__ WsfB, const u16* __restrict__ featWB,
        const u16* __restrict__ fusWbB,
        const float* __restrict__ c1, const float* __restrict__ featb,
        const float* __restrict__ ln_g, const float* __restrict__ ln_b,
        float* __restrict__ outp) {
    __shared__ u16 Xs[128][136];
    __shared__ u16 Wt[128][72];
    __shared__ float rw[3][128];
    int tid = threadIdx.x;
    int wv = tid >> 6, lane = tid & 63;
    int quad = lane >> 4, l15 = lane & 15;
    int row0 = blockIdx.x * 128;

    #pragma unroll
    for (int rep = 0; rep < 8; ++rep) {
        int flat = rep * 256 + tid;
        int n = flat >> 4, c8 = flat & 15;
        int gr = row0 + n; if (gr >= NN) gr = NN - 1;
        uint4 q = *reinterpret_cast<const uint4*>(featB + (size_t)gr * DD + c8 * 8);
        *reinterpret_cast<uint4*>(&Xs[n][c8 * 8]) = q;
    }
    // per-row combine weights
    if (tid < 128) {
        int gr = row0 + tid; if (gr >= NN) gr = NN - 1;
        float s0 = vsc[gr], s1 = vsc[NN + gr], s2 = vsc[2 * NN + gr];
        float m = fmaxf(s0, fmaxf(s1, s2));
        float e0 = expf(s0 - m), e1 = expf(s1 - m), e2 = expf(s2 - m);
        float inv = 1.f / (e0 + e1 + e2);
        float na = natt[gr];
        rw[0][tid] = e0 * inv * na;
        rw[1][tid] = e1 * inv * na;
        rw[2][tid] = e2 * inv * na;
    }

    f4v acc1[2][8], acc2[2][8];
    #pragma unroll
    for (int rt = 0; rt < 2; ++rt)
        #pragma unroll
        for (int c = 0; c < 8; ++c) {
            acc1[rt][c] = f4v{0.f, 0.f, 0.f, 0.f};
            acc2[rt][c] = f4v{0.f, 0.f, 0.f, 0.f};
        }

    #pragma unroll
    for (int h = 0; h < 2; ++h) {
        #pragma unroll
        for (int rep = 0; rep < 4; ++rep) {
            int flat = rep * 256 + tid;
            int n = flat >> 3, c8 = flat & 7;
            uint4 q = *reinterpret_cast<const uint4*>(WsfB + (size_t)n * DD + h * 64 + c8 * 8);
            *reinterpret_cast<uint4*>(&Wt[n][c8 * 8]) = q;
        }
        __syncthreads();
        #pragma unroll
        for (int t = 0; t < 2; ++t) {
            int kl = t * 32 + quad * 8;
            s8v a0 = *reinterpret_cast<const s8v*>(&Xs[wv * 32 + l15][h * 64 + kl]);
            s8v a1 = *reinterpret_cast<const s8v*>(&Xs[wv * 32 + 16 + l15][h * 64 + kl]);
            #pragma unroll
            for (int c = 0; c < 8; ++c) {
                s8v b = *reinterpret_cast<const s8v*>(&Wt[c * 16 + l15][kl]);
                acc1[0][c] = __builtin_amdgcn_mfma_f32_16x16x32_bf16(a0, b, acc1[0][c], 0, 0, 0);
                acc1[1][c] = __builtin_amdgcn_mfma_f32_16x16x32_bf16(a1, b, acc1[1][c], 0, 0, 0);
            }
        }
        __syncthreads();
        #pragma unroll
        for (int rep = 0; rep < 4; ++rep) {
            int flat = rep * 256 + tid;
            int n = flat >> 3, c8 = flat & 7;
            uint4 q = *reinterpret_cast<const uint4*>(featWB + (size_t)n * DD + h * 64 + c8 * 8);
            *reinterpret_cast<uint4*>(&Wt[n][c8 * 8]) = q;
        }
        __syncthreads();
        #pragma unroll
        for (int t = 0; t < 2; ++t) {
            int kl = t * 32 + quad * 8;
            s8v a0 = *reinterpret_cast<const s8v*>(&Xs[wv * 32 + l15][h * 64 + kl]);
            s8v a1 = *reinterpret_cast<const s8v*>(&Xs[wv * 32 + 16 + l15][h * 64 + kl]);
            #pragma unroll
            for (int c = 0; c < 8; ++c) {
                s8v b = *reinterpret_cast<const s8v*>(&Wt[c * 16 + l15][kl]);
                acc2[0][c] = __builtin_amdgcn_mfma_f32_16x16x32_bf16(a0, b, acc2[0][c], 0, 0, 0);
                acc2[1][c] = __builtin_amdgcn_mfma_f32_16x16x32_bf16(a1, b, acc2[1][c], 0, 0, 0);
            }
        }
        __syncthreads();
    }

    // fused combine: Xs = bf16( rw0*view0 + rw1*view1 + rw2*view2 )
    #pragma unroll
    for (int rep = 0; rep < 8; ++rep) {
        int flat = rep * 256 + tid;
        int n = flat >> 4, c8 = flat & 15;
        int gr = row0 + n; if (gr >= NN) gr = NN - 1;
        size_t off = (size_t)gr * DD + c8 * 8;
        uint4 q0 = *reinterpret_cast<const uint4*>(aggB + off);
        uint4 q1 = *reinterpret_cast<const uint4*>(aggB + (size_t)NN * DD + off);
        uint4 q2 = *reinterpret_cast<const uint4*>(aggB + 2 * (size_t)NN * DD + off);
        float w0 = rw[0][n], w1 = rw[1][n], w2 = rw[2][n];
        u32 o[4];
        const u32* a = &q0.x; const u32* b = &q1.x; const u32* c = &q2.x;
        #pragma unroll
        for (int j = 0; j < 4; ++j) {
            float lo = bf2f((u16)(a[j] & 0xffffu)) * w0 + bf2f((u16)(b[j] & 0xffffu)) * w1
                     + bf2f((u16)(c[j] & 0xffffu)) * w2;
            float hi = bf2f((u16)(a[j] >> 16)) * w0 + bf2f((u16)(b[j] >> 16)) * w1
                     + bf2f((u16)(c[j] >> 16)) * w2;
            o[j] = (u32)f2bf(lo) | ((u32)f2bf(hi) << 16);
        }
        uint4 r; r.x = o[0]; r.y = o[1]; r.z = o[2]; r.w = o[3];
        *reinterpret_cast<uint4*>(&Xs[n][c8 * 8]) = r;
    }
    #pragma unroll
    for (int h = 0; h < 2; ++h) {
        #pragma unroll
        for (int rep = 0; rep < 4; ++rep) {
            int flat = rep * 256 + tid;
            int n = flat >> 3, c8 = flat & 7;
            uint4 q = *reinterpret_cast<const uint4*>(fusWbB + (size_t)n * DD + h * 64 + c8 * 8);
            *reinterpret_cast<uint4*>(&Wt[n][c8 * 8]) = q;
        }
        __syncthreads();
        #pragma unroll
        for (int t = 0; t < 2; ++t) {
            int kl = t * 32 + quad * 8;
            s8v a0 = *reinterpret_cast<const s8v*>(&Xs[wv * 32 + l15][h * 64 + kl]);
            s8v a1 = *reinterpret_cast<const s8v*>(&Xs[wv * 32 + 16 + l15][h * 64 + kl]);
            #pragma unroll
            for (int c = 0; c < 8; ++c) {
                s8v b = *reinterpret_cast<const s8v*>(&Wt[c * 16 + l15][kl]);
                acc1[0][c] = __builtin_amdgcn_mfma_f32_16x16x32_bf16(a0, b, acc1[0][c], 0, 0, 0);
                acc1[1][c] = __builtin_amdgcn_mfma_f32_16x16x32_bf16(a1, b, acc1[1][c], 0, 0, 0);
            }
        }
        __syncthreads();
    }

    float c1j[8], fbj[8], gj[8], bj[8];
    #pragma unroll
    for (int c = 0; c < 8; ++c) {
        int col = c * 16 + l15;
        c1j[c] = c1[col];
        fbj[c] = featb[col];
        gj[c]  = ln_g[col];
        bj[c]  = ln_b[col];
    }
    #pragma unroll
    for (int rt = 0; rt < 2; ++rt)
        #pragma unroll
        for (int c = 0; c < 8; ++c)
            #pragma unroll
            for (int r = 0; r < 4; ++r) {
                float f = acc1[rt][c][r] + c1j[c];
                f = f > 0.f ? f : 0.f;
                acc1[rt][c][r] = f + acc2[rt][c][r] + fbj[c];
            }
    #pragma unroll
    for (int rt = 0; rt < 2; ++rt)
        #pragma unroll
        for (int r = 0; r < 4; ++r) {
            float s = 0.f, q = 0.f;
            #pragma unroll
            for (int c = 0; c < 8; ++c) {
                float x = acc1[rt][c][r];
                s += x; q += x * x;
            }
            #pragma unroll
            for (int m = 1; m < 16; m <<= 1) {
                s += __shfl_xor(s, m);
                q += __shfl_xor(q, m);
            }
            float mu = s * (1.f / 128.f);
            float var = q * (1.f / 128.f) - mu * mu;
            float rs = rsqrtf(var + 1e-5f);
            int gr = row0 + wv * 32 + rt * 16 + quad * 4 + r;
            if (gr < NN) {
                #pragma unroll
                for (int c = 0; c < 8; ++c)
                    outp[(size_t)gr * DD + c * 16 + l15] =
                        (acc1[rt][c][r] - mu) * rs * gj[c] + bj[c];
            }
        }
}

// ---------------- fallback VALU final ----
__global__ __launch_bounds__(256) void final_kernel(
        const float* __restrict__ feat, const u16* __restrict__ weightedB,
        const float* __restrict__ Wsf, const float* __restrict__ c1,
        const float* __restrict__ fusW, const float* __restrict__ featW,
        const float* __restrict__ featb, const float* __restrict__ ln_g,
        const float* __restrict__ ln_b, float* __restrict__ outp) {
    __shared__ float Xs[32][128];
    __shared__ float Ws[64][128];
    int tid = threadIdx.x;
    int row0 = blockIdx.x * 32;
    stage_x_f32<128, 256>(&Xs[0][0], feat + (size_t)row0 * DD, tid);
    int to = tid & 31, tn = tid >> 5;
    int o0 = to * 4, n0 = tn * 4;
    float acc1[4][4] = {}, acc2[4][4] = {};
    for (int half = 0; half < 2; ++half) {
        __syncthreads();
        stage_w_f32<128, 256>(&Ws[0][0], Wsf + half * 64 * 128, tid);
        __syncthreads();
        gemm16<128, 128>(acc1, &Xs[0][0], &Ws[0][0], n0, o0, half * 64);
    }
    for (int half = 0; half < 2; ++half) {
        __syncthreads();
        stage_w_f32<128, 256>(&Ws[0][0], featW + half * 64 * 128, tid);
        __syncthreads();
        gemm16<128, 128>(acc2, &Xs[0][0], &Ws[0][0], n0, o0, half * 64);
    }
    __syncthreads();
    stage_x_bf16<128, 256>(&Xs[0][0], weightedB + (size_t)row0 * DD, tid);
    for (int half = 0; half < 2; ++half) {
        __syncthreads();
        stage_w_f32<128, 256>(&Ws[0][0], fusW + (size_t)(128 + half * 64) * 128, tid);
        __syncthreads();
        gemm16<128, 128>(acc1, &Xs[0][0], &Ws[0][0], n0, o0, half * 64);
    }
    float c1j[4], fbj[4], gj[4], bj[4];
    #pragma unroll
    for (int j = 0; j < 4; ++j) {
        c1j[j] = c1[o0 + j];
        fbj[j] = featb[o0 + j];
        gj[j]  = ln_g[o0 + j];
        bj[j]  = ln_b[o0 + j];
    }
    float val[4][4];
    #pragma unroll
    for (int i = 0; i < 4; ++i)
        #pragma unroll
        for (int j = 0; j < 4; ++j) {
            float f = acc1[i][j] + c1j[j];
            f = f > 0.f ? f : 0.f;
            val[i][j] = f + acc2[i][j] + fbj[j];
        }
    __syncthreads();
    float* red_s = &Ws[0][0];
    float* red_q = red_s + 32 * 33;
    float* mus   = red_q + 32 * 33;
    float* rss   = mus + 32;
    #pragma unroll
    for (int i = 0; i < 4; ++i) {
        float s = 0.f, q = 0.f;
        #pragma unroll
        for (int j = 0; j < 4; ++j) { s += val[i][j]; q += val[i][j] * val[i][j]; }
        red_s[(n0 + i) * 33 + to] = s;
        red_q[(n0 + i) * 33 + to] = q;
    }
    __syncthreads();
    if (tid < 32) {
        float s = 0.f, q = 0.f;
        for (int u = 0; u < 32; ++u) { s += red_s[tid * 33 + u]; q += red_q[tid * 33 + u]; }
        float mu = s / 128.f;
        float var = q / 128.f - mu * mu;
        mus[tid] = mu;
        rss[tid] = rsqrtf(var + 1e-5f);
    }
    __syncthreads();
    #pragma unroll
    for (int i = 0; i < 4; ++i) {
        float mu = mus[n0 + i], rs = rss[n0 + i];
        float4 o;
        o.x = (val[i][0] - mu) * rs * gj[0] + bj[0];
        o.y = (val[i][1] - mu) * rs * gj[1] + bj[1];
        o.z = (val[i][2] - mu) * rs * gj[2] + bj[2];
        o.w = (val[i][3] - mu) * rs * gj[3] + bj[3];
        *reinterpret_cast<float4*>(outp + (size_t)(row0 + n0 + i) * DD + o0) = o;
    }
}

extern "C" void kernel_launch(void* const* d_in, const int* in_sizes, int n_in,
                              void* d_out, int out_size, void* d_ws, size_t ws_size,
                              hipStream_t stream) {
    (void)in_sizes; (void)n_in; (void)out_size;
    const float* feat      = (const float*)d_in[0];
    const int*   esrc      = (const int*)d_in[1];
    const int*   edst      = (const int*)d_in[2];
    const float* ew        = (const float*)d_in[3];
    const float* clsW      = (const float*)d_in[4];
    const float* clsb      = (const float*)d_in[5];
    const float* attW1     = (const float*)d_in[6];
    const float* attb1     = (const float*)d_in[7];
    const float* attW2     = (const float*)d_in[8];
    const float* attb2     = (const float*)d_in[9];
    const float* att_bias  = (const float*)d_in[10];
    const float* relW      = (const float*)d_in[11];
    const float* relb      = (const float*)d_in[12];
    const float* gateW     = (const float*)d_in[13];
    const float* gateb     = (const float*)d_in[14];
    const float* view_pref = (const float*)d_in[15];
    const float* vattW1    = (const float*)d_in[16];
    const float* vattb1    = (const float*)d_in[17];
    const float* vattW2    = (const float*)d_in[18];
    const float* vattb2    = (const float*)d_in[19];
    const float* selfW     = (const float*)d_in[20];
    const float* selfb     = (const float*)d_in[21];
    const float* featW     = (const float*)d_in[22];
    const float* featb     = (const float*)d_in[23];
    const float* fusW      = (const float*)d_in[24];
    const float* fusb      = (const float*)d_in[25];
    const float* ln_g      = (const float*)d_in[26];
    const float* ln_b      = (const float*)d_in[27];

    // workspace layout (~120 MiB):
    u16*   aggB = (u16*)d_ws;                                   // [3][N][128] bf16
    float* wsum = (float*)(aggB + (size_t)VV * NN * DD);        // [3][N]
    float* natt = wsum + (size_t)VV * NN;                       // [N]
    float* vsc  = natt + NN;                                    // [3][N]
    float* Wsf  = vsc + (size_t)VV * NN;                        // [128][128]
    float* c1   = Wsf + DD * DD;                                // [128]
    u16* relWb  = (u16*)(c1 + DD);                              // [3][128][128] bf16
    u16* gateWb = relWb + (size_t)VV * DD * DD;                 // [3][128][128] bf16
    u16* WsfB   = gateWb + (size_t)VV * DD * DD;                // [128][128] bf16
    u16* featWB = WsfB + DD * DD;                               // [128][128] bf16
    u16* fusWbB = featWB + DD * DD;                             // [128][128] bf16
    u16* attW1B = fusWbB + DD * DD;                             // [128][128] bf16
    u16* vattW1p = attW1B + DD * DD;                            // [3][64][128] bf16
    int*   C    = (int*)(vattW1p + (size_t)VV * 64 * DD);       // [3N]
    int*   bs   = C + (size_t)TOT;                              // [NB]
    int2*  bsw  = (int2*)(bs + NB + 1);                         // [3E] packed (src,w)
    u16* featB  = (u16*)(bsw + (size_t)VV * EE);                // [N][128] bf16
    size_t needed = (size_t)((char*)(featB + (size_t)NN * DD) - (char*)d_ws);

    float* outp  = (float*)d_out;
    float* probs = outp + (size_t)NN * DD;

    prep_kernel<<<129, 128, 0, stream>>>(selfW, selfb, fusW, fusb, Wsf, c1);
    if (ws_size >= needed) {
        featconv_kernel<<<12500, 256, 0, stream>>>(feat, featB);
        wprep_kernel<<<384, 128, 0, stream>>>(relW, gateW, relWb, gateWb);
        wprep2_kernel<<<128, 128, 0, stream>>>(Wsf, featW, fusW, WsfB, featWB, fusWbB);
        wprep3_kernel<<<128, 128, 0, stream>>>(attW1, attW1B);
        wprep4_kernel<<<192, 128, 0, stream>>>(vattW1, view_pref, vattW1p);
        label_mfma_kernel<<<RGB, 256, 0, stream>>>(featB, attW1B, clsW, clsb, attb1,
                                                   attW2, attb2, att_bias, natt, probs);
        hipMemsetAsync(C, 0, (size_t)TOT * sizeof(int), stream);
        count_kernel<<<(VV * EE + 255) / 256, 256, 0, stream>>>(edst, C);
        scanA_kernel<<<NB, 256, 0, stream>>>(C, bs);
        scanB_kernel<<<1, 1024, 0, stream>>>(bs);
        scanC_kernel<<<NB, 256, 0, stream>>>(C, bs);
        fill_kernel<<<(VV * EE + 255) / 256, 256, 0, stream>>>(esrc, edst, ew, C, bsw);
        gather_kernel<<<(VV * NN) / 4, 256, 0, stream>>>(featB, C, bsw, aggB, wsum);
        relgate_mfma_kernel<<<dim3(RGB, 3), 256, 0, stream>>>(relWb, relb, gateWb, gateb,
                                                              vattW1p, vattb1, vattW2, vattb2,
                                                              aggB, wsum, vsc);
        final_mfma_kernel<<<RGB, 256, 0, stream>>>(featB, aggB, vsc, natt,
                                                   WsfB, featWB, fusWbB,
                                                   c1, featb, ln_g, ln_b, outp);
    } else {
        label_kernel<<<3125, 256, 0, stream>>>(feat, clsW, clsb, attW1, attb1, attW2, attb2,
                                               att_bias, natt, probs);
        hipMemsetAsync(d_ws, 0,
                       (size_t)VV * NN * DD * sizeof(u16) + (size_t)VV * NN * sizeof(float),
                       stream);
        scatter_kernel<<<187500, 256, 0, stream>>>(esrc, edst, ew, feat, aggB, wsum);
        relgate_kernel<<<dim3(3125, 3), 256, 0, stream>>>(relW, relb, gateW, gateb, aggB, wsum);
        vatt_kernel<<<dim3(3125, 3), 128, 0, stream>>>(aggB, view_pref, vattW1, vattb1,
                                                       vattW2, vattb2, vsc);
        combine_kernel<<<12500, 256, 0, stream>>>(aggB, vsc, natt);
        final_kernel<<<3125, 256, 0, stream>>>(feat, aggB, Wsf, c1, fusW, featW, featb,
                                               ln_g, ln_b, outp);
    }
}